// Round 2
// baseline (2321.794 us; speedup 1.0000x reference)
//
#include <hip/hip_runtime.h>

// ---------------------------------------------------------------------------
// NodeModel (GraphNet node block), MI355X / gfx950.
//   Phase A (edges, E rows):  h0=[x[row],ea] -> (BN,Lin,LReLU)x2 -> BN,Lin
//   scatter-sum by col -> agg[N,64]
//   Phase B (nodes, N rows):  h2=[x,agg] -> (BN,Lin,LReLU)x2 -> BN,Lin -> out
// BN folded into GEMM weights (needs column stats of each layer input).
// GEMMs use v_mfma_f32_16x16x32_bf16; weights pre-packed into per-lane
// fragment order by fold kernels. Layouts per verified guide:
//   A[m=lane&15][k=(lane>>4)*8+j], B[k=(lane>>4)*8+j][n=lane&15],
//   C/D: col=lane&15, row=(lane>>4)*4+reg.
// Input dtype (fp32 vs bf16 harness mode) detected at runtime from bit
// patterns of x; all raw-input loads + final store branch on the mode flag.
// ---------------------------------------------------------------------------

typedef unsigned short u16;
typedef __bf16  bf16x8  __attribute__((ext_vector_type(8)));
typedef float   floatx4 __attribute__((ext_vector_type(4)));

__device__ __forceinline__ float bf2f(u16 u) {
  union { float f; unsigned int i; } v; v.i = ((unsigned int)u) << 16; return v.f;
}
__device__ __forceinline__ u16 f2bf(float f) {
  union { float f; unsigned int i; } v; v.f = f;
  unsigned int x = v.i;
  return (u16)((x + 0x7fffu + ((x >> 16) & 1u)) >> 16);  // RNE
}
__device__ __forceinline__ bf16x8 ldb8(const u16* p) {
  return *reinterpret_cast<const bf16x8*>(p);
}
__device__ __forceinline__ floatx4 mfma16(bf16x8 a, bf16x8 b, floatx4 c) {
  return __builtin_amdgcn_mfma_f32_16x16x32_bf16(a, b, c, 0, 0, 0);
}
// mode: 0 = input is float32, 1 = input is bf16
__device__ __forceinline__ float loadf(const void* p, long idx, int mode) {
  return mode ? bf2f(((const u16*)p)[idx]) : ((const float*)p)[idx];
}
__device__ __forceinline__ bf16x8 load8(const void* p, long idx, int mode) {
  if (mode) return ldb8((const u16*)p + idx);
  const float* f = (const float*)p + idx;
  bf16x8 r;
#pragma unroll
  for (int j = 0; j < 8; j++) r[j] = (__bf16)f[j];
  return r;
}

// ---------------- dtype detection: bf16 N(0,1) data has exponents ~0x7F;
// fp32 read as u16 has ~40% extreme/NaN exponent patterns.
__global__ void detect_kernel(const u16* __restrict__ x, int* __restrict__ modep) {
  __shared__ int cnt;
  if (threadIdx.x == 0) cnt = 0;
  __syncthreads();
  int weird = 0;
  for (int i = threadIdx.x; i < 1024; i += blockDim.x) {
    unsigned e = (x[i] >> 7) & 0xFFu;
    if (e == 0xFFu || e >= 0x90u || (e != 0u && e < 0x60u)) weird++;
  }
  atomicAdd(&cnt, weird);
  __syncthreads();
  if (threadIdx.x == 0) *modep = (cnt > 128) ? 0 : 1;
}

// ---------------- column stats: partial sums per block -> partials[P][2*COLS]
// fixed: -1 = read dtype from modep; 0 = float32; 1 = bf16
template <int COLS>
__global__ void stats_kernel(const void* __restrict__ Mv, int rows,
                             float* __restrict__ partials,
                             const int* __restrict__ modep, int fixed) {
  const int mode = fixed >= 0 ? fixed : *modep;
  const int c    = threadIdx.x % COLS;
  const int rsub = threadIdx.x / COLS;
  const int RPB  = blockDim.x / COLS;
  float s = 0.f, q = 0.f;
  for (long r = (long)blockIdx.x * RPB + rsub; r < rows;
       r += (long)gridDim.x * RPB) {
    float v = loadf(Mv, r * COLS + c, mode);
    s += v; q += v * v;
  }
  __shared__ float sm1[256], sm2[256];
  sm1[threadIdx.x] = s; sm2[threadIdx.x] = q;
  __syncthreads();
  if (rsub == 0) {
    for (int i = 1; i < RPB; i++) { s += sm1[i * COLS + c]; q += sm2[i * COLS + c]; }
    partials[blockIdx.x * 2 * COLS + c]        = s;
    partials[blockIdx.x * 2 * COLS + COLS + c] = q;
  }
}

// stats of gathered x[row[e]] over edges (cols 0..31 of h0)
__global__ void gather_stats_kernel(const void* __restrict__ x,
                                    const int* __restrict__ rowidx, int E,
                                    float* __restrict__ partials,
                                    const int* __restrict__ modep) {
  const int mode = *modep;
  const int c    = threadIdx.x & 31;
  const int esub = threadIdx.x >> 5;  // 0..7
  float s = 0.f, q = 0.f;
  for (long e = (long)blockIdx.x * 8 + esub; e < E; e += (long)gridDim.x * 8) {
    int src = rowidx[e];
    float v = loadf(x, (long)src * 32 + c, mode);
    s += v; q += v * v;
  }
  __shared__ float sm1[256], sm2[256];
  sm1[threadIdx.x] = s; sm2[threadIdx.x] = q;
  __syncthreads();
  if (esub == 0) {
    for (int i = 1; i < 8; i++) { s += sm1[i * 32 + c]; q += sm2[i * 32 + c]; }
    partials[blockIdx.x * 64 + c]      = s;
    partials[blockIdx.x * 64 + 32 + c] = q;
  }
}

// ---------------- fold: reduce partials -> BN scale/offset -> packed W + bias
// Wpack layout: [(t*H + h)*64 + lane]*8 + j, k = h*32 + (lane>>4)*8 + j,
//               n = t*16 + (lane&15).
__global__ void fold_kernel(const float* __restrict__ pa, int pa_cols,
                            const float* __restrict__ pb, int pb_cols,
                            int P, float inv_rows,
                            const void* __restrict__ g, const void* __restrict__ b,
                            const void* __restrict__ W, const void* __restrict__ c,
                            int K, int OUT,
                            u16* __restrict__ Wpack, float* __restrict__ biasOut,
                            const int* __restrict__ modep) {
  const int mode = *modep;
  __shared__ float s_s[96], s_off[96];
  const int tid = threadIdx.x;
  for (int k = tid; k < K; k += blockDim.x) {
    float sum = 0.f, sq = 0.f;
    if (k < pa_cols) {
      for (int p = 0; p < P; p++) {
        sum += pa[p * 2 * pa_cols + k];
        sq  += pa[p * 2 * pa_cols + pa_cols + k];
      }
    } else {
      int kk = k - pa_cols;
      for (int p = 0; p < P; p++) {
        sum += pb[p * 2 * pb_cols + kk];
        sq  += pb[p * 2 * pb_cols + pb_cols + kk];
      }
    }
    float m   = sum * inv_rows;
    float var = sq * inv_rows - m * m;
    float s   = loadf(g, k, mode) * rsqrtf(var + 1e-5f);
    s_s[k]   = s;
    s_off[k] = loadf(b, k, mode) - m * s;
  }
  __syncthreads();
  for (int n = tid; n < OUT; n += blockDim.x) {
    float acc = loadf(c, n, mode);
    for (int k = 0; k < K; k++) acc += s_off[k] * loadf(W, k * OUT + n, mode);
    biasOut[n] = acc;
  }
  const int H = K / 32, T = OUT / 16;
  const int total = T * H * 64 * 8;
  for (int i = tid; i < total; i += blockDim.x) {
    int j = i & 7, lane = (i >> 3) & 63, th = i >> 9;
    int h = th % H, t = th / H;
    int k = h * 32 + (lane >> 4) * 8 + j;
    int n = t * 16 + (lane & 15);
    Wpack[i] = f2bf(s_s[k] * loadf(W, k * OUT + n, mode));
  }
}

// ---------------- GEMM 1: A = [x[row[e]], ea[e]]  (K=64 -> 64), LReLU
__global__ __launch_bounds__(256) void gemm1_kernel(
    const void* __restrict__ x, const void* __restrict__ ea,
    const int* __restrict__ erow, const u16* __restrict__ Wp,
    const float* __restrict__ bias, u16* __restrict__ hout, int E,
    const int* __restrict__ modep) {
  const int mode = *modep;
  const int lane = threadIdx.x & 63, wave = threadIdx.x >> 6;
  const int q = lane >> 4, r = lane & 15;
  const long rowbase = (long)blockIdx.x * 64 + wave * 16;
  bf16x8 bfr[4][2];
#pragma unroll
  for (int t = 0; t < 4; t++)
#pragma unroll
    for (int h = 0; h < 2; h++)
      bfr[t][h] = ldb8(Wp + ((t * 2 + h) * 64 + lane) * 8);
  long e = rowbase + r; if (e > E - 1) e = E - 1;
  int src = erow[e];
  bf16x8 a0 = load8(x, (long)src * 32 + q * 8, mode);
  bf16x8 a1 = load8(ea, e * 32 + q * 8, mode);
  floatx4 acc[4];
#pragma unroll
  for (int t = 0; t < 4; t++) {
    float bv = bias[t * 16 + r];
    acc[t] = (floatx4){bv, bv, bv, bv};
    acc[t] = mfma16(a0, bfr[t][0], acc[t]);
    acc[t] = mfma16(a1, bfr[t][1], acc[t]);
  }
#pragma unroll
  for (int t = 0; t < 4; t++)
#pragma unroll
    for (int gi = 0; gi < 4; gi++) {
      long row = rowbase + q * 4 + gi;
      if (row < E) {
        float v = acc[t][gi];
        v = v > 0.f ? v : 0.1f * v;
        hout[row * 64 + t * 16 + r] = f2bf(v);
      }
    }
}

// ---------------- GEMM 2: h[E,64] -> h[E,64] in place, LReLU
__global__ __launch_bounds__(256) void gemm2_kernel(
    const u16* __restrict__ hin, const u16* __restrict__ Wp,
    const float* __restrict__ bias, u16* __restrict__ hout, int E) {
  const int lane = threadIdx.x & 63, wave = threadIdx.x >> 6;
  const int q = lane >> 4, r = lane & 15;
  const long rowbase = (long)blockIdx.x * 64 + wave * 16;
  bf16x8 bfr[4][2];
#pragma unroll
  for (int t = 0; t < 4; t++)
#pragma unroll
    for (int h = 0; h < 2; h++)
      bfr[t][h] = ldb8(Wp + ((t * 2 + h) * 64 + lane) * 8);
  long e = rowbase + r; if (e > E - 1) e = E - 1;
  bf16x8 a0 = ldb8(hin + e * 64 + q * 8);
  bf16x8 a1 = ldb8(hin + e * 64 + 32 + q * 8);
  floatx4 acc[4];
#pragma unroll
  for (int t = 0; t < 4; t++) {
    float bv = bias[t * 16 + r];
    acc[t] = (floatx4){bv, bv, bv, bv};
    acc[t] = mfma16(a0, bfr[t][0], acc[t]);
    acc[t] = mfma16(a1, bfr[t][1], acc[t]);
  }
#pragma unroll
  for (int t = 0; t < 4; t++)
#pragma unroll
    for (int gi = 0; gi < 4; gi++) {
      long row = rowbase + q * 4 + gi;
      if (row < E) {
        float v = acc[t][gi];
        v = v > 0.f ? v : 0.1f * v;
        hout[row * 64 + t * 16 + r] = f2bf(v);
      }
    }
}

// ---------------- GEMM 3: h[E,64] -> scatter atomicAdd into agg[N,64] (no act)
__global__ __launch_bounds__(256) void gemm3_kernel(
    const u16* __restrict__ hin, const u16* __restrict__ Wp,
    const float* __restrict__ bias, const int* __restrict__ ecol,
    float* __restrict__ agg, int E) {
  const int lane = threadIdx.x & 63, wave = threadIdx.x >> 6;
  const int q = lane >> 4, r = lane & 15;
  const long rowbase = (long)blockIdx.x * 64 + wave * 16;
  bf16x8 bfr[4][2];
#pragma unroll
  for (int t = 0; t < 4; t++)
#pragma unroll
    for (int h = 0; h < 2; h++)
      bfr[t][h] = ldb8(Wp + ((t * 2 + h) * 64 + lane) * 8);
  long e = rowbase + r; if (e > E - 1) e = E - 1;
  bf16x8 a0 = ldb8(hin + e * 64 + q * 8);
  bf16x8 a1 = ldb8(hin + e * 64 + 32 + q * 8);
  floatx4 acc[4];
#pragma unroll
  for (int t = 0; t < 4; t++) {
    float bv = bias[t * 16 + r];
    acc[t] = (floatx4){bv, bv, bv, bv};
    acc[t] = mfma16(a0, bfr[t][0], acc[t]);
    acc[t] = mfma16(a1, bfr[t][1], acc[t]);
  }
#pragma unroll
  for (int gi = 0; gi < 4; gi++) {
    long row = rowbase + q * 4 + gi;
    if (row < E) {
      int node = ecol[row];
      float* dst = agg + (long)node * 64;
#pragma unroll
      for (int t = 0; t < 4; t++) atomicAdd(dst + t * 16 + r, acc[t][gi]);
    }
  }
}

// ---------------- GEMM B1: A = [x, agg(fp32)] (K=96 -> 96), LReLU
__global__ __launch_bounds__(256) void gemmB1_kernel(
    const void* __restrict__ x, const float* __restrict__ agg,
    const u16* __restrict__ Wp, const float* __restrict__ bias,
    u16* __restrict__ hout, int N, const int* __restrict__ modep) {
  const int mode = *modep;
  const int lane = threadIdx.x & 63, wave = threadIdx.x >> 6;
  const int q = lane >> 4, r = lane & 15;
  const long rowbase = (long)blockIdx.x * 64 + wave * 16;
  bf16x8 bfr[6][3];
#pragma unroll
  for (int t = 0; t < 6; t++)
#pragma unroll
    for (int h = 0; h < 3; h++)
      bfr[t][h] = ldb8(Wp + ((t * 3 + h) * 64 + lane) * 8);
  long m = rowbase + r;
  long mm = m < N ? m : (long)N - 1;
  bf16x8 a0 = load8(x, mm * 32 + q * 8, mode);
  bf16x8 a1, a2;
  {
    const float* ap = agg + mm * 64 + q * 8;
#pragma unroll
    for (int j = 0; j < 8; j++) a1[j] = (__bf16)ap[j];
#pragma unroll
    for (int j = 0; j < 8; j++) a2[j] = (__bf16)ap[32 + j];
  }
  floatx4 acc[6];
#pragma unroll
  for (int t = 0; t < 6; t++) {
    float bv = bias[t * 16 + r];
    acc[t] = (floatx4){bv, bv, bv, bv};
    acc[t] = mfma16(a0, bfr[t][0], acc[t]);
    acc[t] = mfma16(a1, bfr[t][1], acc[t]);
    acc[t] = mfma16(a2, bfr[t][2], acc[t]);
  }
#pragma unroll
  for (int t = 0; t < 6; t++)
#pragma unroll
    for (int gi = 0; gi < 4; gi++) {
      long row = rowbase + q * 4 + gi;
      if (row < N) {
        float v = acc[t][gi];
        v = v > 0.f ? v : 0.1f * v;
        hout[row * 96 + t * 16 + r] = f2bf(v);
      }
    }
}

// ---------------- GEMM B2: h[N,96] -> h[N,96] in place, LReLU
__global__ __launch_bounds__(256) void gemmB2_kernel(
    const u16* __restrict__ hin, const u16* __restrict__ Wp,
    const float* __restrict__ bias, u16* __restrict__ hout, int N) {
  const int lane = threadIdx.x & 63, wave = threadIdx.x >> 6;
  const int q = lane >> 4, r = lane & 15;
  const long rowbase = (long)blockIdx.x * 64 + wave * 16;
  bf16x8 bfr[6][3];
#pragma unroll
  for (int t = 0; t < 6; t++)
#pragma unroll
    for (int h = 0; h < 3; h++)
      bfr[t][h] = ldb8(Wp + ((t * 3 + h) * 64 + lane) * 8);
  long m = rowbase + r;
  long mm = m < N ? m : (long)N - 1;
  bf16x8 a0 = ldb8(hin + mm * 96 + q * 8);
  bf16x8 a1 = ldb8(hin + mm * 96 + 32 + q * 8);
  bf16x8 a2 = ldb8(hin + mm * 96 + 64 + q * 8);
  floatx4 acc[6];
#pragma unroll
  for (int t = 0; t < 6; t++) {
    float bv = bias[t * 16 + r];
    acc[t] = (floatx4){bv, bv, bv, bv};
    acc[t] = mfma16(a0, bfr[t][0], acc[t]);
    acc[t] = mfma16(a1, bfr[t][1], acc[t]);
    acc[t] = mfma16(a2, bfr[t][2], acc[t]);
  }
#pragma unroll
  for (int t = 0; t < 6; t++)
#pragma unroll
    for (int gi = 0; gi < 4; gi++) {
      long row = rowbase + q * 4 + gi;
      if (row < N) {
        float v = acc[t][gi];
        v = v > 0.f ? v : 0.1f * v;
        hout[row * 96 + t * 16 + r] = f2bf(v);
      }
    }
}

// ---------------- GEMM B3: h[N,96] -> out[N,32], no activation
__global__ __launch_bounds__(256) void gemmB3_kernel(
    const u16* __restrict__ hin, const u16* __restrict__ Wp,
    const float* __restrict__ bias, void* __restrict__ outv, int N,
    const int* __restrict__ modep) {
  const int mode = *modep;
  const int lane = threadIdx.x & 63, wave = threadIdx.x >> 6;
  const int q = lane >> 4, r = lane & 15;
  const long rowbase = (long)blockIdx.x * 64 + wave * 16;
  bf16x8 bfr[2][3];
#pragma unroll
  for (int t = 0; t < 2; t++)
#pragma unroll
    for (int h = 0; h < 3; h++)
      bfr[t][h] = ldb8(Wp + ((t * 3 + h) * 64 + lane) * 8);
  long m = rowbase + r;
  long mm = m < N ? m : (long)N - 1;
  bf16x8 a0 = ldb8(hin + mm * 96 + q * 8);
  bf16x8 a1 = ldb8(hin + mm * 96 + 32 + q * 8);
  bf16x8 a2 = ldb8(hin + mm * 96 + 64 + q * 8);
  floatx4 acc[2];
#pragma unroll
  for (int t = 0; t < 2; t++) {
    float bv = bias[t * 16 + r];
    acc[t] = (floatx4){bv, bv, bv, bv};
    acc[t] = mfma16(a0, bfr[t][0], acc[t]);
    acc[t] = mfma16(a1, bfr[t][1], acc[t]);
    acc[t] = mfma16(a2, bfr[t][2], acc[t]);
  }
#pragma unroll
  for (int t = 0; t < 2; t++)
#pragma unroll
    for (int gi = 0; gi < 4; gi++) {
      long row = rowbase + q * 4 + gi;
      if (row < N) {
        float v = acc[t][gi];
        if (mode) ((u16*)outv)[row * 32 + t * 16 + r] = f2bf(v);
        else      ((float*)outv)[row * 32 + t * 16 + r] = v;
      }
    }
}

// ---------------------------------------------------------------------------
extern "C" void kernel_launch(void* const* d_in, const int* in_sizes, int n_in,
                              void* d_out, int out_size, void* d_ws,
                              size_t ws_size, hipStream_t stream) {
  const int N = in_sizes[0] / 32;
  const int E = in_sizes[2] / 32;

  const void* x    = d_in[0];
  const int*  eidx = (const int*)d_in[1];  // [2][E]: row=eidx, col=eidx+E
  const void* ea   = d_in[2];
  const void *m1_g1 = d_in[5],  *m1_b1 = d_in[6];
  const void *m1_w1 = d_in[7],  *m1_c1 = d_in[8];
  const void *m1_g2 = d_in[9],  *m1_b2 = d_in[10];
  const void *m1_w2 = d_in[11], *m1_c2 = d_in[12];
  const void *m1_g3 = d_in[13], *m1_b3 = d_in[14];
  const void *m1_w3 = d_in[15], *m1_c3 = d_in[16];
  const void *m2_g1 = d_in[17], *m2_b1 = d_in[18];
  const void *m2_w1 = d_in[19], *m2_c1 = d_in[20];
  const void *m2_g2 = d_in[21], *m2_b2 = d_in[22];
  const void *m2_w2 = d_in[23], *m2_c2 = d_in[24];
  const void *m2_g3 = d_in[25], *m2_b3 = d_in[26];
  const void *m2_w3 = d_in[27], *m2_c3 = d_in[28];

  // workspace carve (all offsets multiples of 16B)
  char* w = (char*)d_ws;
  int*   modep = (int*)w;   w += 16;
  u16*   h_e   = (u16*)w;   w += (size_t)E * 64 * 2;   // 102.4 MB
  float* agg   = (float*)w; w += (size_t)N * 64 * 4;   //  25.6 MB
  u16*   h2b   = (u16*)w;   w += (size_t)N * 96 * 2;   //  19.2 MB
  float* partA = (float*)w; w += (size_t)512 * 192 * 4;
  float* partB = (float*)w; w += (size_t)512 * 192 * 4;
  u16*   Wp1   = (u16*)w;   w += 4096 * 2;
  float* bias1 = (float*)w; w += 64 * 4;
  u16*   Wp2   = (u16*)w;   w += 4096 * 2;
  float* bias2 = (float*)w; w += 64 * 4;
  u16*   Wp3   = (u16*)w;   w += 4096 * 2;
  float* bias3 = (float*)w; w += 64 * 4;
  u16*   WpB1  = (u16*)w;   w += 9216 * 2;
  float* biasB1= (float*)w; w += 96 * 4;
  u16*   WpB2  = (u16*)w;   w += 9216 * 2;
  float* biasB2= (float*)w; w += 96 * 4;
  u16*   WpB3  = (u16*)w;   w += 3072 * 2;
  float* biasB3= (float*)w; w += 32 * 4;

  const int P = 512;
  const float invE = 1.0f / (float)E, invN = 1.0f / (float)N;
  const int gE = (E + 63) / 64, gN = (N + 63) / 64;

  detect_kernel<<<1, 256, 0, stream>>>((const u16*)x, modep);
  hipMemsetAsync(agg, 0, (size_t)N * 64 * 4, stream);

  // --- phase A: edge MLP ---
  gather_stats_kernel<<<P, 256, 0, stream>>>(x, eidx, E, partA, modep);
  stats_kernel<32><<<P, 256, 0, stream>>>(ea, E, partB, modep, -1);
  fold_kernel<<<1, 256, 0, stream>>>(partA, 32, partB, 32, P, invE,
                                     m1_g1, m1_b1, m1_w1, m1_c1, 64, 64,
                                     Wp1, bias1, modep);
  gemm1_kernel<<<gE, 256, 0, stream>>>(x, ea, eidx, Wp1, bias1, h_e, E, modep);

  stats_kernel<64><<<P, 256, 0, stream>>>(h_e, E, partA, modep, 1);
  fold_kernel<<<1, 256, 0, stream>>>(partA, 64, nullptr, 1, P, invE,
                                     m1_g2, m1_b2, m1_w2, m1_c2, 64, 64,
                                     Wp2, bias2, modep);
  gemm2_kernel<<<gE, 256, 0, stream>>>(h_e, Wp2, bias2, h_e, E);

  stats_kernel<64><<<P, 256, 0, stream>>>(h_e, E, partA, modep, 1);
  fold_kernel<<<1, 256, 0, stream>>>(partA, 64, nullptr, 1, P, invE,
                                     m1_g3, m1_b3, m1_w3, m1_c3, 64, 64,
                                     Wp3, bias3, modep);
  gemm3_kernel<<<gE, 256, 0, stream>>>(h_e, Wp3, bias3, eidx + E, agg, E);

  // --- phase B: node MLP ---
  stats_kernel<32><<<P, 256, 0, stream>>>(x, N, partA, modep, -1);
  stats_kernel<64><<<P, 256, 0, stream>>>(agg, N, partB, modep, 0);
  fold_kernel<<<1, 256, 0, stream>>>(partA, 32, partB, 64, P, invN,
                                     m2_g1, m2_b1, m2_w1, m2_c1, 96, 96,
                                     WpB1, biasB1, modep);
  gemmB1_kernel<<<gN, 256, 0, stream>>>(x, agg, WpB1, biasB1, h2b, N, modep);

  stats_kernel<96><<<P, 192, 0, stream>>>(h2b, N, partA, modep, 1);
  fold_kernel<<<1, 256, 0, stream>>>(partA, 96, nullptr, 1, P, invN,
                                     m2_g2, m2_b2, m2_w2, m2_c2, 96, 96,
                                     WpB2, biasB2, modep);
  gemmB2_kernel<<<gN, 256, 0, stream>>>(h2b, WpB2, biasB2, h2b, N);

  stats_kernel<96><<<P, 192, 0, stream>>>(h2b, N, partA, modep, 1);
  fold_kernel<<<1, 256, 0, stream>>>(partA, 96, nullptr, 1, P, invN,
                                     m2_g3, m2_b3, m2_w3, m2_c3, 96, 32,
                                     WpB3, biasB3, modep);
  gemmB3_kernel<<<gN, 256, 0, stream>>>(h2b, WpB3, biasB3, d_out, N, modep);
}

// Round 3
// 948.374 us; speedup vs baseline: 2.4482x; 2.4482x over previous
//
#include <hip/hip_runtime.h>

// ---------------------------------------------------------------------------
// NodeModel (GraphNet node block), MI355X / gfx950.
// v3: stats fused into GEMM epilogues (binned global atomics), trivial folds,
// 4 row-tiles per wave in all GEMMs. Remaining big cost: gemm3 atomic scatter.
// MFMA layouts (verified): A[m=lane&15][k=(lane>>4)*8+j],
//   B[k=(lane>>4)*8+j][n=lane&15], C/D: col=lane&15, row=(lane>>4)*4+reg.
// Input dtype (fp32 vs bf16 harness mode) detected at runtime.
// ---------------------------------------------------------------------------

typedef unsigned short u16;
typedef __bf16  bf16x8  __attribute__((ext_vector_type(8)));
typedef float   floatx4 __attribute__((ext_vector_type(4)));

#define NBIN 8

__device__ __forceinline__ float bf2f(u16 u) {
  union { float f; unsigned int i; } v; v.i = ((unsigned int)u) << 16; return v.f;
}
__device__ __forceinline__ u16 f2bf(float f) {
  union { float f; unsigned int i; } v; v.f = f;
  unsigned int x = v.i;
  return (u16)((x + 0x7fffu + ((x >> 16) & 1u)) >> 16);  // RNE
}
__device__ __forceinline__ bf16x8 ldb8(const u16* p) {
  return *reinterpret_cast<const bf16x8*>(p);
}
__device__ __forceinline__ floatx4 mfma16(bf16x8 a, bf16x8 b, floatx4 c) {
  return __builtin_amdgcn_mfma_f32_16x16x32_bf16(a, b, c, 0, 0, 0);
}
// mode: 0 = input is float32, 1 = input is bf16
__device__ __forceinline__ float loadf(const void* p, long idx, int mode) {
  return mode ? bf2f(((const u16*)p)[idx]) : ((const float*)p)[idx];
}
__device__ __forceinline__ bf16x8 load8(const void* p, long idx, int mode) {
  if (mode) return ldb8((const u16*)p + idx);
  const float* f = (const float*)p + idx;
  bf16x8 r;
#pragma unroll
  for (int j = 0; j < 8; j++) r[j] = (__bf16)f[j];
  return r;
}

// ---------------- dtype detection
__global__ void detect_kernel(const u16* __restrict__ x, int* __restrict__ modep) {
  __shared__ int cnt;
  if (threadIdx.x == 0) cnt = 0;
  __syncthreads();
  int weird = 0;
  for (int i = threadIdx.x; i < 1024; i += blockDim.x) {
    unsigned e = (x[i] >> 7) & 0xFFu;
    if (e == 0xFFu || e >= 0x90u || (e != 0u && e < 0x60u)) weird++;
  }
  atomicAdd(&cnt, weird);
  __syncthreads();
  if (threadIdx.x == 0) *modep = (cnt > 128) ? 0 : 1;
}

// ---------------- stats of h0 = [x[row[e]], ea[e]]  -> stats0[NBIN][128]
__global__ void stats0_kernel(const void* __restrict__ x, const void* __restrict__ ea,
                              const int* __restrict__ erow, int E,
                              float* __restrict__ stats, const int* __restrict__ modep) {
  const int mode = *modep;
  const int c = threadIdx.x & 63, es = threadIdx.x >> 6;  // 4 edges / block-iter
  float s = 0.f, q = 0.f;
  for (long e = (long)blockIdx.x * 4 + es; e < E; e += (long)gridDim.x * 4) {
    float v;
    if (c < 32) { int src = erow[e]; v = loadf(x, (long)src * 32 + c, mode); }
    else        { v = loadf(ea, e * 32 + (c - 32), mode); }
    s += v; q += v * v;
  }
  __shared__ float sm1[256], sm2[256];
  sm1[threadIdx.x] = s; sm2[threadIdx.x] = q;
  __syncthreads();
  if (es == 0) {
    for (int i = 1; i < 4; i++) { s += sm1[i * 64 + c]; q += sm2[i * 64 + c]; }
    float* o = stats + (blockIdx.x & (NBIN - 1)) * 128;
    atomicAdd(o + c, s); atomicAdd(o + 64 + c, q);
  }
}

// ---------------- stats of [x, agg] over N rows -> statsB0[NBIN][192]
__global__ void statsB0_kernel(const void* __restrict__ x, const float* __restrict__ agg,
                               int N, float* __restrict__ stats,
                               const int* __restrict__ modep) {
  const int mode = *modep;
  const int c = threadIdx.x % 96, rs = threadIdx.x / 96;  // blockDim = 192
  float s = 0.f, q = 0.f;
  for (long r = (long)blockIdx.x * 2 + rs; r < N; r += (long)gridDim.x * 2) {
    float v = (c < 32) ? loadf(x, r * 32 + c, mode) : agg[r * 64 + (c - 32)];
    s += v; q += v * v;
  }
  __shared__ float sm1[192], sm2[192];
  sm1[threadIdx.x] = s; sm2[threadIdx.x] = q;
  __syncthreads();
  if (rs == 0) {
    s += sm1[96 + c]; q += sm2[96 + c];
    float* o = stats + (blockIdx.x & (NBIN - 1)) * 192;
    atomicAdd(o + c, s); atomicAdd(o + 96 + c, q);
  }
}

// ---------------- fold: binned stats -> BN scale/offset -> packed W + bias
__global__ void fold_kernel(const float* __restrict__ stats, float inv_rows,
                            const void* __restrict__ g, const void* __restrict__ b,
                            const void* __restrict__ W, const void* __restrict__ c,
                            int K, int OUT,
                            u16* __restrict__ Wpack, float* __restrict__ biasOut,
                            const int* __restrict__ modep) {
  const int mode = *modep;
  __shared__ float s_s[96], s_off[96];
  const int tid = threadIdx.x;
  if (tid < K) {
    float sum = 0.f, sq = 0.f;
    for (int p = 0; p < NBIN; p++) {
      sum += stats[p * 2 * K + tid];
      sq  += stats[p * 2 * K + K + tid];
    }
    float m   = sum * inv_rows;
    float var = sq * inv_rows - m * m;
    float s   = loadf(g, tid, mode) * rsqrtf(var + 1e-5f);
    s_s[tid]  = s;
    s_off[tid] = loadf(b, tid, mode) - m * s;
  }
  __syncthreads();
  for (int n = tid; n < OUT; n += blockDim.x) {
    float acc = loadf(c, n, mode);
    for (int k = 0; k < K; k++) acc += s_off[k] * loadf(W, k * OUT + n, mode);
    biasOut[n] = acc;
  }
  const int H = K / 32, T = OUT / 16;
  const int total = T * H * 64 * 8;
  for (int i = tid; i < total; i += blockDim.x) {
    int j = i & 7, lane = (i >> 3) & 63, th = i >> 9;
    int h = th % H, t = th / H;
    int k = h * 32 + (lane >> 4) * 8 + j;
    int n = t * 16 + (lane & 15);
    Wpack[i] = f2bf(s_s[k] * loadf(W, k * OUT + n, mode));
  }
}

// ======== phase-A GEMMs: 64 cols, K=64, 256 rows/block (4 tiles/wave) =======

// GEMM 1: A = [x[row[e]], ea[e]], LReLU, epilogue stats -> statsOut[NBIN][128]
__global__ __launch_bounds__(256) void gemm1_kernel(
    const void* __restrict__ x, const void* __restrict__ ea,
    const int* __restrict__ erow, const u16* __restrict__ Wp,
    const float* __restrict__ bias, u16* __restrict__ hout, int E,
    float* __restrict__ statsOut, const int* __restrict__ modep) {
  const int mode = *modep;
  const int lane = threadIdx.x & 63, wave = threadIdx.x >> 6;
  const int q = lane >> 4, r = lane & 15;
  const long wbase = (long)blockIdx.x * 256 + wave * 64;
  bf16x8 bfr[4][2];
#pragma unroll
  for (int t = 0; t < 4; t++)
#pragma unroll
    for (int h = 0; h < 2; h++)
      bfr[t][h] = ldb8(Wp + ((t * 2 + h) * 64 + lane) * 8);
  float bv[4];
#pragma unroll
  for (int t = 0; t < 4; t++) bv[t] = bias[t * 16 + r];
  float s_[4] = {0, 0, 0, 0}, q_[4] = {0, 0, 0, 0};
#pragma unroll
  for (int r4 = 0; r4 < 4; r4++) {
    const long row0 = wbase + r4 * 16;
    long e = row0 + r; if (e > E - 1) e = E - 1;
    int src = erow[e];
    bf16x8 a0 = load8(x, (long)src * 32 + q * 8, mode);
    bf16x8 a1 = load8(ea, e * 32 + q * 8, mode);
    floatx4 acc[4];
#pragma unroll
    for (int t = 0; t < 4; t++) {
      acc[t] = (floatx4){bv[t], bv[t], bv[t], bv[t]};
      acc[t] = mfma16(a0, bfr[t][0], acc[t]);
      acc[t] = mfma16(a1, bfr[t][1], acc[t]);
    }
#pragma unroll
    for (int t = 0; t < 4; t++)
#pragma unroll
      for (int gi = 0; gi < 4; gi++) {
        long row = row0 + q * 4 + gi;
        if (row < E) {
          float v = acc[t][gi];
          v = v > 0.f ? v : 0.1f * v;
          u16 st = f2bf(v);
          hout[row * 64 + t * 16 + r] = st;
          float vv = bf2f(st);
          s_[t] += vv; q_[t] += vv * vv;
        }
      }
  }
  __shared__ float sm[512];
#pragma unroll
  for (int t = 0; t < 4; t++) {
    float s = s_[t], qq = q_[t];
    s  += __shfl_xor(s, 16, 64);  s  += __shfl_xor(s, 32, 64);
    qq += __shfl_xor(qq, 16, 64); qq += __shfl_xor(qq, 32, 64);
    if (lane < 16) { sm[wave * 128 + t * 16 + lane] = s; sm[wave * 128 + 64 + t * 16 + lane] = qq; }
  }
  __syncthreads();
  if (threadIdx.x < 128) {
    int which = threadIdx.x >> 6, c = threadIdx.x & 63;
    float v = 0.f;
    for (int w = 0; w < 4; w++) v += sm[w * 128 + which * 64 + c];
    atomicAdd(statsOut + (blockIdx.x & (NBIN - 1)) * 128 + which * 64 + c, v);
  }
}

// GEMM 2: h[E,64] -> h[E,64] in place, LReLU, epilogue stats
__global__ __launch_bounds__(256) void gemm2_kernel(
    const u16* __restrict__ hin, const u16* __restrict__ Wp,
    const float* __restrict__ bias, u16* __restrict__ hout, int E,
    float* __restrict__ statsOut) {
  const int lane = threadIdx.x & 63, wave = threadIdx.x >> 6;
  const int q = lane >> 4, r = lane & 15;
  const long wbase = (long)blockIdx.x * 256 + wave * 64;
  bf16x8 bfr[4][2];
#pragma unroll
  for (int t = 0; t < 4; t++)
#pragma unroll
    for (int h = 0; h < 2; h++)
      bfr[t][h] = ldb8(Wp + ((t * 2 + h) * 64 + lane) * 8);
  float bv[4];
#pragma unroll
  for (int t = 0; t < 4; t++) bv[t] = bias[t * 16 + r];
  float s_[4] = {0, 0, 0, 0}, q_[4] = {0, 0, 0, 0};
#pragma unroll
  for (int r4 = 0; r4 < 4; r4++) {
    const long row0 = wbase + r4 * 16;
    long e = row0 + r; if (e > E - 1) e = E - 1;
    bf16x8 a0 = ldb8(hin + e * 64 + q * 8);
    bf16x8 a1 = ldb8(hin + e * 64 + 32 + q * 8);
    floatx4 acc[4];
#pragma unroll
    for (int t = 0; t < 4; t++) {
      acc[t] = (floatx4){bv[t], bv[t], bv[t], bv[t]};
      acc[t] = mfma16(a0, bfr[t][0], acc[t]);
      acc[t] = mfma16(a1, bfr[t][1], acc[t]);
    }
#pragma unroll
    for (int t = 0; t < 4; t++)
#pragma unroll
      for (int gi = 0; gi < 4; gi++) {
        long row = row0 + q * 4 + gi;
        if (row < E) {
          float v = acc[t][gi];
          v = v > 0.f ? v : 0.1f * v;
          u16 st = f2bf(v);
          hout[row * 64 + t * 16 + r] = st;
          float vv = bf2f(st);
          s_[t] += vv; q_[t] += vv * vv;
        }
      }
  }
  __shared__ float sm[512];
#pragma unroll
  for (int t = 0; t < 4; t++) {
    float s = s_[t], qq = q_[t];
    s  += __shfl_xor(s, 16, 64);  s  += __shfl_xor(s, 32, 64);
    qq += __shfl_xor(qq, 16, 64); qq += __shfl_xor(qq, 32, 64);
    if (lane < 16) { sm[wave * 128 + t * 16 + lane] = s; sm[wave * 128 + 64 + t * 16 + lane] = qq; }
  }
  __syncthreads();
  if (threadIdx.x < 128) {
    int which = threadIdx.x >> 6, c = threadIdx.x & 63;
    float v = 0.f;
    for (int w = 0; w < 4; w++) v += sm[w * 128 + which * 64 + c];
    atomicAdd(statsOut + (blockIdx.x & (NBIN - 1)) * 128 + which * 64 + c, v);
  }
}

// GEMM 3: h[E,64] -> scatter atomicAdd into agg[N,64] (no act, no stats)
__global__ __launch_bounds__(256) void gemm3_kernel(
    const u16* __restrict__ hin, const u16* __restrict__ Wp,
    const float* __restrict__ bias, const int* __restrict__ ecol,
    float* __restrict__ agg, int E) {
  const int lane = threadIdx.x & 63, wave = threadIdx.x >> 6;
  const int q = lane >> 4, r = lane & 15;
  const long wbase = (long)blockIdx.x * 256 + wave * 64;
  bf16x8 bfr[4][2];
#pragma unroll
  for (int t = 0; t < 4; t++)
#pragma unroll
    for (int h = 0; h < 2; h++)
      bfr[t][h] = ldb8(Wp + ((t * 2 + h) * 64 + lane) * 8);
  float bv[4];
#pragma unroll
  for (int t = 0; t < 4; t++) bv[t] = bias[t * 16 + r];
#pragma unroll
  for (int r4 = 0; r4 < 4; r4++) {
    const long row0 = wbase + r4 * 16;
    long e = row0 + r; if (e > E - 1) e = E - 1;
    bf16x8 a0 = ldb8(hin + e * 64 + q * 8);
    bf16x8 a1 = ldb8(hin + e * 64 + 32 + q * 8);
    floatx4 acc[4];
#pragma unroll
    for (int t = 0; t < 4; t++) {
      acc[t] = (floatx4){bv[t], bv[t], bv[t], bv[t]};
      acc[t] = mfma16(a0, bfr[t][0], acc[t]);
      acc[t] = mfma16(a1, bfr[t][1], acc[t]);
    }
#pragma unroll
    for (int gi = 0; gi < 4; gi++) {
      long row = row0 + q * 4 + gi;
      if (row < E) {
        int node = ecol[row];
        float* dst = agg + (long)node * 64;
#pragma unroll
        for (int t = 0; t < 4; t++) atomicAdd(dst + t * 16 + r, acc[t][gi]);
      }
    }
  }
}

// ======== phase-B GEMMs: 96-wide, 256 rows/block (4 tiles/wave) =============

// GEMM B1: A = [x, agg(fp32)] (K=96 -> 96), LReLU, stats -> statsOut[NBIN][192]
__global__ __launch_bounds__(256) void gemmB1_kernel(
    const void* __restrict__ x, const float* __restrict__ agg,
    const u16* __restrict__ Wp, const float* __restrict__ bias,
    u16* __restrict__ hout, int N, float* __restrict__ statsOut,
    const int* __restrict__ modep) {
  const int mode = *modep;
  const int lane = threadIdx.x & 63, wave = threadIdx.x >> 6;
  const int q = lane >> 4, r = lane & 15;
  const long wbase = (long)blockIdx.x * 256 + wave * 64;
  bf16x8 bfr[6][3];
#pragma unroll
  for (int t = 0; t < 6; t++)
#pragma unroll
    for (int h = 0; h < 3; h++)
      bfr[t][h] = ldb8(Wp + ((t * 3 + h) * 64 + lane) * 8);
  float bv[6];
#pragma unroll
  for (int t = 0; t < 6; t++) bv[t] = bias[t * 16 + r];
  float s_[6] = {0, 0, 0, 0, 0, 0}, q_[6] = {0, 0, 0, 0, 0, 0};
#pragma unroll
  for (int r4 = 0; r4 < 4; r4++) {
    const long row0 = wbase + r4 * 16;
    long m = row0 + r;
    long mm = m < N ? m : (long)N - 1;
    bf16x8 a0 = load8(x, mm * 32 + q * 8, mode);
    bf16x8 a1, a2;
    {
      const float* ap = agg + mm * 64 + q * 8;
#pragma unroll
      for (int j = 0; j < 8; j++) a1[j] = (__bf16)ap[j];
#pragma unroll
      for (int j = 0; j < 8; j++) a2[j] = (__bf16)ap[32 + j];
    }
    floatx4 acc[6];
#pragma unroll
    for (int t = 0; t < 6; t++) {
      acc[t] = (floatx4){bv[t], bv[t], bv[t], bv[t]};
      acc[t] = mfma16(a0, bfr[t][0], acc[t]);
      acc[t] = mfma16(a1, bfr[t][1], acc[t]);
      acc[t] = mfma16(a2, bfr[t][2], acc[t]);
    }
#pragma unroll
    for (int t = 0; t < 6; t++)
#pragma unroll
      for (int gi = 0; gi < 4; gi++) {
        long row = row0 + q * 4 + gi;
        if (row < N) {
          float v = acc[t][gi];
          v = v > 0.f ? v : 0.1f * v;
          u16 st = f2bf(v);
          hout[row * 96 + t * 16 + r] = st;
          float vv = bf2f(st);
          s_[t] += vv; q_[t] += vv * vv;
        }
      }
  }
  __shared__ float sm[768];
#pragma unroll
  for (int t = 0; t < 6; t++) {
    float s = s_[t], qq = q_[t];
    s  += __shfl_xor(s, 16, 64);  s  += __shfl_xor(s, 32, 64);
    qq += __shfl_xor(qq, 16, 64); qq += __shfl_xor(qq, 32, 64);
    if (lane < 16) { sm[wave * 192 + t * 16 + lane] = s; sm[wave * 192 + 96 + t * 16 + lane] = qq; }
  }
  __syncthreads();
  if (threadIdx.x < 192) {
    int which = threadIdx.x / 96, c = threadIdx.x % 96;
    float v = 0.f;
    for (int w = 0; w < 4; w++) v += sm[w * 192 + which * 96 + c];
    atomicAdd(statsOut + (blockIdx.x & (NBIN - 1)) * 192 + which * 96 + c, v);
  }
}

// GEMM B2: h[N,96] -> h[N,96] in place, LReLU, stats
__global__ __launch_bounds__(256) void gemmB2_kernel(
    const u16* __restrict__ hin, const u16* __restrict__ Wp,
    const float* __restrict__ bias, u16* __restrict__ hout, int N,
    float* __restrict__ statsOut) {
  const int lane = threadIdx.x & 63, wave = threadIdx.x >> 6;
  const int q = lane >> 4, r = lane & 15;
  const long wbase = (long)blockIdx.x * 256 + wave * 64;
  bf16x8 bfr[6][3];
#pragma unroll
  for (int t = 0; t < 6; t++)
#pragma unroll
    for (int h = 0; h < 3; h++)
      bfr[t][h] = ldb8(Wp + ((t * 3 + h) * 64 + lane) * 8);
  float bv[6];
#pragma unroll
  for (int t = 0; t < 6; t++) bv[t] = bias[t * 16 + r];
  float s_[6] = {0, 0, 0, 0, 0, 0}, q_[6] = {0, 0, 0, 0, 0, 0};
#pragma unroll
  for (int r4 = 0; r4 < 4; r4++) {
    const long row0 = wbase + r4 * 16;
    long m = row0 + r;
    long mm = m < N ? m : (long)N - 1;
    bf16x8 a0 = ldb8(hin + mm * 96 + q * 8);
    bf16x8 a1 = ldb8(hin + mm * 96 + 32 + q * 8);
    bf16x8 a2 = ldb8(hin + mm * 96 + 64 + q * 8);
    floatx4 acc[6];
#pragma unroll
    for (int t = 0; t < 6; t++) {
      acc[t] = (floatx4){bv[t], bv[t], bv[t], bv[t]};
      acc[t] = mfma16(a0, bfr[t][0], acc[t]);
      acc[t] = mfma16(a1, bfr[t][1], acc[t]);
      acc[t] = mfma16(a2, bfr[t][2], acc[t]);
    }
#pragma unroll
    for (int t = 0; t < 6; t++)
#pragma unroll
      for (int gi = 0; gi < 4; gi++) {
        long row = row0 + q * 4 + gi;
        if (row < N) {
          float v = acc[t][gi];
          v = v > 0.f ? v : 0.1f * v;
          u16 st = f2bf(v);
          hout[row * 96 + t * 16 + r] = st;
          float vv = bf2f(st);
          s_[t] += vv; q_[t] += vv * vv;
        }
      }
  }
  __shared__ float sm[768];
#pragma unroll
  for (int t = 0; t < 6; t++) {
    float s = s_[t], qq = q_[t];
    s  += __shfl_xor(s, 16, 64);  s  += __shfl_xor(s, 32, 64);
    qq += __shfl_xor(qq, 16, 64); qq += __shfl_xor(qq, 32, 64);
    if (lane < 16) { sm[wave * 192 + t * 16 + lane] = s; sm[wave * 192 + 96 + t * 16 + lane] = qq; }
  }
  __syncthreads();
  if (threadIdx.x < 192) {
    int which = threadIdx.x / 96, c = threadIdx.x % 96;
    float v = 0.f;
    for (int w = 0; w < 4; w++) v += sm[w * 192 + which * 96 + c];
    atomicAdd(statsOut + (blockIdx.x & (NBIN - 1)) * 192 + which * 96 + c, v);
  }
}

// GEMM B3: h[N,96] -> out[N,32], no activation, no stats
__global__ __launch_bounds__(256) void gemmB3_kernel(
    const u16* __restrict__ hin, const u16* __restrict__ Wp,
    const float* __restrict__ bias, void* __restrict__ outv, int N,
    const int* __restrict__ modep) {
  const int mode = *modep;
  const int lane = threadIdx.x & 63, wave = threadIdx.x >> 6;
  const int q = lane >> 4, r = lane & 15;
  const long wbase = (long)blockIdx.x * 256 + wave * 64;
  bf16x8 bfr[2][3];
#pragma unroll
  for (int t = 0; t < 2; t++)
#pragma unroll
    for (int h = 0; h < 3; h++)
      bfr[t][h] = ldb8(Wp + ((t * 3 + h) * 64 + lane) * 8);
  float bv[2];
#pragma unroll
  for (int t = 0; t < 2; t++) bv[t] = bias[t * 16 + r];
#pragma unroll
  for (int r4 = 0; r4 < 4; r4++) {
    const long row0 = wbase + r4 * 16;
    long m = row0 + r;
    long mm = m < N ? m : (long)N - 1;
    bf16x8 a0 = ldb8(hin + mm * 96 + q * 8);
    bf16x8 a1 = ldb8(hin + mm * 96 + 32 + q * 8);
    bf16x8 a2 = ldb8(hin + mm * 96 + 64 + q * 8);
    floatx4 acc[2];
#pragma unroll
    for (int t = 0; t < 2; t++) {
      acc[t] = (floatx4){bv[t], bv[t], bv[t], bv[t]};
      acc[t] = mfma16(a0, bfr[t][0], acc[t]);
      acc[t] = mfma16(a1, bfr[t][1], acc[t]);
      acc[t] = mfma16(a2, bfr[t][2], acc[t]);
    }
#pragma unroll
    for (int t = 0; t < 2; t++)
#pragma unroll
      for (int gi = 0; gi < 4; gi++) {
        long row = row0 + q * 4 + gi;
        if (row < N) {
          float v = acc[t][gi];
          if (mode) ((u16*)outv)[row * 32 + t * 16 + r] = f2bf(v);
          else      ((float*)outv)[row * 32 + t * 16 + r] = v;
        }
      }
  }
}

// ---------------------------------------------------------------------------
extern "C" void kernel_launch(void* const* d_in, const int* in_sizes, int n_in,
                              void* d_out, int out_size, void* d_ws,
                              size_t ws_size, hipStream_t stream) {
  const int N = in_sizes[0] / 32;
  const int E = in_sizes[2] / 32;

  const void* x    = d_in[0];
  const int*  eidx = (const int*)d_in[1];  // [2][E]: row=eidx, col=eidx+E
  const void* ea   = d_in[2];
  const void *m1_g1 = d_in[5],  *m1_b1 = d_in[6];
  const void *m1_w1 = d_in[7],  *m1_c1 = d_in[8];
  const void *m1_g2 = d_in[9],  *m1_b2 = d_in[10];
  const void *m1_w2 = d_in[11], *m1_c2 = d_in[12];
  const void *m1_g3 = d_in[13], *m1_b3 = d_in[14];
  const void *m1_w3 = d_in[15], *m1_c3 = d_in[16];
  const void *m2_g1 = d_in[17], *m2_b1 = d_in[18];
  const void *m2_w1 = d_in[19], *m2_c1 = d_in[20];
  const void *m2_g2 = d_in[21], *m2_b2 = d_in[22];
  const void *m2_w2 = d_in[23], *m2_c2 = d_in[24];
  const void *m2_g3 = d_in[25], *m2_b3 = d_in[26];
  const void *m2_w3 = d_in[27], *m2_c3 = d_in[28];

  // workspace carve (16B-aligned chunks)
  char* w = (char*)d_ws;
  int*   modep  = (int*)w;   w += 16;
  u16*   h_e    = (u16*)w;   w += (size_t)E * 64 * 2;   // 102.4 MB
  u16*   h2b    = (u16*)w;   w += (size_t)N * 96 * 2;   //  19.2 MB
  // zero zone: agg + all stats buffers (contiguous)
  float* agg    = (float*)w; w += (size_t)N * 64 * 4;   //  25.6 MB
  float* stats0 = (float*)w; w += NBIN * 128 * 4;
  float* stats1 = (float*)w; w += NBIN * 128 * 4;
  float* stats2 = (float*)w; w += NBIN * 128 * 4;
  float* statsB0= (float*)w; w += NBIN * 192 * 4;
  float* statsB1= (float*)w; w += NBIN * 192 * 4;
  float* statsB2= (float*)w; w += NBIN * 192 * 4;
  const size_t zero_bytes = (size_t)N * 64 * 4 + NBIN * (128 * 3 + 192 * 3) * 4;
  u16*   Wp1    = (u16*)w;   w += 4096 * 2;
  float* bias1  = (float*)w; w += 64 * 4;
  u16*   Wp2    = (u16*)w;   w += 4096 * 2;
  float* bias2  = (float*)w; w += 64 * 4;
  u16*   Wp3    = (u16*)w;   w += 4096 * 2;
  float* bias3  = (float*)w; w += 64 * 4;
  u16*   WpB1   = (u16*)w;   w += 9216 * 2;
  float* biasB1 = (float*)w; w += 96 * 4;
  u16*   WpB2   = (u16*)w;   w += 9216 * 2;
  float* biasB2 = (float*)w; w += 96 * 4;
  u16*   WpB3   = (u16*)w;   w += 3072 * 2;
  float* biasB3 = (float*)w; w += 32 * 4;

  const float invE = 1.0f / (float)E, invN = 1.0f / (float)N;
  const int gA = (E + 255) / 256, gB = (N + 255) / 256;

  detect_kernel<<<1, 256, 0, stream>>>((const u16*)x, modep);
  hipMemsetAsync(agg, 0, zero_bytes, stream);

  // --- phase A: edge MLP ---
  stats0_kernel<<<1024, 256, 0, stream>>>(x, ea, eidx, E, stats0, modep);
  fold_kernel<<<1, 256, 0, stream>>>(stats0, invE, m1_g1, m1_b1, m1_w1, m1_c1,
                                     64, 64, Wp1, bias1, modep);
  gemm1_kernel<<<gA, 256, 0, stream>>>(x, ea, eidx, Wp1, bias1, h_e, E,
                                       stats1, modep);
  fold_kernel<<<1, 256, 0, stream>>>(stats1, invE, m1_g2, m1_b2, m1_w2, m1_c2,
                                     64, 64, Wp2, bias2, modep);
  gemm2_kernel<<<gA, 256, 0, stream>>>(h_e, Wp2, bias2, h_e, E, stats2);
  fold_kernel<<<1, 256, 0, stream>>>(stats2, invE, m1_g3, m1_b3, m1_w3, m1_c3,
                                     64, 64, Wp3, bias3, modep);
  gemm3_kernel<<<gA, 256, 0, stream>>>(h_e, Wp3, bias3, eidx + E, agg, E);

  // --- phase B: node MLP ---
  statsB0_kernel<<<512, 192, 0, stream>>>(x, agg, N, statsB0, modep);
  fold_kernel<<<1, 256, 0, stream>>>(statsB0, invN, m2_g1, m2_b1, m2_w1, m2_c1,
                                     96, 96, WpB1, biasB1, modep);
  gemmB1_kernel<<<gB, 256, 0, stream>>>(x, agg, WpB1, biasB1, h2b, N,
                                        statsB1, modep);
  fold_kernel<<<1, 256, 0, stream>>>(statsB1, invN, m2_g2, m2_b2, m2_w2, m2_c2,
                                     96, 96, WpB2, biasB2, modep);
  gemmB2_kernel<<<gB, 256, 0, stream>>>(h2b, WpB2, biasB2, h2b, N, statsB2);
  fold_kernel<<<1, 256, 0, stream>>>(statsB2, invN, m2_g3, m2_b3, m2_w3, m2_c3,
                                     96, 32, WpB3, biasB3, modep);
  gemmB3_kernel<<<gB, 256, 0, stream>>>(h2b, WpB3, biasB3, d_out, N, modep);
}

// Round 4
// 859.580 us; speedup vs baseline: 2.7011x; 1.1033x over previous
//
#include <hip/hip_runtime.h>

// ---------------------------------------------------------------------------
// NodeModel (GraphNet node block), MI355X / gfx950.
// v4: atomic scatter eliminated. Since BN+Linear is affine, segment-sum
// commutes with layer 3:  agg[n] = (sum_e h_e) @ W3' + deg[n]*b3'.
// Edge IDs counting-sorted by dest -> coalesced per-node row sums (no
// atomics) -> one dense GEMM with deg-scaled bias (+fused agg stats).
// Stats for all other layers fused into GEMM epilogues (binned atomics).
// MFMA layouts (verified): A[m=lane&15][k=(lane>>4)*8+j],
//   B[k=(lane>>4)*8+j][n=lane&15], C/D: col=lane&15, row=(lane>>4)*4+reg.
// Input dtype (fp32 vs bf16 harness mode) detected at runtime.
// ---------------------------------------------------------------------------

typedef unsigned short u16;
typedef __bf16  bf16x8  __attribute__((ext_vector_type(8)));
typedef float   floatx4 __attribute__((ext_vector_type(4)));

#define NBIN 8

__device__ __forceinline__ float bf2f(u16 u) {
  union { float f; unsigned int i; } v; v.i = ((unsigned int)u) << 16; return v.f;
}
__device__ __forceinline__ u16 f2bf(float f) {
  union { float f; unsigned int i; } v; v.f = f;
  unsigned int x = v.i;
  return (u16)((x + 0x7fffu + ((x >> 16) & 1u)) >> 16);  // RNE
}
__device__ __forceinline__ bf16x8 ldb8(const u16* p) {
  return *reinterpret_cast<const bf16x8*>(p);
}
__device__ __forceinline__ floatx4 mfma16(bf16x8 a, bf16x8 b, floatx4 c) {
  return __builtin_amdgcn_mfma_f32_16x16x32_bf16(a, b, c, 0, 0, 0);
}
// mode: 0 = input is float32, 1 = input is bf16
__device__ __forceinline__ float loadf(const void* p, long idx, int mode) {
  return mode ? bf2f(((const u16*)p)[idx]) : ((const float*)p)[idx];
}
__device__ __forceinline__ bf16x8 load8(const void* p, long idx, int mode) {
  if (mode) return ldb8((const u16*)p + idx);
  const float* f = (const float*)p + idx;
  bf16x8 r;
#pragma unroll
  for (int j = 0; j < 8; j++) r[j] = (__bf16)f[j];
  return r;
}

// ---------------- dtype detection
__global__ void detect_kernel(const u16* __restrict__ x, int* __restrict__ modep) {
  __shared__ int cnt;
  if (threadIdx.x == 0) cnt = 0;
  __syncthreads();
  int weird = 0;
  for (int i = threadIdx.x; i < 1024; i += blockDim.x) {
    unsigned e = (x[i] >> 7) & 0xFFu;
    if (e == 0xFFu || e >= 0x90u || (e != 0u && e < 0x60u)) weird++;
  }
  atomicAdd(&cnt, weird);
  __syncthreads();
  if (threadIdx.x == 0) *modep = (cnt > 128) ? 0 : 1;
}

// ================= counting sort of edges by destination ====================
__global__ void count_kernel(const int* __restrict__ col, int E,
                             int* __restrict__ deg) {
  for (int e = blockIdx.x * blockDim.x + threadIdx.x; e < E;
       e += gridDim.x * blockDim.x)
    atomicAdd(&deg[col[e]], 1);
}

// per-1024-block exclusive scan; block totals to bsum
__global__ void scan1_kernel(const int* __restrict__ deg, int n,
                             int* __restrict__ excl, int* __restrict__ bsum) {
  __shared__ int tmp[2][1024];
  const int tid = threadIdx.x;
  const int i = blockIdx.x * 1024 + tid;
  int v = (i < n) ? deg[i] : 0;
  tmp[0][tid] = v;
  __syncthreads();
  int src = 0;
  for (int off = 1; off < 1024; off <<= 1) {
    int t = tmp[src][tid];
    if (tid >= off) t += tmp[src][tid - off];
    tmp[1 - src][tid] = t;
    src = 1 - src;
    __syncthreads();
  }
  if (i < n) excl[i] = tmp[src][tid] - v;
  if (tid == 1023) bsum[blockIdx.x] = tmp[src][1023];
}

__global__ void scan2_kernel(int* __restrict__ bsum, int nb,
                             int* __restrict__ offsets, int N, int E) {
  if (threadIdx.x == 0) {
    int run = 0;
    for (int i = 0; i < nb; i++) { int v = bsum[i]; bsum[i] = run; run += v; }
    offsets[N] = E;
  }
}

__global__ void scan3_kernel(int* __restrict__ offsets, const int* __restrict__ bsum,
                             int n, int* __restrict__ cursor) {
  int i = blockIdx.x * 1024 + threadIdx.x;
  if (i < n) {
    int v = offsets[i] + bsum[blockIdx.x];
    offsets[i] = v;
    cursor[i] = v;
  }
}

__global__ void scatter_kernel(const int* __restrict__ col, int E,
                               int* __restrict__ cursor, int* __restrict__ perm) {
  for (int e = blockIdx.x * blockDim.x + threadIdx.x; e < E;
       e += gridDim.x * blockDim.x) {
    int d = col[e];
    int pos = atomicAdd(&cursor[d], 1);
    perm[pos] = e;
  }
}

// ---------------- segment-sum of raw h_e rows per node (coalesced, no atomics)
__global__ __launch_bounds__(256) void aggsum_kernel(
    const u16* __restrict__ h_e, const int* __restrict__ perm,
    const int* __restrict__ offsets, float* __restrict__ s_e, int N) {
  const int lane = threadIdx.x & 63, wave = threadIdx.x >> 6;
  for (long n = (long)blockIdx.x * 4 + wave; n < N; n += (long)gridDim.x * 4) {
    int start = offsets[n], end = offsets[n + 1];
    float acc = 0.f;
    for (int j = start; j < end; j++) {
      long e = perm[j];
      acc += bf2f(h_e[e * 64 + lane]);
    }
    s_e[n * 64 + lane] = acc;
  }
}

// ---------------- stats of h0 = [x[row[e]], ea[e]]  -> stats0[NBIN][128]
__global__ void stats0_kernel(const void* __restrict__ x, const void* __restrict__ ea,
                              const int* __restrict__ erow, int E,
                              float* __restrict__ stats, const int* __restrict__ modep) {
  const int mode = *modep;
  const int c = threadIdx.x & 63, es = threadIdx.x >> 6;  // 4 edges / block-iter
  float s = 0.f, q = 0.f;
  for (long e = (long)blockIdx.x * 4 + es; e < E; e += (long)gridDim.x * 4) {
    float v;
    if (c < 32) { int src = erow[e]; v = loadf(x, (long)src * 32 + c, mode); }
    else        { v = loadf(ea, e * 32 + (c - 32), mode); }
    s += v; q += v * v;
  }
  __shared__ float sm1[256], sm2[256];
  sm1[threadIdx.x] = s; sm2[threadIdx.x] = q;
  __syncthreads();
  if (es == 0) {
    for (int i = 1; i < 4; i++) { s += sm1[i * 64 + c]; q += sm2[i * 64 + c]; }
    float* o = stats + (blockIdx.x & (NBIN - 1)) * 128;
    atomicAdd(o + c, s); atomicAdd(o + 64 + c, q);
  }
}

// ---------------- stats of x over N rows -> statsB0 cols 0..31
__global__ void statsX_kernel(const void* __restrict__ x, int N,
                              float* __restrict__ stats,
                              const int* __restrict__ modep) {
  const int mode = *modep;
  const int c = threadIdx.x & 31, rs = threadIdx.x >> 5;  // 8 rows / block-iter
  float s = 0.f, q = 0.f;
  for (long r = (long)blockIdx.x * 8 + rs; r < N; r += (long)gridDim.x * 8) {
    float v = loadf(x, r * 32 + c, mode);
    s += v; q += v * v;
  }
  __shared__ float sm1[256], sm2[256];
  sm1[threadIdx.x] = s; sm2[threadIdx.x] = q;
  __syncthreads();
  if (rs == 0) {
    for (int i = 1; i < 8; i++) { s += sm1[i * 32 + c]; q += sm2[i * 32 + c]; }
    float* o = stats + (blockIdx.x & (NBIN - 1)) * 192;
    atomicAdd(o + c, s); atomicAdd(o + 96 + c, q);
  }
}

// ---------------- fold: binned stats -> BN scale/offset -> packed W + bias
__global__ void fold_kernel(const float* __restrict__ stats, float inv_rows,
                            const void* __restrict__ g, const void* __restrict__ b,
                            const void* __restrict__ W, const void* __restrict__ c,
                            int K, int OUT,
                            u16* __restrict__ Wpack, float* __restrict__ biasOut,
                            const int* __restrict__ modep) {
  const int mode = *modep;
  __shared__ float s_s[96], s_off[96];
  const int tid = threadIdx.x;
  if (tid < K) {
    float sum = 0.f, sq = 0.f;
    for (int p = 0; p < NBIN; p++) {
      sum += stats[p * 2 * K + tid];
      sq  += stats[p * 2 * K + K + tid];
    }
    float m   = sum * inv_rows;
    float var = sq * inv_rows - m * m;
    float s   = loadf(g, tid, mode) * rsqrtf(var + 1e-5f);
    s_s[tid]  = s;
    s_off[tid] = loadf(b, tid, mode) - m * s;
  }
  __syncthreads();
  for (int n = tid; n < OUT; n += blockDim.x) {
    float acc = loadf(c, n, mode);
    for (int k = 0; k < K; k++) acc += s_off[k] * loadf(W, k * OUT + n, mode);
    biasOut[n] = acc;
  }
  const int H = K / 32, T = OUT / 16;
  const int total = T * H * 64 * 8;
  for (int i = tid; i < total; i += blockDim.x) {
    int j = i & 7, lane = (i >> 3) & 63, th = i >> 9;
    int h = th % H, t = th / H;
    int k = h * 32 + (lane >> 4) * 8 + j;
    int n = t * 16 + (lane & 15);
    Wpack[i] = f2bf(s_s[k] * loadf(W, k * OUT + n, mode));
  }
}

// ======== phase-A GEMMs: 64 cols, K=64, 256 rows/block (4 tiles/wave) =======

// GEMM 1: A = [x[row[e]], ea[e]], LReLU, epilogue stats -> statsOut[NBIN][128]
__global__ __launch_bounds__(256) void gemm1_kernel(
    const void* __restrict__ x, const void* __restrict__ ea,
    const int* __restrict__ erow, const u16* __restrict__ Wp,
    const float* __restrict__ bias, u16* __restrict__ hout, int E,
    float* __restrict__ statsOut, const int* __restrict__ modep) {
  const int mode = *modep;
  const int lane = threadIdx.x & 63, wave = threadIdx.x >> 6;
  const int q = lane >> 4, r = lane & 15;
  const long wbase = (long)blockIdx.x * 256 + wave * 64;
  bf16x8 bfr[4][2];
#pragma unroll
  for (int t = 0; t < 4; t++)
#pragma unroll
    for (int h = 0; h < 2; h++)
      bfr[t][h] = ldb8(Wp + ((t * 2 + h) * 64 + lane) * 8);
  float bv[4];
#pragma unroll
  for (int t = 0; t < 4; t++) bv[t] = bias[t * 16 + r];
  float s_[4] = {0, 0, 0, 0}, q_[4] = {0, 0, 0, 0};
#pragma unroll
  for (int r4 = 0; r4 < 4; r4++) {
    const long row0 = wbase + r4 * 16;
    long e = row0 + r; if (e > E - 1) e = E - 1;
    int src = erow[e];
    bf16x8 a0 = load8(x, (long)src * 32 + q * 8, mode);
    bf16x8 a1 = load8(ea, e * 32 + q * 8, mode);
    floatx4 acc[4];
#pragma unroll
    for (int t = 0; t < 4; t++) {
      acc[t] = (floatx4){bv[t], bv[t], bv[t], bv[t]};
      acc[t] = mfma16(a0, bfr[t][0], acc[t]);
      acc[t] = mfma16(a1, bfr[t][1], acc[t]);
    }
#pragma unroll
    for (int t = 0; t < 4; t++)
#pragma unroll
      for (int gi = 0; gi < 4; gi++) {
        long row = row0 + q * 4 + gi;
        if (row < E) {
          float v = acc[t][gi];
          v = v > 0.f ? v : 0.1f * v;
          u16 st = f2bf(v);
          hout[row * 64 + t * 16 + r] = st;
          float vv = bf2f(st);
          s_[t] += vv; q_[t] += vv * vv;
        }
      }
  }
  __shared__ float sm[512];
#pragma unroll
  for (int t = 0; t < 4; t++) {
    float s = s_[t], qq = q_[t];
    s  += __shfl_xor(s, 16, 64);  s  += __shfl_xor(s, 32, 64);
    qq += __shfl_xor(qq, 16, 64); qq += __shfl_xor(qq, 32, 64);
    if (lane < 16) { sm[wave * 128 + t * 16 + lane] = s; sm[wave * 128 + 64 + t * 16 + lane] = qq; }
  }
  __syncthreads();
  if (threadIdx.x < 128) {
    int which = threadIdx.x >> 6, c = threadIdx.x & 63;
    float v = 0.f;
    for (int w = 0; w < 4; w++) v += sm[w * 128 + which * 64 + c];
    atomicAdd(statsOut + (blockIdx.x & (NBIN - 1)) * 128 + which * 64 + c, v);
  }
}

// GEMM 2: h[E,64] -> h[E,64] in place, LReLU, epilogue stats
__global__ __launch_bounds__(256) void gemm2_kernel(
    const u16* __restrict__ hin, const u16* __restrict__ Wp,
    const float* __restrict__ bias, u16* __restrict__ hout, int E,
    float* __restrict__ statsOut) {
  const int lane = threadIdx.x & 63, wave = threadIdx.x >> 6;
  const int q = lane >> 4, r = lane & 15;
  const long wbase = (long)blockIdx.x * 256 + wave * 64;
  bf16x8 bfr[4][2];
#pragma unroll
  for (int t = 0; t < 4; t++)
#pragma unroll
    for (int h = 0; h < 2; h++)
      bfr[t][h] = ldb8(Wp + ((t * 2 + h) * 64 + lane) * 8);
  float bv[4];
#pragma unroll
  for (int t = 0; t < 4; t++) bv[t] = bias[t * 16 + r];
  float s_[4] = {0, 0, 0, 0}, q_[4] = {0, 0, 0, 0};
#pragma unroll
  for (int r4 = 0; r4 < 4; r4++) {
    const long row0 = wbase + r4 * 16;
    long e = row0 + r; if (e > E - 1) e = E - 1;
    bf16x8 a0 = ldb8(hin + e * 64 + q * 8);
    bf16x8 a1 = ldb8(hin + e * 64 + 32 + q * 8);
    floatx4 acc[4];
#pragma unroll
    for (int t = 0; t < 4; t++) {
      acc[t] = (floatx4){bv[t], bv[t], bv[t], bv[t]};
      acc[t] = mfma16(a0, bfr[t][0], acc[t]);
      acc[t] = mfma16(a1, bfr[t][1], acc[t]);
    }
#pragma unroll
    for (int t = 0; t < 4; t++)
#pragma unroll
      for (int gi = 0; gi < 4; gi++) {
        long row = row0 + q * 4 + gi;
        if (row < E) {
          float v = acc[t][gi];
          v = v > 0.f ? v : 0.1f * v;
          u16 st = f2bf(v);
          hout[row * 64 + t * 16 + r] = st;
          float vv = bf2f(st);
          s_[t] += vv; q_[t] += vv * vv;
        }
      }
  }
  __shared__ float sm[512];
#pragma unroll
  for (int t = 0; t < 4; t++) {
    float s = s_[t], qq = q_[t];
    s  += __shfl_xor(s, 16, 64);  s  += __shfl_xor(s, 32, 64);
    qq += __shfl_xor(qq, 16, 64); qq += __shfl_xor(qq, 32, 64);
    if (lane < 16) { sm[wave * 128 + t * 16 + lane] = s; sm[wave * 128 + 64 + t * 16 + lane] = qq; }
  }
  __syncthreads();
  if (threadIdx.x < 128) {
    int which = threadIdx.x >> 6, c = threadIdx.x & 63;
    float v = 0.f;
    for (int w = 0; w < 4; w++) v += sm[w * 128 + which * 64 + c];
    atomicAdd(statsOut + (blockIdx.x & (NBIN - 1)) * 128 + which * 64 + c, v);
  }
}

// GEMM Agg: agg[n] = bf16(s_e[n]) @ W3' + deg[n]*b3'  (fp32 out) + agg stats
__global__ __launch_bounds__(256) void gemmAgg_kernel(
    const float* __restrict__ s_e, const int* __restrict__ deg,
    const u16* __restrict__ Wp, const float* __restrict__ bias,
    float* __restrict__ agg, int N, float* __restrict__ statsOut) {
  const int lane = threadIdx.x & 63, wave = threadIdx.x >> 6;
  const int q = lane >> 4, r = lane & 15;
  const long wbase = (long)blockIdx.x * 256 + wave * 64;
  bf16x8 bfr[4][2];
#pragma unroll
  for (int t = 0; t < 4; t++)
#pragma unroll
    for (int h = 0; h < 2; h++)
      bfr[t][h] = ldb8(Wp + ((t * 2 + h) * 64 + lane) * 8);
  float bv[4];
#pragma unroll
  for (int t = 0; t < 4; t++) bv[t] = bias[t * 16 + r];
  float s_[4] = {0, 0, 0, 0}, q_[4] = {0, 0, 0, 0};
#pragma unroll
  for (int r4 = 0; r4 < 4; r4++) {
    const long row0 = wbase + r4 * 16;
    long m = row0 + r;
    long mm = m < N ? m : (long)N - 1;
    bf16x8 a0, a1;
    {
      const float* ap = s_e + mm * 64 + q * 8;
#pragma unroll
      for (int j = 0; j < 8; j++) a0[j] = (__bf16)ap[j];
#pragma unroll
      for (int j = 0; j < 8; j++) a1[j] = (__bf16)ap[32 + j];
    }
    floatx4 acc[4];
#pragma unroll
    for (int t = 0; t < 4; t++) {
      acc[t] = (floatx4){0.f, 0.f, 0.f, 0.f};
      acc[t] = mfma16(a0, bfr[t][0], acc[t]);
      acc[t] = mfma16(a1, bfr[t][1], acc[t]);
    }
#pragma unroll
    for (int gi = 0; gi < 4; gi++) {
      long row = row0 + q * 4 + gi;
      if (row < N) {
        float d = (float)deg[row];
#pragma unroll
        for (int t = 0; t < 4; t++) {
          float v = acc[t][gi] + d * bv[t];
          agg[row * 64 + t * 16 + r] = v;
          s_[t] += v; q_[t] += v * v;
        }
      }
    }
  }
  __shared__ float sm[512];
#pragma unroll
  for (int t = 0; t < 4; t++) {
    float s = s_[t], qq = q_[t];
    s  += __shfl_xor(s, 16, 64);  s  += __shfl_xor(s, 32, 64);
    qq += __shfl_xor(qq, 16, 64); qq += __shfl_xor(qq, 32, 64);
    if (lane < 16) { sm[wave * 128 + t * 16 + lane] = s; sm[wave * 128 + 64 + t * 16 + lane] = qq; }
  }
  __syncthreads();
  if (threadIdx.x < 128) {
    int which = threadIdx.x >> 6, c = threadIdx.x & 63;
    float v = 0.f;
    for (int w = 0; w < 4; w++) v += sm[w * 128 + which * 64 + c];
    // statsB0 layout [NBIN][192]: sums at [0..95], sumsq at [96..191]; agg = cols 32..95
    atomicAdd(statsOut + (blockIdx.x & (NBIN - 1)) * 192 + which * 96 + 32 + c, v);
  }
}

// ======== phase-B GEMMs: 96-wide, 256 rows/block (4 tiles/wave) =============

// GEMM B1: A = [x, agg(fp32)] (K=96 -> 96), LReLU, stats -> statsOut[NBIN][192]
__global__ __launch_bounds__(256) void gemmB1_kernel(
    const void* __restrict__ x, const float* __restrict__ agg,
    const u16* __restrict__ Wp, const float* __restrict__ bias,
    u16* __restrict__ hout, int N, float* __restrict__ statsOut,
    const int* __restrict__ modep) {
  const int mode = *modep;
  const int lane = threadIdx.x & 63, wave = threadIdx.x >> 6;
  const int q = lane >> 4, r = lane & 15;
  const long wbase = (long)blockIdx.x * 256 + wave * 64;
  bf16x8 bfr[6][3];
#pragma unroll
  for (int t = 0; t < 6; t++)
#pragma unroll
    for (int h = 0; h < 3; h++)
      bfr[t][h] = ldb8(Wp + ((t * 3 + h) * 64 + lane) * 8);
  float bv[6];
#pragma unroll
  for (int t = 0; t < 6; t++) bv[t] = bias[t * 16 + r];
  float s_[6] = {0, 0, 0, 0, 0, 0}, q_[6] = {0, 0, 0, 0, 0, 0};
#pragma unroll
  for (int r4 = 0; r4 < 4; r4++) {
    const long row0 = wbase + r4 * 16;
    long m = row0 + r;
    long mm = m < N ? m : (long)N - 1;
    bf16x8 a0 = load8(x, mm * 32 + q * 8, mode);
    bf16x8 a1, a2;
    {
      const float* ap = agg + mm * 64 + q * 8;
#pragma unroll
      for (int j = 0; j < 8; j++) a1[j] = (__bf16)ap[j];
#pragma unroll
      for (int j = 0; j < 8; j++) a2[j] = (__bf16)ap[32 + j];
    }
    floatx4 acc[6];
#pragma unroll
    for (int t = 0; t < 6; t++) {
      acc[t] = (floatx4){bv[t], bv[t], bv[t], bv[t]};
      acc[t] = mfma16(a0, bfr[t][0], acc[t]);
      acc[t] = mfma16(a1, bfr[t][1], acc[t]);
      acc[t] = mfma16(a2, bfr[t][2], acc[t]);
    }
#pragma unroll
    for (int t = 0; t < 6; t++)
#pragma unroll
      for (int gi = 0; gi < 4; gi++) {
        long row = row0 + q * 4 + gi;
        if (row < N) {
          float v = acc[t][gi];
          v = v > 0.f ? v : 0.1f * v;
          u16 st = f2bf(v);
          hout[row * 96 + t * 16 + r] = st;
          float vv = bf2f(st);
          s_[t] += vv; q_[t] += vv * vv;
        }
      }
  }
  __shared__ float sm[768];
#pragma unroll
  for (int t = 0; t < 6; t++) {
    float s = s_[t], qq = q_[t];
    s  += __shfl_xor(s, 16, 64);  s  += __shfl_xor(s, 32, 64);
    qq += __shfl_xor(qq, 16, 64); qq += __shfl_xor(qq, 32, 64);
    if (lane < 16) { sm[wave * 192 + t * 16 + lane] = s; sm[wave * 192 + 96 + t * 16 + lane] = qq; }
  }
  __syncthreads();
  if (threadIdx.x < 192) {
    int which = threadIdx.x / 96, c = threadIdx.x % 96;
    float v = 0.f;
    for (int w = 0; w < 4; w++) v += sm[w * 192 + which * 96 + c];
    atomicAdd(statsOut + (blockIdx.x & (NBIN - 1)) * 192 + which * 96 + c, v);
  }
}

// GEMM B2: h[N,96] -> h[N,96] in place, LReLU, stats
__global__ __launch_bounds__(256) void gemmB2_kernel(
    const u16* __restrict__ hin, const u16* __restrict__ Wp,
    const float* __restrict__ bias, u16* __restrict__ hout, int N,
    float* __restrict__ statsOut) {
  const int lane = threadIdx.x & 63, wave = threadIdx.x >> 6;
  const int q = lane >> 4, r = lane & 15;
  const long wbase = (long)blockIdx.x * 256 + wave * 64;
  bf16x8 bfr[6][3];
#pragma unroll
  for (int t = 0; t < 6; t++)
#pragma unroll
    for (int h = 0; h < 3; h++)
      bfr[t][h] = ldb8(Wp + ((t * 3 + h) * 64 + lane) * 8);
  float bv[6];
#pragma unroll
  for (int t = 0; t < 6; t++) bv[t] = bias[t * 16 + r];
  float s_[6] = {0, 0, 0, 0, 0, 0}, q_[6] = {0, 0, 0, 0, 0, 0};
#pragma unroll
  for (int r4 = 0; r4 < 4; r4++) {
    const long row0 = wbase + r4 * 16;
    long m = row0 + r;
    long mm = m < N ? m : (long)N - 1;
    bf16x8 a0 = ldb8(hin + mm * 96 + q * 8);
    bf16x8 a1 = ldb8(hin + mm * 96 + 32 + q * 8);
    bf16x8 a2 = ldb8(hin + mm * 96 + 64 + q * 8);
    floatx4 acc[6];
#pragma unroll
    for (int t = 0; t < 6; t++) {
      acc[t] = (floatx4){bv[t], bv[t], bv[t], bv[t]};
      acc[t] = mfma16(a0, bfr[t][0], acc[t]);
      acc[t] = mfma16(a1, bfr[t][1], acc[t]);
      acc[t] = mfma16(a2, bfr[t][2], acc[t]);
    }
#pragma unroll
    for (int t = 0; t < 6; t++)
#pragma unroll
      for (int gi = 0; gi < 4; gi++) {
        long row = row0 + q * 4 + gi;
        if (row < N) {
          float v = acc[t][gi];
          v = v > 0.f ? v : 0.1f * v;
          u16 st = f2bf(v);
          hout[row * 96 + t * 16 + r] = st;
          float vv = bf2f(st);
          s_[t] += vv; q_[t] += vv * vv;
        }
      }
  }
  __shared__ float sm[768];
#pragma unroll
  for (int t = 0; t < 6; t++) {
    float s = s_[t], qq = q_[t];
    s  += __shfl_xor(s, 16, 64);  s  += __shfl_xor(s, 32, 64);
    qq += __shfl_xor(qq, 16, 64); qq += __shfl_xor(qq, 32, 64);
    if (lane < 16) { sm[wave * 192 + t * 16 + lane] = s; sm[wave * 192 + 96 + t * 16 + lane] = qq; }
  }
  __syncthreads();
  if (threadIdx.x < 192) {
    int which = threadIdx.x / 96, c = threadIdx.x % 96;
    float v = 0.f;
    for (int w = 0; w < 4; w++) v += sm[w * 192 + which * 96 + c];
    atomicAdd(statsOut + (blockIdx.x & (NBIN - 1)) * 192 + which * 96 + c, v);
  }
}

// GEMM B3: h[N,96] -> out[N,32], no activation, no stats
__global__ __launch_bounds__(256) void gemmB3_kernel(
    const u16* __restrict__ hin, const u16* __restrict__ Wp,
    const float* __restrict__ bias, void* __restrict__ outv, int N,
    const int* __restrict__ modep) {
  const int mode = *modep;
  const int lane = threadIdx.x & 63, wave = threadIdx.x >> 6;
  const int q = lane >> 4, r = lane & 15;
  const long wbase = (long)blockIdx.x * 256 + wave * 64;
  bf16x8 bfr[2][3];
#pragma unroll
  for (int t = 0; t < 2; t++)
#pragma unroll
    for (int h = 0; h < 3; h++)
      bfr[t][h] = ldb8(Wp + ((t * 3 + h) * 64 + lane) * 8);
  float bv[2];
#pragma unroll
  for (int t = 0; t < 2; t++) bv[t] = bias[t * 16 + r];
#pragma unroll
  for (int r4 = 0; r4 < 4; r4++) {
    const long row0 = wbase + r4 * 16;
    long m = row0 + r;
    long mm = m < N ? m : (long)N - 1;
    bf16x8 a0 = ldb8(hin + mm * 96 + q * 8);
    bf16x8 a1 = ldb8(hin + mm * 96 + 32 + q * 8);
    bf16x8 a2 = ldb8(hin + mm * 96 + 64 + q * 8);
    floatx4 acc[2];
#pragma unroll
    for (int t = 0; t < 2; t++) {
      acc[t] = (floatx4){bv[t], bv[t], bv[t], bv[t]};
      acc[t] = mfma16(a0, bfr[t][0], acc[t]);
      acc[t] = mfma16(a1, bfr[t][1], acc[t]);
      acc[t] = mfma16(a2, bfr[t][2], acc[t]);
    }
#pragma unroll
    for (int t = 0; t < 2; t++)
#pragma unroll
      for (int gi = 0; gi < 4; gi++) {
        long row = row0 + q * 4 + gi;
        if (row < N) {
          float v = acc[t][gi];
          if (mode) ((u16*)outv)[row * 32 + t * 16 + r] = f2bf(v);
          else      ((float*)outv)[row * 32 + t * 16 + r] = v;
        }
      }
  }
}

// ---------------------------------------------------------------------------
extern "C" void kernel_launch(void* const* d_in, const int* in_sizes, int n_in,
                              void* d_out, int out_size, void* d_ws,
                              size_t ws_size, hipStream_t stream) {
  const int N = in_sizes[0] / 32;
  const int E = in_sizes[2] / 32;

  const void* x    = d_in[0];
  const int*  eidx = (const int*)d_in[1];  // [2][E]: row=eidx, col=eidx+E
  const void* ea   = d_in[2];
  const void *m1_g1 = d_in[5],  *m1_b1 = d_in[6];
  const void *m1_w1 = d_in[7],  *m1_c1 = d_in[8];
  const void *m1_g2 = d_in[9],  *m1_b2 = d_in[10];
  const void *m1_w2 = d_in[11], *m1_c2 = d_in[12];
  const void *m1_g3 = d_in[13], *m1_b3 = d_in[14];
  const void *m1_w3 = d_in[15], *m1_c3 = d_in[16];
  const void *m2_g1 = d_in[17], *m2_b1 = d_in[18];
  const void *m2_w1 = d_in[19], *m2_c1 = d_in[20];
  const void *m2_g2 = d_in[21], *m2_b2 = d_in[22];
  const void *m2_w2 = d_in[23], *m2_c2 = d_in[24];
  const void *m2_g3 = d_in[25], *m2_b3 = d_in[26];
  const void *m2_w3 = d_in[27], *m2_c3 = d_in[28];

  // workspace carve (16B-aligned chunks)
  char* w = (char*)d_ws;
  int*   modep  = (int*)w;   w += 16;
  u16*   h_e    = (u16*)w;   w += (size_t)E * 64 * 2;       // 102.4 MB
  u16*   h2b    = (u16*)w;   w += (size_t)N * 96 * 2;       //  19.2 MB
  float* agg    = (float*)w; w += (size_t)N * 64 * 4;       //  25.6 MB
  float* s_e    = (float*)w; w += (size_t)N * 64 * 4;       //  25.6 MB
  int*   offs   = (int*)w;   w += ((size_t)N + 4) * 4;
  int*   cursor = (int*)w;   w += ((size_t)N + 4) * 4;
  int*   perm   = (int*)w;   w += (size_t)E * 4;            //   3.2 MB
  int*   bsum   = (int*)w;   w += 1024 * 4;
  // zero zone: deg + all stats buffers (contiguous)
  int*   deg    = (int*)w;   w += (size_t)N * 4;
  float* stats0 = (float*)w; w += NBIN * 128 * 4;
  float* stats1 = (float*)w; w += NBIN * 128 * 4;
  float* stats2 = (float*)w; w += NBIN * 128 * 4;
  float* statsB0= (float*)w; w += NBIN * 192 * 4;
  float* statsB1= (float*)w; w += NBIN * 192 * 4;
  float* statsB2= (float*)w; w += NBIN * 192 * 4;
  const size_t zero_bytes = (size_t)N * 4 + NBIN * (128 * 3 + 192 * 3) * 4;
  u16*   Wp1    = (u16*)w;   w += 4096 * 2;
  float* bias1  = (float*)w; w += 64 * 4;
  u16*   Wp2    = (u16*)w;   w += 4096 * 2;
  float* bias2  = (float*)w; w += 64 * 4;
  u16*   Wp3    = (u16*)w;   w += 4096 * 2;
  float* bias3  = (float*)w; w += 64 * 4;
  u16*   WpB1   = (u16*)w;   w += 9216 * 2;
  float* biasB1 = (float*)w; w += 96 * 4;
  u16*   WpB2   = (u16*)w;   w += 9216 * 2;
  float* biasB2 = (float*)w; w += 96 * 4;
  u16*   WpB3   = (u16*)w;   w += 3072 * 2;
  float* biasB3 = (float*)w; w += 32 * 4;

  const int* ecol = eidx + E;
  const float invE = 1.0f / (float)E, invN = 1.0f / (float)N;
  const int gA = (E + 255) / 256, gB = (N + 255) / 256;
  const int nb = (N + 1023) / 1024;

  detect_kernel<<<1, 256, 0, stream>>>((const u16*)x, modep);
  hipMemsetAsync(deg, 0, zero_bytes, stream);

  // --- counting sort of edges by destination (independent of MLP) ---
  count_kernel<<<1024, 256, 0, stream>>>(ecol, E, deg);
  scan1_kernel<<<nb, 1024, 0, stream>>>(deg, N, offs, bsum);
  scan2_kernel<<<1, 64, 0, stream>>>(bsum, nb, offs, N, E);
  scan3_kernel<<<nb, 1024, 0, stream>>>(offs, bsum, N, cursor);
  scatter_kernel<<<1024, 256, 0, stream>>>(ecol, E, cursor, perm);
  statsX_kernel<<<512, 256, 0, stream>>>(x, N, statsB0, modep);

  // --- phase A: edge MLP ---
  stats0_kernel<<<1024, 256, 0, stream>>>(x, ea, eidx, E, stats0, modep);
  fold_kernel<<<1, 256, 0, stream>>>(stats0, invE, m1_g1, m1_b1, m1_w1, m1_c1,
                                     64, 64, Wp1, bias1, modep);
  gemm1_kernel<<<gA, 256, 0, stream>>>(x, ea, eidx, Wp1, bias1, h_e, E,
                                       stats1, modep);
  fold_kernel<<<1, 256, 0, stream>>>(stats1, invE, m1_g2, m1_b2, m1_w2, m1_c2,
                                     64, 64, Wp2, bias2, modep);
  gemm2_kernel<<<gA, 256, 0, stream>>>(h_e, Wp2, bias2, h_e, E, stats2);

  // --- aggregation: segment-sum then dense GEMM (no atomics) ---
  aggsum_kernel<<<1024, 256, 0, stream>>>(h_e, perm, offs, s_e, N);
  fold_kernel<<<1, 256, 0, stream>>>(stats2, invE, m1_g3, m1_b3, m1_w3, m1_c3,
                                     64, 64, Wp3, bias3, modep);
  gemmAgg_kernel<<<gB, 256, 0, stream>>>(s_e, deg, Wp3, bias3, agg, N, statsB0);

  // --- phase B: node MLP ---
  fold_kernel<<<1, 256, 0, stream>>>(statsB0, invN, m2_g1, m2_b1, m2_w1, m2_c1,
                                     96, 96, WpB1, biasB1, modep);
  gemmB1_kernel<<<gB, 256, 0, stream>>>(x, agg, WpB1, biasB1, h2b, N,
                                        statsB1, modep);
  fold_kernel<<<1, 256, 0, stream>>>(statsB1, invN, m2_g2, m2_b2, m2_w2, m2_c2,
                                     96, 96, WpB2, biasB2, modep);
  gemmB2_kernel<<<gB, 256, 0, stream>>>(h2b, WpB2, biasB2, h2b, N, statsB2);
  fold_kernel<<<1, 256, 0, stream>>>(statsB2, invN, m2_g3, m2_b3, m2_w3, m2_c3,
                                     96, 32, WpB3, biasB3, modep);
  gemmB3_kernel<<<gB, 256, 0, stream>>>(h2b, WpB3, biasB3, d_out, N, modep);
}

// Round 5
// 741.523 us; speedup vs baseline: 3.1311x; 1.1592x over previous
//
#include <hip/hip_runtime.h>

// ---------------------------------------------------------------------------
// NodeModel (GraphNet node block), MI355X / gfx950.
// v5: (a) gathered-x stats replaced by out-degree-weighted node stats
//     (sum_e x[row[e]] == sum_n odeg[n]*x[n]); ea stats vectorized.
//     (b) gemm1 writes its output destination-sorted via ipos[] so the
//     segment-sum (aggsum) is a pure sequential scan — no random reads,
//     no atomics anywhere in the aggregation path.
// BN folded into GEMM weights; stats fused into GEMM epilogues elsewhere.
// MFMA layouts (verified): A[m=lane&15][k=(lane>>4)*8+j],
//   B[k=(lane>>4)*8+j][n=lane&15], C/D: col=lane&15, row=(lane>>4)*4+reg.
// Input dtype (fp32 vs bf16 harness mode) detected at runtime.
// ---------------------------------------------------------------------------

typedef unsigned short u16;
typedef __bf16  bf16x8  __attribute__((ext_vector_type(8)));
typedef float   floatx4 __attribute__((ext_vector_type(4)));

#define NBIN 8

__device__ __forceinline__ float bf2f(u16 u) {
  union { float f; unsigned int i; } v; v.i = ((unsigned int)u) << 16; return v.f;
}
__device__ __forceinline__ u16 f2bf(float f) {
  union { float f; unsigned int i; } v; v.f = f;
  unsigned int x = v.i;
  return (u16)((x + 0x7fffu + ((x >> 16) & 1u)) >> 16);  // RNE
}
__device__ __forceinline__ bf16x8 ldb8(const u16* p) {
  return *reinterpret_cast<const bf16x8*>(p);
}
__device__ __forceinline__ floatx4 mfma16(bf16x8 a, bf16x8 b, floatx4 c) {
  return __builtin_amdgcn_mfma_f32_16x16x32_bf16(a, b, c, 0, 0, 0);
}
// mode: 0 = input is float32, 1 = input is bf16
__device__ __forceinline__ float loadf(const void* p, long idx, int mode) {
  return mode ? bf2f(((const u16*)p)[idx]) : ((const float*)p)[idx];
}
__device__ __forceinline__ bf16x8 load8(const void* p, long idx, int mode) {
  if (mode) return ldb8((const u16*)p + idx);
  const float* f = (const float*)p + idx;
  bf16x8 r;
#pragma unroll
  for (int j = 0; j < 8; j++) r[j] = (__bf16)f[j];
  return r;
}

// ---------------- dtype detection
__global__ void detect_kernel(const u16* __restrict__ x, int* __restrict__ modep) {
  __shared__ int cnt;
  if (threadIdx.x == 0) cnt = 0;
  __syncthreads();
  int weird = 0;
  for (int i = threadIdx.x; i < 1024; i += blockDim.x) {
    unsigned e = (x[i] >> 7) & 0xFFu;
    if (e == 0xFFu || e >= 0x90u || (e != 0u && e < 0x60u)) weird++;
  }
  atomicAdd(&cnt, weird);
  __syncthreads();
  if (threadIdx.x == 0) *modep = (cnt > 128) ? 0 : 1;
}

// ================= counting sort of edges by destination ====================
// also builds out-degree histogram (for weighted x stats)
__global__ void count2_kernel(const int* __restrict__ row, const int* __restrict__ col,
                              int E, int* __restrict__ odeg, int* __restrict__ deg) {
  for (int e = blockIdx.x * blockDim.x + threadIdx.x; e < E;
       e += gridDim.x * blockDim.x) {
    atomicAdd(&odeg[row[e]], 1);
    atomicAdd(&deg[col[e]], 1);
  }
}

// per-1024-block exclusive scan; block totals to bsum
__global__ void scan1_kernel(const int* __restrict__ deg, int n,
                             int* __restrict__ excl, int* __restrict__ bsum) {
  __shared__ int tmp[2][1024];
  const int tid = threadIdx.x;
  const int i = blockIdx.x * 1024 + tid;
  int v = (i < n) ? deg[i] : 0;
  tmp[0][tid] = v;
  __syncthreads();
  int src = 0;
  for (int off = 1; off < 1024; off <<= 1) {
    int t = tmp[src][tid];
    if (tid >= off) t += tmp[src][tid - off];
    tmp[1 - src][tid] = t;
    src = 1 - src;
    __syncthreads();
  }
  if (i < n) excl[i] = tmp[src][tid] - v;
  if (tid == 1023) bsum[blockIdx.x] = tmp[src][1023];
}

__global__ void scan2_kernel(int* __restrict__ bsum, int nb,
                             int* __restrict__ offsets, int N, int E) {
  if (threadIdx.x == 0) {
    int run = 0;
    for (int i = 0; i < nb; i++) { int v = bsum[i]; bsum[i] = run; run += v; }
    offsets[N] = E;
  }
}

__global__ void scan3_kernel(int* __restrict__ offsets, const int* __restrict__ bsum,
                             int n, int* __restrict__ cursor) {
  int i = blockIdx.x * 1024 + threadIdx.x;
  if (i < n) {
    int v = offsets[i] + bsum[blockIdx.x];
    offsets[i] = v;
    cursor[i] = v;
  }
}

// edge -> its position in destination-sorted order
__global__ void scatter_kernel(const int* __restrict__ col, int E,
                               int* __restrict__ cursor, int* __restrict__ ipos) {
  for (int e = blockIdx.x * blockDim.x + threadIdx.x; e < E;
       e += gridDim.x * blockDim.x) {
    int d = col[e];
    ipos[e] = atomicAdd(&cursor[d], 1);
  }
}

// ---------------- x stats: unweighted -> statsB0 cols 0..31,
//                  odeg-weighted (== gathered-x stats) -> stats0 cols 0..31
__global__ void statsXW_kernel(const void* __restrict__ x, const int* __restrict__ odeg,
                               int N, float* __restrict__ stats0,
                               float* __restrict__ statsB0,
                               const int* __restrict__ modep) {
  const int mode = *modep;
  const int c = threadIdx.x & 31, rs = threadIdx.x >> 5;  // 8 rows / block-iter
  float s = 0.f, q = 0.f, ws = 0.f, wq = 0.f;
  for (long r = (long)blockIdx.x * 8 + rs; r < N; r += (long)gridDim.x * 8) {
    float v = loadf(x, r * 32 + c, mode);
    float w = (float)odeg[r];
    s += v; q += v * v;
    ws += w * v; wq += w * v * v;
  }
  __shared__ float sm[4][256];
  sm[0][threadIdx.x] = s; sm[1][threadIdx.x] = q;
  sm[2][threadIdx.x] = ws; sm[3][threadIdx.x] = wq;
  __syncthreads();
  if (threadIdx.x < 32) {
    for (int i = 1; i < 8; i++) {
      s  += sm[0][i * 32 + c]; q  += sm[1][i * 32 + c];
      ws += sm[2][i * 32 + c]; wq += sm[3][i * 32 + c];
    }
    const int bin = blockIdx.x & (NBIN - 1);
    atomicAdd(statsB0 + bin * 192 + c, s);
    atomicAdd(statsB0 + bin * 192 + 96 + c, q);
    atomicAdd(stats0 + bin * 128 + c, ws);
    atomicAdd(stats0 + bin * 128 + 64 + c, wq);
  }
}

// ---------------- ea stats: streaming, 8 cols per thread, vector loads
__global__ void statsEA_kernel(const void* __restrict__ ea, int E,
                               float* __restrict__ stats,
                               const int* __restrict__ modep) {
  const int mode = *modep;
  const int cg = threadIdx.x & 3;        // col group: cols cg*8..cg*8+7
  const int rsub = threadIdx.x >> 2;     // 64 rows / block-iter
  float s[8], q[8];
#pragma unroll
  for (int j = 0; j < 8; j++) { s[j] = 0.f; q[j] = 0.f; }
  for (long r = (long)blockIdx.x * 64 + rsub; r < E; r += (long)gridDim.x * 64) {
    if (mode) {
      bf16x8 v = ldb8((const u16*)ea + r * 32 + cg * 8);
#pragma unroll
      for (int j = 0; j < 8; j++) { float f = (float)v[j]; s[j] += f; q[j] += f * f; }
    } else {
      const float* p = (const float*)ea + r * 32 + cg * 8;
      float4 a = *(const float4*)p;
      float4 b = *(const float4*)(p + 4);
      float f0[8] = {a.x, a.y, a.z, a.w, b.x, b.y, b.z, b.w};
#pragma unroll
      for (int j = 0; j < 8; j++) { s[j] += f0[j]; q[j] += f0[j] * f0[j]; }
    }
  }
  // reduce across row-sub lanes within the wave (lane = (rsub&15)*4 + cg)
  const int lane = threadIdx.x & 63;
#pragma unroll
  for (int st = 4; st < 64; st <<= 1) {
#pragma unroll
    for (int j = 0; j < 8; j++) {
      s[j] += __shfl_xor(s[j], st, 64);
      q[j] += __shfl_xor(q[j], st, 64);
    }
  }
  if (lane < 4) {
    float* o = stats + (blockIdx.x & (NBIN - 1)) * 128;
#pragma unroll
    for (int j = 0; j < 8; j++) {
      atomicAdd(o + 32 + lane * 8 + j, s[j]);
      atomicAdd(o + 96 + lane * 8 + j, q[j]);
    }
  }
}

// ---------------- segment-sum of sorted h rows per node (pure sequential)
__global__ __launch_bounds__(256) void aggsum_kernel(
    const u16* __restrict__ h_s, const int* __restrict__ offsets,
    float* __restrict__ s_e, int N) {
  const int lane = threadIdx.x & 63, wave = threadIdx.x >> 6;
  for (long n = (long)blockIdx.x * 4 + wave; n < N; n += (long)gridDim.x * 4) {
    int start = offsets[n], end = offsets[n + 1];
    float acc = 0.f;
    for (int j = start; j < end; j++)
      acc += bf2f(h_s[(long)j * 64 + lane]);
    s_e[n * 64 + lane] = acc;
  }
}

// ---------------- fold: binned stats -> BN scale/offset -> packed W + bias
__global__ void fold_kernel(const float* __restrict__ stats, float inv_rows,
                            const void* __restrict__ g, const void* __restrict__ b,
                            const void* __restrict__ W, const void* __restrict__ c,
                            int K, int OUT,
                            u16* __restrict__ Wpack, float* __restrict__ biasOut,
                            const int* __restrict__ modep) {
  const int mode = *modep;
  __shared__ float s_s[96], s_off[96];
  const int tid = threadIdx.x;
  if (tid < K) {
    float sum = 0.f, sq = 0.f;
    for (int p = 0; p < NBIN; p++) {
      sum += stats[p * 2 * K + tid];
      sq  += stats[p * 2 * K + K + tid];
    }
    float m   = sum * inv_rows;
    float var = sq * inv_rows - m * m;
    float s   = loadf(g, tid, mode) * rsqrtf(var + 1e-5f);
    s_s[tid]  = s;
    s_off[tid] = loadf(b, tid, mode) - m * s;
  }
  __syncthreads();
  for (int n = tid; n < OUT; n += blockDim.x) {
    float acc = loadf(c, n, mode);
    for (int k = 0; k < K; k++) acc += s_off[k] * loadf(W, k * OUT + n, mode);
    biasOut[n] = acc;
  }
  const int H = K / 32, T = OUT / 16;
  const int total = T * H * 64 * 8;
  for (int i = tid; i < total; i += blockDim.x) {
    int j = i & 7, lane = (i >> 3) & 63, th = i >> 9;
    int h = th % H, t = th / H;
    int k = h * 32 + (lane >> 4) * 8 + j;
    int n = t * 16 + (lane & 15);
    Wpack[i] = f2bf(s_s[k] * loadf(W, k * OUT + n, mode));
  }
}

// ======== phase-A GEMMs: 64 cols, K=64, 256 rows/block (4 tiles/wave) =======

// GEMM 1: A = [x[row[e]], ea[e]], LReLU, writes DEST-SORTED rows via ipos,
//         epilogue stats -> statsOut[NBIN][128]
__global__ __launch_bounds__(256) void gemm1_kernel(
    const void* __restrict__ x, const void* __restrict__ ea,
    const int* __restrict__ erow, const int* __restrict__ ipos,
    const u16* __restrict__ Wp, const float* __restrict__ bias,
    u16* __restrict__ hout, int E,
    float* __restrict__ statsOut, const int* __restrict__ modep) {
  const int mode = *modep;
  const int lane = threadIdx.x & 63, wave = threadIdx.x >> 6;
  const int q = lane >> 4, r = lane & 15;
  const long wbase = (long)blockIdx.x * 256 + wave * 64;
  bf16x8 bfr[4][2];
#pragma unroll
  for (int t = 0; t < 4; t++)
#pragma unroll
    for (int h = 0; h < 2; h++)
      bfr[t][h] = ldb8(Wp + ((t * 2 + h) * 64 + lane) * 8);
  float bv[4];
#pragma unroll
  for (int t = 0; t < 4; t++) bv[t] = bias[t * 16 + r];
  float s_[4] = {0, 0, 0, 0}, q_[4] = {0, 0, 0, 0};
#pragma unroll
  for (int r4 = 0; r4 < 4; r4++) {
    const long row0 = wbase + r4 * 16;
    long e = row0 + r; if (e > E - 1) e = E - 1;
    int src = erow[e];
    bf16x8 a0 = load8(x, (long)src * 32 + q * 8, mode);
    bf16x8 a1 = load8(ea, e * 32 + q * 8, mode);
    floatx4 acc[4];
#pragma unroll
    for (int t = 0; t < 4; t++) {
      acc[t] = (floatx4){bv[t], bv[t], bv[t], bv[t]};
      acc[t] = mfma16(a0, bfr[t][0], acc[t]);
      acc[t] = mfma16(a1, bfr[t][1], acc[t]);
    }
#pragma unroll
    for (int gi = 0; gi < 4; gi++) {
      long row = row0 + q * 4 + gi;
      if (row < E) {
        long p = ipos[row];
#pragma unroll
        for (int t = 0; t < 4; t++) {
          float v = acc[t][gi];
          v = v > 0.f ? v : 0.1f * v;
          u16 st = f2bf(v);
          hout[p * 64 + t * 16 + r] = st;
          float vv = bf2f(st);
          s_[t] += vv; q_[t] += vv * vv;
        }
      }
    }
  }
  __shared__ float sm[512];
#pragma unroll
  for (int t = 0; t < 4; t++) {
    float s = s_[t], qq = q_[t];
    s  += __shfl_xor(s, 16, 64);  s  += __shfl_xor(s, 32, 64);
    qq += __shfl_xor(qq, 16, 64); qq += __shfl_xor(qq, 32, 64);
    if (lane < 16) { sm[wave * 128 + t * 16 + lane] = s; sm[wave * 128 + 64 + t * 16 + lane] = qq; }
  }
  __syncthreads();
  if (threadIdx.x < 128) {
    int which = threadIdx.x >> 6, c = threadIdx.x & 63;
    float v = 0.f;
    for (int w = 0; w < 4; w++) v += sm[w * 128 + which * 64 + c];
    atomicAdd(statsOut + (blockIdx.x & (NBIN - 1)) * 128 + which * 64 + c, v);
  }
}

// GEMM 2: h_s[E,64] -> h_s[E,64] in place (sorted space), LReLU, stats
__global__ __launch_bounds__(256) void gemm2_kernel(
    const u16* __restrict__ hin, const u16* __restrict__ Wp,
    const float* __restrict__ bias, u16* __restrict__ hout, int E,
    float* __restrict__ statsOut) {
  const int lane = threadIdx.x & 63, wave = threadIdx.x >> 6;
  const int q = lane >> 4, r = lane & 15;
  const long wbase = (long)blockIdx.x * 256 + wave * 64;
  bf16x8 bfr[4][2];
#pragma unroll
  for (int t = 0; t < 4; t++)
#pragma unroll
    for (int h = 0; h < 2; h++)
      bfr[t][h] = ldb8(Wp + ((t * 2 + h) * 64 + lane) * 8);
  float bv[4];
#pragma unroll
  for (int t = 0; t < 4; t++) bv[t] = bias[t * 16 + r];
  float s_[4] = {0, 0, 0, 0}, q_[4] = {0, 0, 0, 0};
#pragma unroll
  for (int r4 = 0; r4 < 4; r4++) {
    const long row0 = wbase + r4 * 16;
    long e = row0 + r; if (e > E - 1) e = E - 1;
    bf16x8 a0 = ldb8(hin + e * 64 + q * 8);
    bf16x8 a1 = ldb8(hin + e * 64 + 32 + q * 8);
    floatx4 acc[4];
#pragma unroll
    for (int t = 0; t < 4; t++) {
      acc[t] = (floatx4){bv[t], bv[t], bv[t], bv[t]};
      acc[t] = mfma16(a0, bfr[t][0], acc[t]);
      acc[t] = mfma16(a1, bfr[t][1], acc[t]);
    }
#pragma unroll
    for (int t = 0; t < 4; t++)
#pragma unroll
      for (int gi = 0; gi < 4; gi++) {
        long row = row0 + q * 4 + gi;
        if (row < E) {
          float v = acc[t][gi];
          v = v > 0.f ? v : 0.1f * v;
          u16 st = f2bf(v);
          hout[row * 64 + t * 16 + r] = st;
          float vv = bf2f(st);
          s_[t] += vv; q_[t] += vv * vv;
        }
      }
  }
  __shared__ float sm[512];
#pragma unroll
  for (int t = 0; t < 4; t++) {
    float s = s_[t], qq = q_[t];
    s  += __shfl_xor(s, 16, 64);  s  += __shfl_xor(s, 32, 64);
    qq += __shfl_xor(qq, 16, 64); qq += __shfl_xor(qq, 32, 64);
    if (lane < 16) { sm[wave * 128 + t * 16 + lane] = s; sm[wave * 128 + 64 + t * 16 + lane] = qq; }
  }
  __syncthreads();
  if (threadIdx.x < 128) {
    int which = threadIdx.x >> 6, c = threadIdx.x & 63;
    float v = 0.f;
    for (int w = 0; w < 4; w++) v += sm[w * 128 + which * 64 + c];
    atomicAdd(statsOut + (blockIdx.x & (NBIN - 1)) * 128 + which * 64 + c, v);
  }
}

// GEMM Agg: agg[n] = bf16(s_e[n]) @ W3' + deg[n]*b3'  (fp32 out) + agg stats
__global__ __launch_bounds__(256) void gemmAgg_kernel(
    const float* __restrict__ s_e, const int* __restrict__ deg,
    const u16* __restrict__ Wp, const float* __restrict__ bias,
    float* __restrict__ agg, int N, float* __restrict__ statsOut) {
  const int lane = threadIdx.x & 63, wave = threadIdx.x >> 6;
  const int q = lane >> 4, r = lane & 15;
  const long wbase = (long)blockIdx.x * 256 + wave * 64;
  bf16x8 bfr[4][2];
#pragma unroll
  for (int t = 0; t < 4; t++)
#pragma unroll
    for (int h = 0; h < 2; h++)
      bfr[t][h] = ldb8(Wp + ((t * 2 + h) * 64 + lane) * 8);
  float bv[4];
#pragma unroll
  for (int t = 0; t < 4; t++) bv[t] = bias[t * 16 + r];
  float s_[4] = {0, 0, 0, 0}, q_[4] = {0, 0, 0, 0};
#pragma unroll
  for (int r4 = 0; r4 < 4; r4++) {
    const long row0 = wbase + r4 * 16;
    long m = row0 + r;
    long mm = m < N ? m : (long)N - 1;
    bf16x8 a0, a1;
    {
      const float* ap = s_e + mm * 64 + q * 8;
#pragma unroll
      for (int j = 0; j < 8; j++) a0[j] = (__bf16)ap[j];
#pragma unroll
      for (int j = 0; j < 8; j++) a1[j] = (__bf16)ap[32 + j];
    }
    floatx4 acc[4];
#pragma unroll
    for (int t = 0; t < 4; t++) {
      acc[t] = (floatx4){0.f, 0.f, 0.f, 0.f};
      acc[t] = mfma16(a0, bfr[t][0], acc[t]);
      acc[t] = mfma16(a1, bfr[t][1], acc[t]);
    }
#pragma unroll
    for (int gi = 0; gi < 4; gi++) {
      long row = row0 + q * 4 + gi;
      if (row < N) {
        float d = (float)deg[row];
#pragma unroll
        for (int t = 0; t < 4; t++) {
          float v = acc[t][gi] + d * bv[t];
          agg[row * 64 + t * 16 + r] = v;
          s_[t] += v; q_[t] += v * v;
        }
      }
    }
  }
  __shared__ float sm[512];
#pragma unroll
  for (int t = 0; t < 4; t++) {
    float s = s_[t], qq = q_[t];
    s  += __shfl_xor(s, 16, 64);  s  += __shfl_xor(s, 32, 64);
    qq += __shfl_xor(qq, 16, 64); qq += __shfl_xor(qq, 32, 64);
    if (lane < 16) { sm[wave * 128 + t * 16 + lane] = s; sm[wave * 128 + 64 + t * 16 + lane] = qq; }
  }
  __syncthreads();
  if (threadIdx.x < 128) {
    int which = threadIdx.x >> 6, c = threadIdx.x & 63;
    float v = 0.f;
    for (int w = 0; w < 4; w++) v += sm[w * 128 + which * 64 + c];
    // statsB0 layout [NBIN][192]: sums [0..95], sumsq [96..191]; agg = cols 32..95
    atomicAdd(statsOut + (blockIdx.x & (NBIN - 1)) * 192 + which * 96 + 32 + c, v);
  }
}

// ======== phase-B GEMMs: 96-wide, 256 rows/block (4 tiles/wave) =============

// GEMM B1: A = [x, agg(fp32)] (K=96 -> 96), LReLU, stats -> statsOut[NBIN][192]
__global__ __launch_bounds__(256) void gemmB1_kernel(
    const void* __restrict__ x, const float* __restrict__ agg,
    const u16* __restrict__ Wp, const float* __restrict__ bias,
    u16* __restrict__ hout, int N, float* __restrict__ statsOut,
    const int* __restrict__ modep) {
  const int mode = *modep;
  const int lane = threadIdx.x & 63, wave = threadIdx.x >> 6;
  const int q = lane >> 4, r = lane & 15;
  const long wbase = (long)blockIdx.x * 256 + wave * 64;
  bf16x8 bfr[6][3];
#pragma unroll
  for (int t = 0; t < 6; t++)
#pragma unroll
    for (int h = 0; h < 3; h++)
      bfr[t][h] = ldb8(Wp + ((t * 3 + h) * 64 + lane) * 8);
  float bv[6];
#pragma unroll
  for (int t = 0; t < 6; t++) bv[t] = bias[t * 16 + r];
  float s_[6] = {0, 0, 0, 0, 0, 0}, q_[6] = {0, 0, 0, 0, 0, 0};
#pragma unroll
  for (int r4 = 0; r4 < 4; r4++) {
    const long row0 = wbase + r4 * 16;
    long m = row0 + r;
    long mm = m < N ? m : (long)N - 1;
    bf16x8 a0 = load8(x, mm * 32 + q * 8, mode);
    bf16x8 a1, a2;
    {
      const float* ap = agg + mm * 64 + q * 8;
#pragma unroll
      for (int j = 0; j < 8; j++) a1[j] = (__bf16)ap[j];
#pragma unroll
      for (int j = 0; j < 8; j++) a2[j] = (__bf16)ap[32 + j];
    }
    floatx4 acc[6];
#pragma unroll
    for (int t = 0; t < 6; t++) {
      acc[t] = (floatx4){bv[t], bv[t], bv[t], bv[t]};
      acc[t] = mfma16(a0, bfr[t][0], acc[t]);
      acc[t] = mfma16(a1, bfr[t][1], acc[t]);
      acc[t] = mfma16(a2, bfr[t][2], acc[t]);
    }
#pragma unroll
    for (int t = 0; t < 6; t++)
#pragma unroll
      for (int gi = 0; gi < 4; gi++) {
        long row = row0 + q * 4 + gi;
        if (row < N) {
          float v = acc[t][gi];
          v = v > 0.f ? v : 0.1f * v;
          u16 st = f2bf(v);
          hout[row * 96 + t * 16 + r] = st;
          float vv = bf2f(st);
          s_[t] += vv; q_[t] += vv * vv;
        }
      }
  }
  __shared__ float sm[768];
#pragma unroll
  for (int t = 0; t < 6; t++) {
    float s = s_[t], qq = q_[t];
    s  += __shfl_xor(s, 16, 64);  s  += __shfl_xor(s, 32, 64);
    qq += __shfl_xor(qq, 16, 64); qq += __shfl_xor(qq, 32, 64);
    if (lane < 16) { sm[wave * 192 + t * 16 + lane] = s; sm[wave * 192 + 96 + t * 16 + lane] = qq; }
  }
  __syncthreads();
  if (threadIdx.x < 192) {
    int which = threadIdx.x / 96, c = threadIdx.x % 96;
    float v = 0.f;
    for (int w = 0; w < 4; w++) v += sm[w * 192 + which * 96 + c];
    atomicAdd(statsOut + (blockIdx.x & (NBIN - 1)) * 192 + which * 96 + c, v);
  }
}

// GEMM B2: h[N,96] -> h[N,96] in place, LReLU, stats
__global__ __launch_bounds__(256) void gemmB2_kernel(
    const u16* __restrict__ hin, const u16* __restrict__ Wp,
    const float* __restrict__ bias, u16* __restrict__ hout, int N,
    float* __restrict__ statsOut) {
  const int lane = threadIdx.x & 63, wave = threadIdx.x >> 6;
  const int q = lane >> 4, r = lane & 15;
  const long wbase = (long)blockIdx.x * 256 + wave * 64;
  bf16x8 bfr[6][3];
#pragma unroll
  for (int t = 0; t < 6; t++)
#pragma unroll
    for (int h = 0; h < 3; h++)
      bfr[t][h] = ldb8(Wp + ((t * 3 + h) * 64 + lane) * 8);
  float bv[6];
#pragma unroll
  for (int t = 0; t < 6; t++) bv[t] = bias[t * 16 + r];
  float s_[6] = {0, 0, 0, 0, 0, 0}, q_[6] = {0, 0, 0, 0, 0, 0};
#pragma unroll
  for (int r4 = 0; r4 < 4; r4++) {
    const long row0 = wbase + r4 * 16;
    long m = row0 + r;
    long mm = m < N ? m : (long)N - 1;
    bf16x8 a0 = ldb8(hin + mm * 96 + q * 8);
    bf16x8 a1 = ldb8(hin + mm * 96 + 32 + q * 8);
    bf16x8 a2 = ldb8(hin + mm * 96 + 64 + q * 8);
    floatx4 acc[6];
#pragma unroll
    for (int t = 0; t < 6; t++) {
      acc[t] = (floatx4){bv[t], bv[t], bv[t], bv[t]};
      acc[t] = mfma16(a0, bfr[t][0], acc[t]);
      acc[t] = mfma16(a1, bfr[t][1], acc[t]);
      acc[t] = mfma16(a2, bfr[t][2], acc[t]);
    }
#pragma unroll
    for (int t = 0; t < 6; t++)
#pragma unroll
      for (int gi = 0; gi < 4; gi++) {
        long row = row0 + q * 4 + gi;
        if (row < N) {
          float v = acc[t][gi];
          v = v > 0.f ? v : 0.1f * v;
          u16 st = f2bf(v);
          hout[row * 96 + t * 16 + r] = st;
          float vv = bf2f(st);
          s_[t] += vv; q_[t] += vv * vv;
        }
      }
  }
  __shared__ float sm[768];
#pragma unroll
  for (int t = 0; t < 6; t++) {
    float s = s_[t], qq = q_[t];
    s  += __shfl_xor(s, 16, 64);  s  += __shfl_xor(s, 32, 64);
    qq += __shfl_xor(qq, 16, 64); qq += __shfl_xor(qq, 32, 64);
    if (lane < 16) { sm[wave * 192 + t * 16 + lane] = s; sm[wave * 192 + 96 + t * 16 + lane] = qq; }
  }
  __syncthreads();
  if (threadIdx.x < 192) {
    int which = threadIdx.x / 96, c = threadIdx.x % 96;
    float v = 0.f;
    for (int w = 0; w < 4; w++) v += sm[w * 192 + which * 96 + c];
    atomicAdd(statsOut + (blockIdx.x & (NBIN - 1)) * 192 + which * 96 + c, v);
  }
}

// GEMM B3: h[N,96] -> out[N,32], no activation, no stats
__global__ __launch_bounds__(256) void gemmB3_kernel(
    const u16* __restrict__ hin, const u16* __restrict__ Wp,
    const float* __restrict__ bias, void* __restrict__ outv, int N,
    const int* __restrict__ modep) {
  const int mode = *modep;
  const int lane = threadIdx.x & 63, wave = threadIdx.x >> 6;
  const int q = lane >> 4, r = lane & 15;
  const long wbase = (long)blockIdx.x * 256 + wave * 64;
  bf16x8 bfr[2][3];
#pragma unroll
  for (int t = 0; t < 2; t++)
#pragma unroll
    for (int h = 0; h < 3; h++)
      bfr[t][h] = ldb8(Wp + ((t * 3 + h) * 64 + lane) * 8);
  float bv[2];
#pragma unroll
  for (int t = 0; t < 2; t++) bv[t] = bias[t * 16 + r];
#pragma unroll
  for (int r4 = 0; r4 < 4; r4++) {
    const long row0 = wbase + r4 * 16;
    long m = row0 + r;
    long mm = m < N ? m : (long)N - 1;
    bf16x8 a0 = ldb8(hin + mm * 96 + q * 8);
    bf16x8 a1 = ldb8(hin + mm * 96 + 32 + q * 8);
    bf16x8 a2 = ldb8(hin + mm * 96 + 64 + q * 8);
    floatx4 acc[2];
#pragma unroll
    for (int t = 0; t < 2; t++) {
      acc[t] = (floatx4){bv[t], bv[t], bv[t], bv[t]};
      acc[t] = mfma16(a0, bfr[t][0], acc[t]);
      acc[t] = mfma16(a1, bfr[t][1], acc[t]);
      acc[t] = mfma16(a2, bfr[t][2], acc[t]);
    }
#pragma unroll
    for (int t = 0; t < 2; t++)
#pragma unroll
      for (int gi = 0; gi < 4; gi++) {
        long row = row0 + q * 4 + gi;
        if (row < N) {
          float v = acc[t][gi];
          if (mode) ((u16*)outv)[row * 32 + t * 16 + r] = f2bf(v);
          else      ((float*)outv)[row * 32 + t * 16 + r] = v;
        }
      }
  }
}

// ---------------------------------------------------------------------------
extern "C" void kernel_launch(void* const* d_in, const int* in_sizes, int n_in,
                              void* d_out, int out_size, void* d_ws,
                              size_t ws_size, hipStream_t stream) {
  const int N = in_sizes[0] / 32;
  const int E = in_sizes[2] / 32;

  const void* x    = d_in[0];
  const int*  eidx = (const int*)d_in[1];  // [2][E]: row=eidx, col=eidx+E
  const void* ea   = d_in[2];
  const void *m1_g1 = d_in[5],  *m1_b1 = d_in[6];
  const void *m1_w1 = d_in[7],  *m1_c1 = d_in[8];
  const void *m1_g2 = d_in[9],  *m1_b2 = d_in[10];
  const void *m1_w2 = d_in[11], *m1_c2 = d_in[12];
  const void *m1_g3 = d_in[13], *m1_b3 = d_in[14];
  const void *m1_w3 = d_in[15], *m1_c3 = d_in[16];
  const void *m2_g1 = d_in[17], *m2_b1 = d_in[18];
  const void *m2_w1 = d_in[19], *m2_c1 = d_in[20];
  const void *m2_g2 = d_in[21], *m2_b2 = d_in[22];
  const void *m2_w2 = d_in[23], *m2_c2 = d_in[24];
  const void *m2_g3 = d_in[25], *m2_b3 = d_in[26];
  const void *m2_w3 = d_in[27], *m2_c3 = d_in[28];

  // workspace carve (16B-aligned chunks)
  char* w = (char*)d_ws;
  int*   modep  = (int*)w;   w += 16;
  u16*   h_s    = (u16*)w;   w += (size_t)E * 64 * 2;       // 102.4 MB (sorted)
  u16*   h2b    = (u16*)w;   w += (size_t)N * 96 * 2;       //  19.2 MB
  float* agg    = (float*)w; w += (size_t)N * 64 * 4;       //  25.6 MB
  float* s_e    = (float*)w; w += (size_t)N * 64 * 4;       //  25.6 MB
  int*   offs   = (int*)w;   w += ((size_t)N + 4) * 4;
  int*   cursor = (int*)w;   w += ((size_t)N + 4) * 4;
  int*   ipos   = (int*)w;   w += (size_t)E * 4;            //   3.2 MB
  int*   bsum   = (int*)w;   w += 1024 * 4;
  // zero zone: deg + odeg + all stats buffers (contiguous)
  int*   deg    = (int*)w;   w += (size_t)N * 4;
  int*   odeg   = (int*)w;   w += (size_t)N * 4;
  float* stats0 = (float*)w; w += NBIN * 128 * 4;
  float* stats1 = (float*)w; w += NBIN * 128 * 4;
  float* stats2 = (float*)w; w += NBIN * 128 * 4;
  float* statsB0= (float*)w; w += NBIN * 192 * 4;
  float* statsB1= (float*)w; w += NBIN * 192 * 4;
  float* statsB2= (float*)w; w += NBIN * 192 * 4;
  const size_t zero_bytes = (size_t)N * 8 + NBIN * (128 * 3 + 192 * 3) * 4;
  u16*   Wp1    = (u16*)w;   w += 4096 * 2;
  float* bias1  = (float*)w; w += 64 * 4;
  u16*   Wp2    = (u16*)w;   w += 4096 * 2;
  float* bias2  = (float*)w; w += 64 * 4;
  u16*   Wp3    = (u16*)w;   w += 4096 * 2;
  float* bias3  = (float*)w; w += 64 * 4;
  u16*   WpB1   = (u16*)w;   w += 9216 * 2;
  float* biasB1 = (float*)w; w += 96 * 4;
  u16*   WpB2   = (u16*)w;   w += 9216 * 2;
  float* biasB2 = (float*)w; w += 96 * 4;
  u16*   WpB3   = (u16*)w;   w += 3072 * 2;
  float* biasB3 = (float*)w; w += 32 * 4;

  const int* erow = eidx;
  const int* ecol = eidx + E;
  const float invE = 1.0f / (float)E, invN = 1.0f / (float)N;
  const int gA = (E + 255) / 256, gB = (N + 255) / 256;
  const int nb = (N + 1023) / 1024;

  detect_kernel<<<1, 256, 0, stream>>>((const u16*)x, modep);
  hipMemsetAsync(deg, 0, zero_bytes, stream);

  // --- counting sort of edges by destination + degree histograms ---
  count2_kernel<<<1024, 256, 0, stream>>>(erow, ecol, E, odeg, deg);
  scan1_kernel<<<nb, 1024, 0, stream>>>(deg, N, offs, bsum);
  scan2_kernel<<<1, 64, 0, stream>>>(bsum, nb, offs, N, E);
  scan3_kernel<<<nb, 1024, 0, stream>>>(offs, bsum, N, cursor);
  scatter_kernel<<<1024, 256, 0, stream>>>(ecol, E, cursor, ipos);

  // --- input stats (no edge-gather: odeg-weighted x stats + streaming ea) ---
  statsXW_kernel<<<512, 256, 0, stream>>>(x, odeg, N, stats0, statsB0, modep);
  statsEA_kernel<<<512, 256, 0, stream>>>(ea, E, stats0, modep);

  // --- phase A: edge MLP (h written destination-sorted) ---
  fold_kernel<<<1, 256, 0, stream>>>(stats0, invE, m1_g1, m1_b1, m1_w1, m1_c1,
                                     64, 64, Wp1, bias1, modep);
  gemm1_kernel<<<gA, 256, 0, stream>>>(x, ea, erow, ipos, Wp1, bias1, h_s, E,
                                       stats1, modep);
  fold_kernel<<<1, 256, 0, stream>>>(stats1, invE, m1_g2, m1_b2, m1_w2, m1_c2,
                                     64, 64, Wp2, bias2, modep);
  gemm2_kernel<<<gA, 256, 0, stream>>>(h_s, Wp2, bias2, h_s, E, stats2);

  // --- aggregation: sequential segment-sum then dense GEMM ---
  aggsum_kernel<<<1024, 256, 0, stream>>>(h_s, offs, s_e, N);
  fold_kernel<<<1, 256, 0, stream>>>(stats2, invE, m1_g3, m1_b3, m1_w3, m1_c3,
                                     64, 64, Wp3, bias3, modep);
  gemmAgg_kernel<<<gB, 256, 0, stream>>>(s_e, deg, Wp3, bias3, agg, N, statsB0);

  // --- phase B: node MLP ---
  fold_kernel<<<1, 256, 0, stream>>>(statsB0, invN, m2_g1, m2_b1, m2_w1, m2_c1,
                                     96, 96, WpB1, biasB1, modep);
  gemmB1_kernel<<<gB, 256, 0, stream>>>(x, agg, WpB1, biasB1, h2b, N,
                                        statsB1, modep);
  fold_kernel<<<1, 256, 0, stream>>>(statsB1, invN, m2_g2, m2_b2, m2_w2, m2_c2,
                                     96, 96, WpB2, biasB2, modep);
  gemmB2_kernel<<<gB, 256, 0, stream>>>(h2b, WpB2, biasB2, h2b, N, statsB2);
  fold_kernel<<<1, 256, 0, stream>>>(statsB2, invN, m2_g3, m2_b3, m2_w3, m2_c3,
                                     96, 32, WpB3, biasB3, modep);
  gemmB3_kernel<<<gB, 256, 0, stream>>>(h2b, WpB3, biasB3, d_out, N, modep);
}

// Round 6
// 697.995 us; speedup vs baseline: 3.3264x; 1.0624x over previous
//
#include <hip/hip_runtime.h>

// ---------------------------------------------------------------------------
// NodeModel (GraphNet node block), MI355X / gfx950.
// v6: gemm2 fuses the per-node segment-sum: sorted output rows staged in
//     LDS (XOR-swizzled, conflict-free), swept per node run -> s_e with one
//     plain store (interior run) or one atomicAdd (block-boundary run).
//     Deletes the 102 MB h2 write + 102 MB aggsum re-read + 1 dispatch.
//     fold kernels stage W via LDS (coalesced); scatter also emits nodeof[].
// Aggregation algebra: agg[n] = (sum_e h2_e) @ W3' + deg[n]*b3' (BN affine
// commutes with segment-sum). Stats fused into GEMM epilogues (binned).
// MFMA layouts (verified): A[m=lane&15][k=(lane>>4)*8+j],
//   B[k=(lane>>4)*8+j][n=lane&15], C/D: col=lane&15, row=(lane>>4)*4+reg.
// Input dtype (fp32 vs bf16 harness mode) detected at runtime.
// ---------------------------------------------------------------------------

typedef unsigned short u16;
typedef __bf16  bf16x8  __attribute__((ext_vector_type(8)));
typedef float   floatx4 __attribute__((ext_vector_type(4)));

#define NBIN 8

__device__ __forceinline__ float bf2f(u16 u) {
  union { float f; unsigned int i; } v; v.i = ((unsigned int)u) << 16; return v.f;
}
__device__ __forceinline__ u16 f2bf(float f) {
  union { float f; unsigned int i; } v; v.f = f;
  unsigned int x = v.i;
  return (u16)((x + 0x7fffu + ((x >> 16) & 1u)) >> 16);  // RNE
}
__device__ __forceinline__ bf16x8 ldb8(const u16* p) {
  return *reinterpret_cast<const bf16x8*>(p);
}
__device__ __forceinline__ floatx4 mfma16(bf16x8 a, bf16x8 b, floatx4 c) {
  return __builtin_amdgcn_mfma_f32_16x16x32_bf16(a, b, c, 0, 0, 0);
}
// mode: 0 = input is float32, 1 = input is bf16
__device__ __forceinline__ float loadf(const void* p, long idx, int mode) {
  return mode ? bf2f(((const u16*)p)[idx]) : ((const float*)p)[idx];
}
__device__ __forceinline__ bf16x8 load8(const void* p, long idx, int mode) {
  if (mode) return ldb8((const u16*)p + idx);
  const float* f = (const float*)p + idx;
  bf16x8 r;
#pragma unroll
  for (int j = 0; j < 8; j++) r[j] = (__bf16)f[j];
  return r;
}

// ---------------- dtype detection
__global__ void detect_kernel(const u16* __restrict__ x, int* __restrict__ modep) {
  __shared__ int cnt;
  if (threadIdx.x == 0) cnt = 0;
  __syncthreads();
  int weird = 0;
  for (int i = threadIdx.x; i < 1024; i += blockDim.x) {
    unsigned e = (x[i] >> 7) & 0xFFu;
    if (e == 0xFFu || e >= 0x90u || (e != 0u && e < 0x60u)) weird++;
  }
  atomicAdd(&cnt, weird);
  __syncthreads();
  if (threadIdx.x == 0) *modep = (cnt > 128) ? 0 : 1;
}

// ================= counting sort of edges by destination ====================
__global__ void count2_kernel(const int* __restrict__ row, const int* __restrict__ col,
                              int E, int* __restrict__ odeg, int* __restrict__ deg) {
  for (int e = blockIdx.x * blockDim.x + threadIdx.x; e < E;
       e += gridDim.x * blockDim.x) {
    atomicAdd(&odeg[row[e]], 1);
    atomicAdd(&deg[col[e]], 1);
  }
}

// per-1024-block exclusive scan; block totals to bsum
__global__ void scan1_kernel(const int* __restrict__ deg, int n,
                             int* __restrict__ excl, int* __restrict__ bsum) {
  __shared__ int tmp[2][1024];
  const int tid = threadIdx.x;
  const int i = blockIdx.x * 1024 + tid;
  int v = (i < n) ? deg[i] : 0;
  tmp[0][tid] = v;
  __syncthreads();
  int src = 0;
  for (int off = 1; off < 1024; off <<= 1) {
    int t = tmp[src][tid];
    if (tid >= off) t += tmp[src][tid - off];
    tmp[1 - src][tid] = t;
    src = 1 - src;
    __syncthreads();
  }
  if (i < n) excl[i] = tmp[src][tid] - v;
  if (tid == 1023) bsum[blockIdx.x] = tmp[src][1023];
}

__global__ void scan2_kernel(int* __restrict__ bsum, int nb,
                             int* __restrict__ offsets, int N, int E) {
  if (threadIdx.x == 0) {
    int run = 0;
    for (int i = 0; i < nb; i++) { int v = bsum[i]; bsum[i] = run; run += v; }
    offsets[N] = E;
  }
}

__global__ void scan3_kernel(int* __restrict__ offsets, const int* __restrict__ bsum,
                             int n, int* __restrict__ cursor) {
  int i = blockIdx.x * 1024 + threadIdx.x;
  if (i < n) {
    int v = offsets[i] + bsum[blockIdx.x];
    offsets[i] = v;
    cursor[i] = v;
  }
}

// edge -> its position in destination-sorted order; nodeof[pos] = dest node
__global__ void scatter_kernel(const int* __restrict__ col, int E,
                               int* __restrict__ cursor, int* __restrict__ ipos,
                               int* __restrict__ nodeof) {
  for (int e = blockIdx.x * blockDim.x + threadIdx.x; e < E;
       e += gridDim.x * blockDim.x) {
    int d = col[e];
    int pos = atomicAdd(&cursor[d], 1);
    ipos[e] = pos;
    nodeof[pos] = d;
  }
}

// ---------------- x stats: unweighted -> statsB0 cols 0..31,
//                  odeg-weighted (== gathered-x stats) -> stats0 cols 0..31
__global__ void statsXW_kernel(const void* __restrict__ x, const int* __restrict__ odeg,
                               int N, float* __restrict__ stats0,
                               float* __restrict__ statsB0,
                               const int* __restrict__ modep) {
  const int mode = *modep;
  const int c = threadIdx.x & 31, rs = threadIdx.x >> 5;  // 8 rows / block-iter
  float s = 0.f, q = 0.f, ws = 0.f, wq = 0.f;
  for (long r = (long)blockIdx.x * 8 + rs; r < N; r += (long)gridDim.x * 8) {
    float v = loadf(x, r * 32 + c, mode);
    float w = (float)odeg[r];
    s += v; q += v * v;
    ws += w * v; wq += w * v * v;
  }
  __shared__ float sm[4][256];
  sm[0][threadIdx.x] = s; sm[1][threadIdx.x] = q;
  sm[2][threadIdx.x] = ws; sm[3][threadIdx.x] = wq;
  __syncthreads();
  if (threadIdx.x < 32) {
    for (int i = 1; i < 8; i++) {
      s  += sm[0][i * 32 + c]; q  += sm[1][i * 32 + c];
      ws += sm[2][i * 32 + c]; wq += sm[3][i * 32 + c];
    }
    const int bin = blockIdx.x & (NBIN - 1);
    atomicAdd(statsB0 + bin * 192 + c, s);
    atomicAdd(statsB0 + bin * 192 + 96 + c, q);
    atomicAdd(stats0 + bin * 128 + c, ws);
    atomicAdd(stats0 + bin * 128 + 64 + c, wq);
  }
}

// ---------------- ea stats: streaming, 8 cols per thread, vector loads
__global__ void statsEA_kernel(const void* __restrict__ ea, int E,
                               float* __restrict__ stats,
                               const int* __restrict__ modep) {
  const int mode = *modep;
  const int cg = threadIdx.x & 3;        // col group: cols cg*8..cg*8+7
  const int rsub = threadIdx.x >> 2;     // 64 rows / block-iter
  float s[8], q[8];
#pragma unroll
  for (int j = 0; j < 8; j++) { s[j] = 0.f; q[j] = 0.f; }
  for (long r = (long)blockIdx.x * 64 + rsub; r < E; r += (long)gridDim.x * 64) {
    if (mode) {
      bf16x8 v = ldb8((const u16*)ea + r * 32 + cg * 8);
#pragma unroll
      for (int j = 0; j < 8; j++) { float f = (float)v[j]; s[j] += f; q[j] += f * f; }
    } else {
      const float* p = (const float*)ea + r * 32 + cg * 8;
      float4 a = *(const float4*)p;
      float4 b = *(const float4*)(p + 4);
      float f0[8] = {a.x, a.y, a.z, a.w, b.x, b.y, b.z, b.w};
#pragma unroll
      for (int j = 0; j < 8; j++) { s[j] += f0[j]; q[j] += f0[j] * f0[j]; }
    }
  }
  const int lane = threadIdx.x & 63;
#pragma unroll
  for (int st = 4; st < 64; st <<= 1) {
#pragma unroll
    for (int j = 0; j < 8; j++) {
      s[j] += __shfl_xor(s[j], st, 64);
      q[j] += __shfl_xor(q[j], st, 64);
    }
  }
  if (lane < 4) {
    float* o = stats + (blockIdx.x & (NBIN - 1)) * 128;
#pragma unroll
    for (int j = 0; j < 8; j++) {
      atomicAdd(o + 32 + lane * 8 + j, s[j]);
      atomicAdd(o + 96 + lane * 8 + j, q[j]);
    }
  }
}

// ---------------- fold: binned stats -> BN scale/offset -> packed W + bias
// W staged through LDS with coalesced loads (avoids strided scalar reads).
__global__ void fold_kernel(const float* __restrict__ stats, float inv_rows,
                            const void* __restrict__ g, const void* __restrict__ b,
                            const void* __restrict__ W, const void* __restrict__ c,
                            int K, int OUT,
                            u16* __restrict__ Wpack, float* __restrict__ biasOut,
                            const int* __restrict__ modep) {
  const int mode = *modep;
  __shared__ float s_s[96], s_off[96];
  __shared__ float wlds[9216];  // up to 96*96
  const int tid = threadIdx.x;
  const int tot = K * OUT;
  for (int i = tid; i < tot; i += blockDim.x) wlds[i] = loadf(W, i, mode);
  if (tid < K) {
    float sum = 0.f, sq = 0.f;
    for (int p = 0; p < NBIN; p++) {
      sum += stats[p * 2 * K + tid];
      sq  += stats[p * 2 * K + K + tid];
    }
    float m   = sum * inv_rows;
    float var = sq * inv_rows - m * m;
    float s   = loadf(g, tid, mode) * rsqrtf(var + 1e-5f);
    s_s[tid]  = s;
    s_off[tid] = loadf(b, tid, mode) - m * s;
  }
  __syncthreads();
  for (int n = tid; n < OUT; n += blockDim.x) {
    float acc = loadf(c, n, mode);
    for (int k = 0; k < K; k++) acc += s_off[k] * wlds[k * OUT + n];
    biasOut[n] = acc;
  }
  const int H = K / 32, T = OUT / 16;
  const int total = T * H * 64 * 8;
  for (int i = tid; i < total; i += blockDim.x) {
    int j = i & 7, lane = (i >> 3) & 63, th = i >> 9;
    int h = th % H, t = th / H;
    int k = h * 32 + (lane >> 4) * 8 + j;
    int n = t * 16 + (lane & 15);
    Wpack[i] = f2bf(s_s[k] * wlds[k * OUT + n]);
  }
}

// ======== phase-A GEMMs: 64 cols, K=64, 256 rows/block (4 tiles/wave) =======

// GEMM 1: A = [x[row[e]], ea[e]], LReLU, writes DEST-SORTED rows via ipos,
//         epilogue stats -> statsOut[NBIN][128]
__global__ __launch_bounds__(256) void gemm1_kernel(
    const void* __restrict__ x, const void* __restrict__ ea,
    const int* __restrict__ erow, const int* __restrict__ ipos,
    const u16* __restrict__ Wp, const float* __restrict__ bias,
    u16* __restrict__ hout, int E,
    float* __restrict__ statsOut, const int* __restrict__ modep) {
  const int mode = *modep;
  const int lane = threadIdx.x & 63, wave = threadIdx.x >> 6;
  const int q = lane >> 4, r = lane & 15;
  const long wbase = (long)blockIdx.x * 256 + wave * 64;
  bf16x8 bfr[4][2];
#pragma unroll
  for (int t = 0; t < 4; t++)
#pragma unroll
    for (int h = 0; h < 2; h++)
      bfr[t][h] = ldb8(Wp + ((t * 2 + h) * 64 + lane) * 8);
  float bv[4];
#pragma unroll
  for (int t = 0; t < 4; t++) bv[t] = bias[t * 16 + r];
  float s_[4] = {0, 0, 0, 0}, q_[4] = {0, 0, 0, 0};
#pragma unroll
  for (int r4 = 0; r4 < 4; r4++) {
    const long row0 = wbase + r4 * 16;
    long e = row0 + r; if (e > E - 1) e = E - 1;
    int src = erow[e];
    bf16x8 a0 = load8(x, (long)src * 32 + q * 8, mode);
    bf16x8 a1 = load8(ea, e * 32 + q * 8, mode);
    floatx4 acc[4];
#pragma unroll
    for (int t = 0; t < 4; t++) {
      acc[t] = (floatx4){bv[t], bv[t], bv[t], bv[t]};
      acc[t] = mfma16(a0, bfr[t][0], acc[t]);
      acc[t] = mfma16(a1, bfr[t][1], acc[t]);
    }
#pragma unroll
    for (int gi = 0; gi < 4; gi++) {
      long row = row0 + q * 4 + gi;
      if (row < E) {
        long p = ipos[row];
#pragma unroll
        for (int t = 0; t < 4; t++) {
          float v = acc[t][gi];
          v = v > 0.f ? v : 0.1f * v;
          u16 st = f2bf(v);
          hout[p * 64 + t * 16 + r] = st;
          float vv = bf2f(st);
          s_[t] += vv; q_[t] += vv * vv;
        }
      }
    }
  }
  __shared__ float sm[512];
#pragma unroll
  for (int t = 0; t < 4; t++) {
    float s = s_[t], qq = q_[t];
    s  += __shfl_xor(s, 16, 64);  s  += __shfl_xor(s, 32, 64);
    qq += __shfl_xor(qq, 16, 64); qq += __shfl_xor(qq, 32, 64);
    if (lane < 16) { sm[wave * 128 + t * 16 + lane] = s; sm[wave * 128 + 64 + t * 16 + lane] = qq; }
  }
  __syncthreads();
  if (threadIdx.x < 128) {
    int which = threadIdx.x >> 6, c = threadIdx.x & 63;
    float v = 0.f;
    for (int w = 0; w < 4; w++) v += sm[w * 128 + which * 64 + c];
    atomicAdd(statsOut + (blockIdx.x & (NBIN - 1)) * 128 + which * 64 + c, v);
  }
}

// GEMM 2 (fused): h_s[E,64] -> LReLU -> LDS tile -> per-node segment sums
//   into s_e[N,64]. Interior runs: plain store. Boundary runs: atomicAdd
//   (s_e pre-zeroed). Also epilogue column stats (BN3 fold input).
// LDS tile XOR-swizzled: stored col = col ^ (((lrow>>2)&3)<<4); for the MFMA
// C-layout write this equals ((t^q)*16 + r) -> conflict-free; the column
// sweep reads one row per instruction (uniform swizzle) -> conflict-free.
__global__ __launch_bounds__(256) void gemm2_kernel(
    const u16* __restrict__ hin, const u16* __restrict__ Wp,
    const float* __restrict__ bias, int E,
    float* __restrict__ statsOut,
    const int* __restrict__ offs, const int* __restrict__ nodeof,
    float* __restrict__ s_e) {
  const int lane = threadIdx.x & 63, wave = threadIdx.x >> 6;
  const int q = lane >> 4, r = lane & 15;
  const long bbase = (long)blockIdx.x * 256;
  const long wbase = bbase + wave * 64;
  __shared__ u16 hs[256 * 64];
  __shared__ float sm[512];
  bf16x8 bfr[4][2];
#pragma unroll
  for (int t = 0; t < 4; t++)
#pragma unroll
    for (int h = 0; h < 2; h++)
      bfr[t][h] = ldb8(Wp + ((t * 2 + h) * 64 + lane) * 8);
  float bv[4];
#pragma unroll
  for (int t = 0; t < 4; t++) bv[t] = bias[t * 16 + r];
  float s_[4] = {0, 0, 0, 0}, q_[4] = {0, 0, 0, 0};
#pragma unroll
  for (int r4 = 0; r4 < 4; r4++) {
    const long row0 = wbase + r4 * 16;
    long e = row0 + r; if (e > E - 1) e = E - 1;
    bf16x8 a0 = ldb8(hin + e * 64 + q * 8);
    bf16x8 a1 = ldb8(hin + e * 64 + 32 + q * 8);
    floatx4 acc[4];
#pragma unroll
    for (int t = 0; t < 4; t++) {
      acc[t] = (floatx4){bv[t], bv[t], bv[t], bv[t]};
      acc[t] = mfma16(a0, bfr[t][0], acc[t]);
      acc[t] = mfma16(a1, bfr[t][1], acc[t]);
    }
    const int lbase = wave * 64 + r4 * 16;
#pragma unroll
    for (int t = 0; t < 4; t++) {
      const int colx = ((t ^ q) << 4) + r;  // swizzled column
#pragma unroll
      for (int gi = 0; gi < 4; gi++) {
        long row = row0 + q * 4 + gi;
        float v = acc[t][gi];
        v = v > 0.f ? v : 0.1f * v;
        u16 st = f2bf(v);
        hs[(lbase + q * 4 + gi) * 64 + colx] = st;
        if (row < E) {
          float vv = bf2f(st);
          s_[t] += vv; q_[t] += vv * vv;
        }
      }
    }
  }
#pragma unroll
  for (int t = 0; t < 4; t++) {
    float s = s_[t], qq = q_[t];
    s  += __shfl_xor(s, 16, 64);  s  += __shfl_xor(s, 32, 64);
    qq += __shfl_xor(qq, 16, 64); qq += __shfl_xor(qq, 32, 64);
    if (lane < 16) { sm[wave * 128 + t * 16 + lane] = s; sm[wave * 128 + 64 + t * 16 + lane] = qq; }
  }
  __syncthreads();
  if (threadIdx.x < 128) {
    int which = threadIdx.x >> 6, c = threadIdx.x & 63;
    float v = 0.f;
    for (int w = 0; w < 4; w++) v += sm[w * 128 + which * 64 + c];
    atomicAdd(statsOut + (blockIdx.x & (NBIN - 1)) * 128 + which * 64 + c, v);
  }
  // ---- segment-sum phase over this block's 256 sorted rows ----
  const long blockEnd = (bbase + 256 < (long)E) ? bbase + 256 : (long)E;
  const int first = nodeof[bbase];
  const int last  = nodeof[blockEnd - 1];
  for (int idx = first + wave; idx <= last; idx += 4) {
    int st = offs[idx], en = offs[idx + 1];
    long cs = st < bbase ? bbase : (long)st;
    long ce = (long)en > blockEnd ? blockEnd : (long)en;
    if (cs >= ce) continue;  // empty (deg-0 nodes rely on memset zero)
    float acc = 0.f;
    for (long i = cs - bbase; i < ce - bbase; i++)
      acc += bf2f(hs[i * 64 + (lane ^ (int)(((i >> 2) & 3) << 4))]);
    if ((long)st >= bbase && (long)en <= blockEnd)
      s_e[(long)idx * 64 + lane] = acc;        // run fully inside block
    else
      atomicAdd(s_e + (long)idx * 64 + lane, acc);  // boundary run
  }
}

// GEMM Agg: agg[n] = bf16(s_e[n]) @ W3' + deg[n]*b3'  (fp32 out) + agg stats
__global__ __launch_bounds__(256) void gemmAgg_kernel(
    const float* __restrict__ s_e, const int* __restrict__ deg,
    const u16* __restrict__ Wp, const float* __restrict__ bias,
    float* __restrict__ agg, int N, float* __restrict__ statsOut) {
  const int lane = threadIdx.x & 63, wave = threadIdx.x >> 6;
  const int q = lane >> 4, r = lane & 15;
  const long wbase = (long)blockIdx.x * 256 + wave * 64;
  bf16x8 bfr[4][2];
#pragma unroll
  for (int t = 0; t < 4; t++)
#pragma unroll
    for (int h = 0; h < 2; h++)
      bfr[t][h] = ldb8(Wp + ((t * 2 + h) * 64 + lane) * 8);
  float bv[4];
#pragma unroll
  for (int t = 0; t < 4; t++) bv[t] = bias[t * 16 + r];
  float s_[4] = {0, 0, 0, 0}, q_[4] = {0, 0, 0, 0};
#pragma unroll
  for (int r4 = 0; r4 < 4; r4++) {
    const long row0 = wbase + r4 * 16;
    long m = row0 + r;
    long mm = m < N ? m : (long)N - 1;
    bf16x8 a0, a1;
    {
      const float* ap = s_e + mm * 64 + q * 8;
#pragma unroll
      for (int j = 0; j < 8; j++) a0[j] = (__bf16)ap[j];
#pragma unroll
      for (int j = 0; j < 8; j++) a1[j] = (__bf16)ap[32 + j];
    }
    floatx4 acc[4];
#pragma unroll
    for (int t = 0; t < 4; t++) {
      acc[t] = (floatx4){0.f, 0.f, 0.f, 0.f};
      acc[t] = mfma16(a0, bfr[t][0], acc[t]);
      acc[t] = mfma16(a1, bfr[t][1], acc[t]);
    }
#pragma unroll
    for (int gi = 0; gi < 4; gi++) {
      long row = row0 + q * 4 + gi;
      if (row < N) {
        float d = (float)deg[row];
#pragma unroll
        for (int t = 0; t < 4; t++) {
          float v = acc[t][gi] + d * bv[t];
          agg[row * 64 + t * 16 + r] = v;
          s_[t] += v; q_[t] += v * v;
        }
      }
    }
  }
  __shared__ float sm[512];
#pragma unroll
  for (int t = 0; t < 4; t++) {
    float s = s_[t], qq = q_[t];
    s  += __shfl_xor(s, 16, 64);  s  += __shfl_xor(s, 32, 64);
    qq += __shfl_xor(qq, 16, 64); qq += __shfl_xor(qq, 32, 64);
    if (lane < 16) { sm[wave * 128 + t * 16 + lane] = s; sm[wave * 128 + 64 + t * 16 + lane] = qq; }
  }
  __syncthreads();
  if (threadIdx.x < 128) {
    int which = threadIdx.x >> 6, c = threadIdx.x & 63;
    float v = 0.f;
    for (int w = 0; w < 4; w++) v += sm[w * 128 + which * 64 + c];
    // statsB0 layout [NBIN][192]: sums [0..95], sumsq [96..191]; agg = cols 32..95
    atomicAdd(statsOut + (blockIdx.x & (NBIN - 1)) * 192 + which * 96 + 32 + c, v);
  }
}

// ======== phase-B GEMMs: 96-wide, 256 rows/block (4 tiles/wave) =============

// GEMM B1: A = [x, agg(fp32)] (K=96 -> 96), LReLU, stats -> statsOut[NBIN][192]
__global__ __launch_bounds__(256) void gemmB1_kernel(
    const void* __restrict__ x, const float* __restrict__ agg,
    const u16* __restrict__ Wp, const float* __restrict__ bias,
    u16* __restrict__ hout, int N, float* __restrict__ statsOut,
    const int* __restrict__ modep) {
  const int mode = *modep;
  const int lane = threadIdx.x & 63, wave = threadIdx.x >> 6;
  const int q = lane >> 4, r = lane & 15;
  const long wbase = (long)blockIdx.x * 256 + wave * 64;
  bf16x8 bfr[6][3];
#pragma unroll
  for (int t = 0; t < 6; t++)
#pragma unroll
    for (int h = 0; h < 3; h++)
      bfr[t][h] = ldb8(Wp + ((t * 3 + h) * 64 + lane) * 8);
  float bv[6];
#pragma unroll
  for (int t = 0; t < 6; t++) bv[t] = bias[t * 16 + r];
  float s_[6] = {0, 0, 0, 0, 0, 0}, q_[6] = {0, 0, 0, 0, 0, 0};
#pragma unroll
  for (int r4 = 0; r4 < 4; r4++) {
    const long row0 = wbase + r4 * 16;
    long m = row0 + r;
    long mm = m < N ? m : (long)N - 1;
    bf16x8 a0 = load8(x, mm * 32 + q * 8, mode);
    bf16x8 a1, a2;
    {
      const float* ap = agg + mm * 64 + q * 8;
#pragma unroll
      for (int j = 0; j < 8; j++) a1[j] = (__bf16)ap[j];
#pragma unroll
      for (int j = 0; j < 8; j++) a2[j] = (__bf16)ap[32 + j];
    }
    floatx4 acc[6];
#pragma unroll
    for (int t = 0; t < 6; t++) {
      acc[t] = (floatx4){bv[t], bv[t], bv[t], bv[t]};
      acc[t] = mfma16(a0, bfr[t][0], acc[t]);
      acc[t] = mfma16(a1, bfr[t][1], acc[t]);
      acc[t] = mfma16(a2, bfr[t][2], acc[t]);
    }
#pragma unroll
    for (int t = 0; t < 6; t++)
#pragma unroll
      for (int gi = 0; gi < 4; gi++) {
        long row = row0 + q * 4 + gi;
        if (row < N) {
          float v = acc[t][gi];
          v = v > 0.f ? v : 0.1f * v;
          u16 st = f2bf(v);
          hout[row * 96 + t * 16 + r] = st;
          float vv = bf2f(st);
          s_[t] += vv; q_[t] += vv * vv;
        }
      }
  }
  __shared__ float sm[768];
#pragma unroll
  for (int t = 0; t < 6; t++) {
    float s = s_[t], qq = q_[t];
    s  += __shfl_xor(s, 16, 64);  s  += __shfl_xor(s, 32, 64);
    qq += __shfl_xor(qq, 16, 64); qq += __shfl_xor(qq, 32, 64);
    if (lane < 16) { sm[wave * 192 + t * 16 + lane] = s; sm[wave * 192 + 96 + t * 16 + lane] = qq; }
  }
  __syncthreads();
  if (threadIdx.x < 192) {
    int which = threadIdx.x / 96, c = threadIdx.x % 96;
    float v = 0.f;
    for (int w = 0; w < 4; w++) v += sm[w * 192 + which * 96 + c];
    atomicAdd(statsOut + (blockIdx.x & (NBIN - 1)) * 192 + which * 96 + c, v);
  }
}

// GEMM B2: h[N,96] -> h[N,96] in place, LReLU, stats
__global__ __launch_bounds__(256) void gemmB2_kernel(
    const u16* __restrict__ hin, const u16* __restrict__ Wp,
    const float* __restrict__ bias, u16* __restrict__ hout, int N,
    float* __restrict__ statsOut) {
  const int lane = threadIdx.x & 63, wave = threadIdx.x >> 6;
  const int q = lane >> 4, r = lane & 15;
  const long wbase = (long)blockIdx.x * 256 + wave * 64;
  bf16x8 bfr[6][3];
#pragma unroll
  for (int t = 0; t < 6; t++)
#pragma unroll
    for (int h = 0; h < 3; h++)
      bfr[t][h] = ldb8(Wp + ((t * 3 + h) * 64 + lane) * 8);
  float bv[6];
#pragma unroll
  for (int t = 0; t < 6; t++) bv[t] = bias[t * 16 + r];
  float s_[6] = {0, 0, 0, 0, 0, 0}, q_[6] = {0, 0, 0, 0, 0, 0};
#pragma unroll
  for (int r4 = 0; r4 < 4; r4++) {
    const long row0 = wbase + r4 * 16;
    long m = row0 + r;
    long mm = m < N ? m : (long)N - 1;
    bf16x8 a0 = ldb8(hin + mm * 96 + q * 8);
    bf16x8 a1 = ldb8(hin + mm * 96 + 32 + q * 8);
    bf16x8 a2 = ldb8(hin + mm * 96 + 64 + q * 8);
    floatx4 acc[6];
#pragma unroll
    for (int t = 0; t < 6; t++) {
      acc[t] = (floatx4){bv[t], bv[t], bv[t], bv[t]};
      acc[t] = mfma16(a0, bfr[t][0], acc[t]);
      acc[t] = mfma16(a1, bfr[t][1], acc[t]);
      acc[t] = mfma16(a2, bfr[t][2], acc[t]);
    }
#pragma unroll
    for (int t = 0; t < 6; t++)
#pragma unroll
      for (int gi = 0; gi < 4; gi++) {
        long row = row0 + q * 4 + gi;
        if (row < N) {
          float v = acc[t][gi];
          v = v > 0.f ? v : 0.1f * v;
          u16 st = f2bf(v);
          hout[row * 96 + t * 16 + r] = st;
          float vv = bf2f(st);
          s_[t] += vv; q_[t] += vv * vv;
        }
      }
  }
  __shared__ float sm[768];
#pragma unroll
  for (int t = 0; t < 6; t++) {
    float s = s_[t], qq = q_[t];
    s  += __shfl_xor(s, 16, 64);  s  += __shfl_xor(s, 32, 64);
    qq += __shfl_xor(qq, 16, 64); qq += __shfl_xor(qq, 32, 64);
    if (lane < 16) { sm[wave * 192 + t * 16 + lane] = s; sm[wave * 192 + 96 + t * 16 + lane] = qq; }
  }
  __syncthreads();
  if (threadIdx.x < 192) {
    int which = threadIdx.x / 96, c = threadIdx.x % 96;
    float v = 0.f;
    for (int w = 0; w < 4; w++) v += sm[w * 192 + which * 96 + c];
    atomicAdd(statsOut + (blockIdx.x & (NBIN - 1)) * 192 + which * 96 + c, v);
  }
}

// GEMM B3: h[N,96] -> out[N,32], no activation, no stats
__global__ __launch_bounds__(256) void gemmB3_kernel(
    const u16* __restrict__ hin, const u16* __restrict__ Wp,
    const float* __restrict__ bias, void* __restrict__ outv, int N,
    const int* __restrict__ modep) {
  const int mode = *modep;
  const int lane = threadIdx.x & 63, wave = threadIdx.x >> 6;
  const int q = lane >> 4, r = lane & 15;
  const long wbase = (long)blockIdx.x * 256 + wave * 64;
  bf16x8 bfr[2][3];
#pragma unroll
  for (int t = 0; t < 2; t++)
#pragma unroll
    for (int h = 0; h < 3; h++)
      bfr[t][h] = ldb8(Wp + ((t * 3 + h) * 64 + lane) * 8);
  float bv[2];
#pragma unroll
  for (int t = 0; t < 2; t++) bv[t] = bias[t * 16 + r];
#pragma unroll
  for (int r4 = 0; r4 < 4; r4++) {
    const long row0 = wbase + r4 * 16;
    long m = row0 + r;
    long mm = m < N ? m : (long)N - 1;
    bf16x8 a0 = ldb8(hin + mm * 96 + q * 8);
    bf16x8 a1 = ldb8(hin + mm * 96 + 32 + q * 8);
    bf16x8 a2 = ldb8(hin + mm * 96 + 64 + q * 8);
    floatx4 acc[2];
#pragma unroll
    for (int t = 0; t < 2; t++) {
      acc[t] = (floatx4){bv[t], bv[t], bv[t], bv[t]};
      acc[t] = mfma16(a0, bfr[t][0], acc[t]);
      acc[t] = mfma16(a1, bfr[t][1], acc[t]);
      acc[t] = mfma16(a2, bfr[t][2], acc[t]);
    }
#pragma unroll
    for (int t = 0; t < 2; t++)
#pragma unroll
      for (int gi = 0; gi < 4; gi++) {
        long row = row0 + q * 4 + gi;
        if (row < N) {
          float v = acc[t][gi];
          if (mode) ((u16*)outv)[row * 32 + t * 16 + r] = f2bf(v);
          else      ((float*)outv)[row * 32 + t * 16 + r] = v;
        }
      }
  }
}

// ---------------------------------------------------------------------------
extern "C" void kernel_launch(void* const* d_in, const int* in_sizes, int n_in,
                              void* d_out, int out_size, void* d_ws,
                              size_t ws_size, hipStream_t stream) {
  const int N = in_sizes[0] / 32;
  const int E = in_sizes[2] / 32;

  const void* x    = d_in[0];
  const int*  eidx = (const int*)d_in[1];  // [2][E]: row=eidx, col=eidx+E
  const void* ea   = d_in[2];
  const void *m1_g1 = d_in[5],  *m1_b1 = d_in[6];
  const void *m1_w1 = d_in[7],  *m1_c1 = d_in[8];
  const void *m1_g2 = d_in[9],  *m1_b2 = d_in[10];
  const void *m1_w2 = d_in[11], *m1_c2 = d_in[12];
  const void *m1_g3 = d_in[13], *m1_b3 = d_in[14];
  const void *m1_w3 = d_in[15], *m1_c3 = d_in[16];
  const void *m2_g1 = d_in[17], *m2_b1 = d_in[18];
  const void *m2_w1 = d_in[19], *m2_c1 = d_in[20];
  const void *m2_g2 = d_in[21], *m2_b2 = d_in[22];
  const void *m2_w2 = d_in[23], *m2_c2 = d_in[24];
  const void *m2_g3 = d_in[25], *m2_b3 = d_in[26];
  const void *m2_w3 = d_in[27], *m2_c3 = d_in[28];

  // workspace carve (16B-aligned chunks)
  char* w = (char*)d_ws;
  int*   modep  = (int*)w;   w += 16;
  u16*   h_s    = (u16*)w;   w += (size_t)E * 64 * 2;       // 102.4 MB (sorted)
  u16*   h2b    = (u16*)w;   w += (size_t)N * 96 * 2;       //  19.2 MB
  float* agg    = (float*)w; w += (size_t)N * 64 * 4;       //  25.6 MB
  int*   offs   = (int*)w;   w += ((size_t)N + 4) * 4;
  int*   cursor = (int*)w;   w += ((size_t)N + 4) * 4;
  int*   ipos   = (int*)w;   w += (size_t)E * 4;            //   3.2 MB
  int*   nodeof = (int*)w;   w += (size_t)E * 4;            //   3.2 MB
  int*   bsum   = (int*)w;   w += 1024 * 4;
  // zero zone: s_e + deg + odeg + all stats buffers (contiguous)
  float* s_e    = (float*)w; w += (size_t)N * 64 * 4;       //  25.6 MB
  int*   deg    = (int*)w;   w += (size_t)N * 4;
  int*   odeg   = (int*)w;   w += (size_t)N * 4;
  float* stats0 = (float*)w; w += NBIN * 128 * 4;
  float* stats1 = (float*)w; w += NBIN * 128 * 4;
  float* stats2 = (float*)w; w += NBIN * 128 * 4;
  float* statsB0= (float*)w; w += NBIN * 192 * 4;
  float* statsB1= (float*)w; w += NBIN * 192 * 4;
  float* statsB2= (float*)w; w += NBIN * 192 * 4;
  const size_t zero_bytes = (size_t)N * 64 * 4 + (size_t)N * 8 +
                            NBIN * (128 * 3 + 192 * 3) * 4;
  u16*   Wp1    = (u16*)w;   w += 4096 * 2;
  float* bias1  = (float*)w; w += 64 * 4;
  u16*   Wp2    = (u16*)w;   w += 4096 * 2;
  float* bias2  = (float*)w; w += 64 * 4;
  u16*   Wp3    = (u16*)w;   w += 4096 * 2;
  float* bias3  = (float*)w; w += 64 * 4;
  u16*   WpB1   = (u16*)w;   w += 9216 * 2;
  float* biasB1 = (float*)w; w += 96 * 4;
  u16*   WpB2   = (u16*)w;   w += 9216 * 2;
  float* biasB2 = (float*)w; w += 96 * 4;
  u16*   WpB3   = (u16*)w;   w += 3072 * 2;
  float* biasB3 = (float*)w; w += 32 * 4;

  const int* erow = eidx;
  const int* ecol = eidx + E;
  const float invE = 1.0f / (float)E, invN = 1.0f / (float)N;
  const int gA = (E + 255) / 256, gB = (N + 255) / 256;
  const int nb = (N + 1023) / 1024;

  detect_kernel<<<1, 256, 0, stream>>>((const u16*)x, modep);
  hipMemsetAsync(s_e, 0, zero_bytes, stream);

  // --- counting sort of edges by destination + degree histograms ---
  count2_kernel<<<1024, 256, 0, stream>>>(erow, ecol, E, odeg, deg);
  scan1_kernel<<<nb, 1024, 0, stream>>>(deg, N, offs, bsum);
  scan2_kernel<<<1, 64, 0, stream>>>(bsum, nb, offs, N, E);
  scan3_kernel<<<nb, 1024, 0, stream>>>(offs, bsum, N, cursor);
  scatter_kernel<<<1024, 256, 0, stream>>>(ecol, E, cursor, ipos, nodeof);

  // --- input stats (odeg-weighted x stats + streaming ea stats) ---
  statsXW_kernel<<<512, 256, 0, stream>>>(x, odeg, N, stats0, statsB0, modep);
  statsEA_kernel<<<512, 256, 0, stream>>>(ea, E, stats0, modep);

  // --- phase A: edge MLP (h written destination-sorted) ---
  fold_kernel<<<1, 256, 0, stream>>>(stats0, invE, m1_g1, m1_b1, m1_w1, m1_c1,
                                     64, 64, Wp1, bias1, modep);
  gemm1_kernel<<<gA, 256, 0, stream>>>(x, ea, erow, ipos, Wp1, bias1, h_s, E,
                                       stats1, modep);
  fold_kernel<<<1, 256, 0, stream>>>(stats1, invE, m1_g2, m1_b2, m1_w2, m1_c2,
                                     64, 64, Wp2, bias2, modep);
  gemm2_kernel<<<gA, 256, 0, stream>>>(h_s, Wp2, bias2, E, stats2,
                                       offs, nodeof, s_e);

  // --- aggregation GEMM: agg = bf16(s_e) @ W3' + deg*b3' ---
  fold_kernel<<<1, 256, 0, stream>>>(stats2, invE, m1_g3, m1_b3, m1_w3, m1_c3,
                                     64, 64, Wp3, bias3, modep);
  gemmAgg_kernel<<<gB, 256, 0, stream>>>(s_e, deg, Wp3, bias3, agg, N, statsB0);

  // --- phase B: node MLP ---
  fold_kernel<<<1, 256, 0, stream>>>(statsB0, invN, m2_g1, m2_b1, m2_w1, m2_c1,
                                     96, 96, WpB1, biasB1, modep);
  gemmB1_kernel<<<gB, 256, 0, stream>>>(x, agg, WpB1, biasB1, h2b, N,
                                        statsB1, modep);
  fold_kernel<<<1, 256, 0, stream>>>(statsB1, invN, m2_g2, m2_b2, m2_w2, m2_c2,
                                     96, 96, WpB2, biasB2, modep);
  gemmB2_kernel<<<gB, 256, 0, stream>>>(h2b, WpB2, biasB2, h2b, N, statsB2);
  fold_kernel<<<1, 256, 0, stream>>>(statsB2, invN, m2_g3, m2_b3, m2_w3, m2_c3,
                                     96, 32, WpB3, biasB3, modep);
  gemmB3_kernel<<<gB, 256, 0, stream>>>(h2b, WpB3, biasB3, d_out, N, modep);
}

// Round 7
// 688.757 us; speedup vs baseline: 3.3710x; 1.0134x over previous
//
#include <hip/hip_runtime.h>

// ---------------------------------------------------------------------------
// NodeModel (GraphNet node block), MI355X / gfx950.
// v7: BN-folds inlined into every GEMM block (no fold dispatches), stats
//     kernels merged, scan2 parallelized, gemm1 gathers from pre-converted
//     bf16 xb/eab with hoisted loads (ILP), agg passed as bf16.
// Aggregation: h written dest-sorted (ipos), gemm2 fuses LDS segment-sum
// -> s_e; agg[n] = bf16(s_e[n]) @ W3' + deg[n]*b3' (BN affine commutes).
// MFMA layouts (verified): A[m=lane&15][k=(lane>>4)*8+j],
//   B[k=(lane>>4)*8+j][n=lane&15], C/D: col=lane&15, row=(lane>>4)*4+reg.
// Input dtype (fp32 vs bf16 harness) detected at runtime (empirically fp32).
// ---------------------------------------------------------------------------

typedef unsigned short u16;
typedef __bf16  bf16x8  __attribute__((ext_vector_type(8)));
typedef float   floatx4 __attribute__((ext_vector_type(4)));

#define NBIN 8

__device__ __forceinline__ float bf2f(u16 u) {
  union { float f; unsigned int i; } v; v.i = ((unsigned int)u) << 16; return v.f;
}
__device__ __forceinline__ u16 f2bf(float f) {
  union { float f; unsigned int i; } v; v.f = f;
  unsigned int x = v.i;
  return (u16)((x + 0x7fffu + ((x >> 16) & 1u)) >> 16);  // RNE
}
__device__ __forceinline__ bf16x8 ldb8(const u16* p) {
  return *reinterpret_cast<const bf16x8*>(p);
}
__device__ __forceinline__ floatx4 mfma16(bf16x8 a, bf16x8 b, floatx4 c) {
  return __builtin_amdgcn_mfma_f32_16x16x32_bf16(a, b, c, 0, 0, 0);
}
// mode: 0 = float32, 1 = bf16
__device__ __forceinline__ float loadf(const void* p, long idx, int mode) {
  return mode ? bf2f(((const u16*)p)[idx]) : ((const float*)p)[idx];
}
__device__ __forceinline__ bf16x8 load8(const void* p, long idx, int mode) {
  if (mode) return ldb8((const u16*)p + idx);
  const float* f = (const float*)p + idx;
  bf16x8 r;
#pragma unroll
  for (int j = 0; j < 8; j++) r[j] = (__bf16)f[j];
  return r;
}

// ---------------- per-block BN fold: stats -> scale/offset -> packed W+bias
// wlds: K*OUT u16 LDS, wpack: same size, s_s/s_off: K floats, sbias: OUT.
__device__ __forceinline__ void fold_block(
    const float* __restrict__ stats, float inv_rows,
    const void* __restrict__ g, const void* __restrict__ b,
    const void* __restrict__ W, const void* __restrict__ c,
    int K, int OUT, int mode,
    u16* wlds, u16* wpack, float* s_s, float* s_off, float* sbias) {
  const int tid = threadIdx.x;
  const int tot = K * OUT;
  for (int i = tid; i < tot; i += 256)
    wlds[i] = mode ? ((const u16*)W)[i] : f2bf(((const float*)W)[i]);
  if (tid < K) {
    float sum = 0.f, sq = 0.f;
    for (int p = 0; p < NBIN; p++) {
      sum += stats[p * 2 * K + tid];
      sq  += stats[p * 2 * K + K + tid];
    }
    float m = sum * inv_rows, var = sq * inv_rows - m * m;
    float s = loadf(g, tid, mode) * rsqrtf(var + 1e-5f);
    s_s[tid] = s;
    s_off[tid] = loadf(b, tid, mode) - m * s;
  }
  __syncthreads();
  if (tid < OUT) {
    float acc = loadf(c, tid, mode);
    for (int k = 0; k < K; k++) acc += s_off[k] * bf2f(wlds[k * OUT + tid]);
    sbias[tid] = acc;
  }
  const int H = K >> 5, T = OUT >> 4;
  const int total = T * H * 512;
  for (int i = tid; i < total; i += 256) {
    int j = i & 7, lane = (i >> 3) & 63, th = i >> 9;
    int h = th % H, t = th / H;
    int k = h * 32 + ((lane >> 4) << 3) + j;
    int n = (t << 4) + (lane & 15);
    wpack[i] = f2bf(s_s[k] * bf2f(wlds[k * OUT + n]));
  }
  __syncthreads();
}

// ---------------- dtype detection
__global__ void detect_kernel(const u16* __restrict__ x, int* __restrict__ modep) {
  __shared__ int cnt;
  if (threadIdx.x == 0) cnt = 0;
  __syncthreads();
  int weird = 0;
  for (int i = threadIdx.x; i < 1024; i += blockDim.x) {
    unsigned e = (x[i] >> 7) & 0xFFu;
    if (e == 0xFFu || e >= 0x90u || (e != 0u && e < 0x60u)) weird++;
  }
  atomicAdd(&cnt, weird);
  __syncthreads();
  if (threadIdx.x == 0) *modep = (cnt > 128) ? 0 : 1;
}

// ================= counting sort of edges by destination ====================
__global__ void count2_kernel(const int* __restrict__ row, const int* __restrict__ col,
                              int E, int* __restrict__ odeg, int* __restrict__ deg) {
  for (int e = blockIdx.x * blockDim.x + threadIdx.x; e < E;
       e += gridDim.x * blockDim.x) {
    atomicAdd(&odeg[row[e]], 1);
    atomicAdd(&deg[col[e]], 1);
  }
}

__global__ void scan1_kernel(const int* __restrict__ deg, int n,
                             int* __restrict__ excl, int* __restrict__ bsum) {
  __shared__ int tmp[2][1024];
  const int tid = threadIdx.x;
  const int i = blockIdx.x * 1024 + tid;
  int v = (i < n) ? deg[i] : 0;
  tmp[0][tid] = v;
  __syncthreads();
  int src = 0;
  for (int off = 1; off < 1024; off <<= 1) {
    int t = tmp[src][tid];
    if (tid >= off) t += tmp[src][tid - off];
    tmp[1 - src][tid] = t;
    src = 1 - src;
    __syncthreads();
  }
  if (i < n) excl[i] = tmp[src][tid] - v;
  if (tid == 1023) bsum[blockIdx.x] = tmp[src][1023];
}

// parallel exclusive scan of up to 1024 block sums
__global__ void scan2_kernel(int* __restrict__ bsum, int nb,
                             int* __restrict__ offsets, int N, int E) {
  __shared__ int tmp[2][1024];
  const int tid = threadIdx.x;
  int v = (tid < nb) ? bsum[tid] : 0;
  tmp[0][tid] = v;
  __syncthreads();
  int src = 0;
  for (int off = 1; off < 1024; off <<= 1) {
    int t = tmp[src][tid];
    if (tid >= off) t += tmp[src][tid - off];
    tmp[1 - src][tid] = t;
    src = 1 - src;
    __syncthreads();
  }
  if (tid < nb) bsum[tid] = tmp[src][tid] - v;
  if (tid == 0) offsets[N] = E;
}

__global__ void scan3_kernel(int* __restrict__ offsets, const int* __restrict__ bsum,
                             int n, int* __restrict__ cursor) {
  int i = blockIdx.x * 1024 + threadIdx.x;
  if (i < n) {
    int v = offsets[i] + bsum[blockIdx.x];
    offsets[i] = v;
    cursor[i] = v;
  }
}

__global__ void scatter_kernel(const int* __restrict__ col, int E,
                               int* __restrict__ cursor, int* __restrict__ ipos,
                               int* __restrict__ nodeof) {
  for (int e = blockIdx.x * blockDim.x + threadIdx.x; e < E;
       e += gridDim.x * blockDim.x) {
    int d = col[e];
    int pos = atomicAdd(&cursor[d], 1);
    ipos[e] = pos;
    nodeof[pos] = d;
  }
}

// ---------------- merged input stats:
// blocks [0,512): x pass -> unweighted stats (statsB0 c0..31), odeg-weighted
//   (stats0 c0..31), and xb = bf16(x).
// blocks [512,1024): ea streaming pass -> stats0 c32..63, optional eab.
__global__ void stats_in_kernel(const void* __restrict__ x,
                                const int* __restrict__ odeg, int N,
                                const void* __restrict__ ea, int E,
                                float* __restrict__ stats0,
                                float* __restrict__ statsB0,
                                u16* __restrict__ xb, u16* __restrict__ eab,
                                const int* __restrict__ modep) {
  const int mode = *modep;
  if (blockIdx.x < 512) {
    const int c = threadIdx.x & 31, rs = threadIdx.x >> 5;  // 8 rows/iter
    float s = 0.f, q = 0.f, ws = 0.f, wq = 0.f;
    for (long rr = (long)blockIdx.x * 8 + rs; rr < N; rr += 512 * 8) {
      float v = loadf(x, rr * 32 + c, mode);
      float w = (float)odeg[rr];
      xb[rr * 32 + c] = f2bf(v);
      s += v; q += v * v; ws += w * v; wq += w * v * v;
    }
    __shared__ float sm[4][256];
    sm[0][threadIdx.x] = s;  sm[1][threadIdx.x] = q;
    sm[2][threadIdx.x] = ws; sm[3][threadIdx.x] = wq;
    __syncthreads();
    if (threadIdx.x < 32) {
      for (int i = 1; i < 8; i++) {
        s  += sm[0][i * 32 + c]; q  += sm[1][i * 32 + c];
        ws += sm[2][i * 32 + c]; wq += sm[3][i * 32 + c];
      }
      const int bin = blockIdx.x & (NBIN - 1);
      atomicAdd(statsB0 + bin * 192 + c, s);
      atomicAdd(statsB0 + bin * 192 + 96 + c, q);
      atomicAdd(stats0 + bin * 128 + c, ws);
      atomicAdd(stats0 + bin * 128 + 64 + c, wq);
    }
  } else {
    const int bid = blockIdx.x - 512;
    const int cg = threadIdx.x & 3, rsub = threadIdx.x >> 2;  // 64 rows/iter
    float s[8], q[8];
#pragma unroll
    for (int j = 0; j < 8; j++) { s[j] = 0.f; q[j] = 0.f; }
    for (long rr = (long)bid * 64 + rsub; rr < E; rr += 512 * 64) {
      float f0[8];
      if (mode) {
        bf16x8 v = ldb8((const u16*)ea + rr * 32 + cg * 8);
#pragma unroll
        for (int j = 0; j < 8; j++) f0[j] = (float)v[j];
      } else {
        const float* p = (const float*)ea + rr * 32 + cg * 8;
        float4 a = *(const float4*)p;
        float4 b = *(const float4*)(p + 4);
        f0[0]=a.x; f0[1]=a.y; f0[2]=a.z; f0[3]=a.w;
        f0[4]=b.x; f0[5]=b.y; f0[6]=b.z; f0[7]=b.w;
      }
      if (eab) {
        bf16x8 o;
#pragma unroll
        for (int j = 0; j < 8; j++) o[j] = (__bf16)f0[j];
        *reinterpret_cast<bf16x8*>(eab + rr * 32 + cg * 8) = o;
      }
#pragma unroll
      for (int j = 0; j < 8; j++) { s[j] += f0[j]; q[j] += f0[j] * f0[j]; }
    }
    const int lane = threadIdx.x & 63;
#pragma unroll
    for (int st = 4; st < 64; st <<= 1) {
#pragma unroll
      for (int j = 0; j < 8; j++) {
        s[j] += __shfl_xor(s[j], st, 64);
        q[j] += __shfl_xor(q[j], st, 64);
      }
    }
    if (lane < 4) {
      float* o = stats0 + (blockIdx.x & (NBIN - 1)) * 128;
#pragma unroll
      for (int j = 0; j < 8; j++) {
        atomicAdd(o + 32 + lane * 8 + j, s[j]);
        atomicAdd(o + 96 + lane * 8 + j, q[j]);
      }
    }
  }
}

// ======== GEMM 1: [xb[row[e]], ea[e]] -> h (dest-sorted), LReLU, stats ======
__global__ __launch_bounds__(256) void gemm1_kernel(
    const u16* __restrict__ xb, const void* __restrict__ ea, int eamode,
    const int* __restrict__ erow, const int* __restrict__ ipos,
    const float* __restrict__ stats0, float invE,
    const void* __restrict__ g, const void* __restrict__ b,
    const void* __restrict__ W, const void* __restrict__ c,
    u16* __restrict__ hout, int E,
    float* __restrict__ statsOut, const int* __restrict__ modep) {
  __shared__ u16 wlds[4096], wpack[4096];
  __shared__ float s_s[64], s_off[64], sbias[64];
  __shared__ float sm[512];
  const int mode = *modep;
  const int em = eamode >= 0 ? eamode : mode;
  fold_block(stats0, invE, g, b, W, c, 64, 64, mode, wlds, wpack, s_s, s_off, sbias);
  const int lane = threadIdx.x & 63, wave = threadIdx.x >> 6;
  const int q = lane >> 4, r = lane & 15;
  const long wbase = (long)blockIdx.x * 256 + wave * 64;
  bf16x8 bfr[4][2];
#pragma unroll
  for (int t = 0; t < 4; t++)
#pragma unroll
    for (int h = 0; h < 2; h++)
      bfr[t][h] = *reinterpret_cast<const bf16x8*>(wpack + ((t * 2 + h) * 64 + lane) * 8);
  float bv[4];
#pragma unroll
  for (int t = 0; t < 4; t++) bv[t] = sbias[t * 16 + r];
  // hoisted gather phase (max outstanding loads)
  bf16x8 a0v[4], a1v[4];
  int pv[4][4];
#pragma unroll
  for (int r4 = 0; r4 < 4; r4++) {
    long e = wbase + r4 * 16 + r; if (e > E - 1) e = E - 1;
    int src = erow[e];
    a0v[r4] = ldb8(xb + (long)src * 32 + q * 8);
    a1v[r4] = load8(ea, e * 32 + q * 8, em);
#pragma unroll
    for (int gi = 0; gi < 4; gi++) {
      long row = wbase + r4 * 16 + q * 4 + gi;
      pv[r4][gi] = (row < E) ? ipos[row] : -1;
    }
  }
  float s_[4] = {0, 0, 0, 0}, q_[4] = {0, 0, 0, 0};
#pragma unroll
  for (int r4 = 0; r4 < 4; r4++) {
    floatx4 acc[4];
#pragma unroll
    for (int t = 0; t < 4; t++) {
      acc[t] = (floatx4){bv[t], bv[t], bv[t], bv[t]};
      acc[t] = mfma16(a0v[r4], bfr[t][0], acc[t]);
      acc[t] = mfma16(a1v[r4], bfr[t][1], acc[t]);
    }
#pragma unroll
    for (int gi = 0; gi < 4; gi++) {
      long p = pv[r4][gi];
      if (p >= 0) {
#pragma unroll
        for (int t = 0; t < 4; t++) {
          float v = acc[t][gi];
          v = v > 0.f ? v : 0.1f * v;
          u16 st = f2bf(v);
          hout[p * 64 + t * 16 + r] = st;
          float vv = bf2f(st);
          s_[t] += vv; q_[t] += vv * vv;
        }
      }
    }
  }
#pragma unroll
  for (int t = 0; t < 4; t++) {
    float s = s_[t], qq = q_[t];
    s  += __shfl_xor(s, 16, 64);  s  += __shfl_xor(s, 32, 64);
    qq += __shfl_xor(qq, 16, 64); qq += __shfl_xor(qq, 32, 64);
    if (lane < 16) { sm[wave * 128 + t * 16 + lane] = s; sm[wave * 128 + 64 + t * 16 + lane] = qq; }
  }
  __syncthreads();
  if (threadIdx.x < 128) {
    int which = threadIdx.x >> 6, cc = threadIdx.x & 63;
    float v = 0.f;
    for (int w = 0; w < 4; w++) v += sm[w * 128 + which * 64 + cc];
    atomicAdd(statsOut + (blockIdx.x & (NBIN - 1)) * 128 + which * 64 + cc, v);
  }
}

// ======== GEMM 2 (fused): h_s -> LReLU -> LDS -> per-node segsum -> s_e =====
__global__ __launch_bounds__(256) void gemm2_kernel(
    const u16* __restrict__ hin,
    const float* __restrict__ stats1, float invE,
    const void* __restrict__ g, const void* __restrict__ b,
    const void* __restrict__ W, const void* __restrict__ c,
    int E, float* __restrict__ statsOut,
    const int* __restrict__ offs, const int* __restrict__ nodeof,
    float* __restrict__ s_e, const int* __restrict__ modep) {
  __shared__ u16 wlds[4096], wpack[4096];
  __shared__ float s_s[64], s_off[64], sbias[64];
  __shared__ u16 hs[256 * 64];
  __shared__ float sm[512];
  const int mode = *modep;
  fold_block(stats1, invE, g, b, W, c, 64, 64, mode, wlds, wpack, s_s, s_off, sbias);
  const int lane = threadIdx.x & 63, wave = threadIdx.x >> 6;
  const int q = lane >> 4, r = lane & 15;
  const long bbase = (long)blockIdx.x * 256;
  const long wbase = bbase + wave * 64;
  bf16x8 bfr[4][2];
#pragma unroll
  for (int t = 0; t < 4; t++)
#pragma unroll
    for (int h = 0; h < 2; h++)
      bfr[t][h] = *reinterpret_cast<const bf16x8*>(wpack + ((t * 2 + h) * 64 + lane) * 8);
  float bv[4];
#pragma unroll
  for (int t = 0; t < 4; t++) bv[t] = sbias[t * 16 + r];
  float s_[4] = {0, 0, 0, 0}, q_[4] = {0, 0, 0, 0};
#pragma unroll
  for (int r4 = 0; r4 < 4; r4++) {
    const long row0 = wbase + r4 * 16;
    long e = row0 + r; if (e > E - 1) e = E - 1;
    bf16x8 a0 = ldb8(hin + e * 64 + q * 8);
    bf16x8 a1 = ldb8(hin + e * 64 + 32 + q * 8);
    floatx4 acc[4];
#pragma unroll
    for (int t = 0; t < 4; t++) {
      acc[t] = (floatx4){bv[t], bv[t], bv[t], bv[t]};
      acc[t] = mfma16(a0, bfr[t][0], acc[t]);
      acc[t] = mfma16(a1, bfr[t][1], acc[t]);
    }
    const int lbase = wave * 64 + r4 * 16;
#pragma unroll
    for (int t = 0; t < 4; t++) {
      const int colx = ((t ^ q) << 4) + r;  // XOR swizzle: conflict-free
#pragma unroll
      for (int gi = 0; gi < 4; gi++) {
        long row = row0 + q * 4 + gi;
        float v = acc[t][gi];
        v = v > 0.f ? v : 0.1f * v;
        u16 st = f2bf(v);
        hs[(lbase + q * 4 + gi) * 64 + colx] = st;
        if (row < E) {
          float vv = bf2f(st);
          s_[t] += vv; q_[t] += vv * vv;
        }
      }
    }
  }
#pragma unroll
  for (int t = 0; t < 4; t++) {
    float s = s_[t], qq = q_[t];
    s  += __shfl_xor(s, 16, 64);  s  += __shfl_xor(s, 32, 64);
    qq += __shfl_xor(qq, 16, 64); qq += __shfl_xor(qq, 32, 64);
    if (lane < 16) { sm[wave * 128 + t * 16 + lane] = s; sm[wave * 128 + 64 + t * 16 + lane] = qq; }
  }
  __syncthreads();
  if (threadIdx.x < 128) {
    int which = threadIdx.x >> 6, cc = threadIdx.x & 63;
    float v = 0.f;
    for (int w = 0; w < 4; w++) v += sm[w * 128 + which * 64 + cc];
    atomicAdd(statsOut + (blockIdx.x & (NBIN - 1)) * 128 + which * 64 + cc, v);
  }
  // ---- segment-sum over this block's 256 sorted rows ----
  const long blockEnd = (bbase + 256 < (long)E) ? bbase + 256 : (long)E;
  const int first = nodeof[bbase];
  const int last  = nodeof[blockEnd - 1];
  for (int idx = first + wave; idx <= last; idx += 4) {
    int st = offs[idx], en = offs[idx + 1];
    long cs = st < bbase ? bbase : (long)st;
    long ce = (long)en > blockEnd ? blockEnd : (long)en;
    if (cs >= ce) continue;
    float acc = 0.f;
    for (long i = cs - bbase; i < ce - bbase; i++)
      acc += bf2f(hs[i * 64 + (lane ^ (int)(((i >> 2) & 3) << 4))]);
    if ((long)st >= bbase && (long)en <= blockEnd)
      s_e[(long)idx * 64 + lane] = acc;
    else
      atomicAdd(s_e + (long)idx * 64 + lane, acc);
  }
}

// ======== GEMM Agg: agg_b[n] = bf16( bf16(s_e[n]) @ W3' + deg[n]*b3' ) ======
__global__ __launch_bounds__(256) void gemmAgg_kernel(
    const float* __restrict__ s_e, const int* __restrict__ deg,
    const float* __restrict__ stats2, float invE,
    const void* __restrict__ g, const void* __restrict__ b,
    const void* __restrict__ W, const void* __restrict__ c,
    u16* __restrict__ agg_b, int N, float* __restrict__ statsOut,
    const int* __restrict__ modep) {
  __shared__ u16 wlds[4096], wpack[4096];
  __shared__ float s_s[64], s_off[64], sbias[64];
  __shared__ float sm[512];
  const int mode = *modep;
  fold_block(stats2, invE, g, b, W, c, 64, 64, mode, wlds, wpack, s_s, s_off, sbias);
  const int lane = threadIdx.x & 63, wave = threadIdx.x >> 6;
  const int q = lane >> 4, r = lane & 15;
  const long wbase = (long)blockIdx.x * 256 + wave * 64;
  bf16x8 bfr[4][2];
#pragma unroll
  for (int t = 0; t < 4; t++)
#pragma unroll
    for (int h = 0; h < 2; h++)
      bfr[t][h] = *reinterpret_cast<const bf16x8*>(wpack + ((t * 2 + h) * 64 + lane) * 8);
  float bv[4];
#pragma unroll
  for (int t = 0; t < 4; t++) bv[t] = sbias[t * 16 + r];
  float s_[4] = {0, 0, 0, 0}, q_[4] = {0, 0, 0, 0};
#pragma unroll
  for (int r4 = 0; r4 < 4; r4++) {
    const long row0 = wbase + r4 * 16;
    long m = row0 + r;
    long mm = m < N ? m : (long)N - 1;
    bf16x8 a0, a1;
    {
      const float* ap = s_e + mm * 64 + q * 8;
#pragma unroll
      for (int j = 0; j < 8; j++) a0[j] = (__bf16)ap[j];
#pragma unroll
      for (int j = 0; j < 8; j++) a1[j] = (__bf16)ap[32 + j];
    }
    floatx4 acc[4];
#pragma unroll
    for (int t = 0; t < 4; t++) {
      acc[t] = (floatx4){0.f, 0.f, 0.f, 0.f};
      acc[t] = mfma16(a0, bfr[t][0], acc[t]);
      acc[t] = mfma16(a1, bfr[t][1], acc[t]);
    }
#pragma unroll
    for (int gi = 0; gi < 4; gi++) {
      long row = row0 + q * 4 + gi;
      if (row < N) {
        float d = (float)deg[row];
#pragma unroll
        for (int t = 0; t < 4; t++) {
          float v = acc[t][gi] + d * bv[t];
          agg_b[row * 64 + t * 16 + r] = f2bf(v);
          s_[t] += v; q_[t] += v * v;
        }
      }
    }
  }
#pragma unroll
  for (int t = 0; t < 4; t++) {
    float s = s_[t], qq = q_[t];
    s  += __shfl_xor(s, 16, 64);  s  += __shfl_xor(s, 32, 64);
    qq += __shfl_xor(qq, 16, 64); qq += __shfl_xor(qq, 32, 64);
    if (lane < 16) { sm[wave * 128 + t * 16 + lane] = s; sm[wave * 128 + 64 + t * 16 + lane] = qq; }
  }
  __syncthreads();
  if (threadIdx.x < 128) {
    int which = threadIdx.x >> 6, cc = threadIdx.x & 63;
    float v = 0.f;
    for (int w = 0; w < 4; w++) v += sm[w * 128 + which * 64 + cc];
    // statsB0 [NBIN][192]: sums [0..95], sumsq [96..191]; agg = cols 32..95
    atomicAdd(statsOut + (blockIdx.x & (NBIN - 1)) * 192 + which * 96 + 32 + cc, v);
  }
}

// ======== GEMM B1: [xb, agg_b] (K=96 -> 96), LReLU, stats =================
__global__ __launch_bounds__(256) void gemmB1_kernel(
    const u16* __restrict__ xb, const u16* __restrict__ agg_b,
    const float* __restrict__ statsB0, float invN,
    const void* __restrict__ g, const void* __restrict__ b,
    const void* __restrict__ W, const void* __restrict__ c,
    u16* __restrict__ hout, int N, float* __restrict__ statsOut,
    const int* __restrict__ modep) {
  __shared__ u16 wlds[9216], wpack[9216];
  __shared__ float s_s[96], s_off[96], sbias[96];
  __shared__ float sm[768];
  const int mode = *modep;
  fold_block(statsB0, invN, g, b, W, c, 96, 96, mode, wlds, wpack, s_s, s_off, sbias);
  const int lane = threadIdx.x & 63, wave = threadIdx.x >> 6;
  const int q = lane >> 4, r = lane & 15;
  const long wbase = (long)blockIdx.x * 256 + wave * 64;
  bf16x8 bfr[6][3];
#pragma unroll
  for (int t = 0; t < 6; t++)
#pragma unroll
    for (int h = 0; h < 3; h++)
      bfr[t][h] = *reinterpret_cast<const bf16x8*>(wpack + ((t * 3 + h) * 64 + lane) * 8);
  float bv[6];
#pragma unroll
  for (int t = 0; t < 6; t++) bv[t] = sbias[t * 16 + r];
  float s_[6] = {0, 0, 0, 0, 0, 0}, q_[6] = {0, 0, 0, 0, 0, 0};
#pragma unroll
  for (int r4 = 0; r4 < 4; r4++) {
    const long row0 = wbase + r4 * 16;
    long m = row0 + r;
    long mm = m < N ? m : (long)N - 1;
    bf16x8 a0 = ldb8(xb + mm * 32 + q * 8);
    bf16x8 a1 = ldb8(agg_b + mm * 64 + q * 8);
    bf16x8 a2 = ldb8(agg_b + mm * 64 + 32 + q * 8);
    floatx4 acc[6];
#pragma unroll
    for (int t = 0; t < 6; t++) {
      acc[t] = (floatx4){bv[t], bv[t], bv[t], bv[t]};
      acc[t] = mfma16(a0, bfr[t][0], acc[t]);
      acc[t] = mfma16(a1, bfr[t][1], acc[t]);
      acc[t] = mfma16(a2, bfr[t][2], acc[t]);
    }
#pragma unroll
    for (int t = 0; t < 6; t++)
#pragma unroll
      for (int gi = 0; gi < 4; gi++) {
        long row = row0 + q * 4 + gi;
        if (row < N) {
          float v = acc[t][gi];
          v = v > 0.f ? v : 0.1f * v;
          u16 st = f2bf(v);
          hout[row * 96 + t * 16 + r] = st;
          float vv = bf2f(st);
          s_[t] += vv; q_[t] += vv * vv;
        }
      }
  }
#pragma unroll
  for (int t = 0; t < 6; t++) {
    float s = s_[t], qq = q_[t];
    s  += __shfl_xor(s, 16, 64);  s  += __shfl_xor(s, 32, 64);
    qq += __shfl_xor(qq, 16, 64); qq += __shfl_xor(qq, 32, 64);
    if (lane < 16) { sm[wave * 192 + t * 16 + lane] = s; sm[wave * 192 + 96 + t * 16 + lane] = qq; }
  }
  __syncthreads();
  if (threadIdx.x < 192) {
    int which = threadIdx.x / 96, cc = threadIdx.x % 96;
    float v = 0.f;
    for (int w = 0; w < 4; w++) v += sm[w * 192 + which * 96 + cc];
    atomicAdd(statsOut + (blockIdx.x & (NBIN - 1)) * 192 + which * 96 + cc, v);
  }
}

// ======== GEMM B2: h[N,96] -> h[N,96] in place, LReLU, stats ===============
__global__ __launch_bounds__(256) void gemmB2_kernel(
    const u16* __restrict__ hin,
    const float* __restrict__ statsB1, float invN,
    const void* __restrict__ g, const void* __restrict__ b,
    const void* __restrict__ W, const void* __restrict__ c,
    u16* __restrict__ hout, int N, float* __restrict__ statsOut,
    const int* __restrict__ modep) {
  __shared__ u16 wlds[9216], wpack[9216];
  __shared__ float s_s[96], s_off[96], sbias[96];
  __shared__ float sm[768];
  const int mode = *modep;
  fold_block(statsB1, invN, g, b, W, c, 96, 96, mode, wlds, wpack, s_s, s_off, sbias);
  const int lane = threadIdx.x & 63, wave = threadIdx.x >> 6;
  const int q = lane >> 4, r = lane & 15;
  const long wbase = (long)blockIdx.x * 256 + wave * 64;
  bf16x8 bfr[6][3];
#pragma unroll
  for (int t = 0; t < 6; t++)
#pragma unroll
    for (int h = 0; h < 3; h++)
      bfr[t][h] = *reinterpret_cast<const bf16x8*>(wpack + ((t * 3 + h) * 64 + lane) * 8);
  float bv[6];
#pragma unroll
  for (int t = 0; t < 6; t++) bv[t] = sbias[t * 16 + r];
  float s_[6] = {0, 0, 0, 0, 0, 0}, q_[6] = {0, 0, 0, 0, 0, 0};
#pragma unroll
  for (int r4 = 0; r4 < 4; r4++) {
    const long row0 = wbase + r4 * 16;
    long m = row0 + r;
    long mm = m < N ? m : (long)N - 1;
    bf16x8 a0 = ldb8(hin + mm * 96 + q * 8);
    bf16x8 a1 = ldb8(hin + mm * 96 + 32 + q * 8);
    bf16x8 a2 = ldb8(hin + mm * 96 + 64 + q * 8);
    floatx4 acc[6];
#pragma unroll
    for (int t = 0; t < 6; t++) {
      acc[t] = (floatx4){bv[t], bv[t], bv[t], bv[t]};
      acc[t] = mfma16(a0, bfr[t][0], acc[t]);
      acc[t] = mfma16(a1, bfr[t][1], acc[t]);
      acc[t] = mfma16(a2, bfr[t][2], acc[t]);
    }
#pragma unroll
    for (int t = 0; t < 6; t++)
#pragma unroll
      for (int gi = 0; gi < 4; gi++) {
        long row = row0 + q * 4 + gi;
        if (row < N) {
          float v = acc[t][gi];
          v = v > 0.f ? v : 0.1f * v;
          u16 st = f2bf(v);
          hout[row * 96 + t * 16 + r] = st;
          float vv = bf2f(st);
          s_[t] += vv; q_[t] += vv * vv;
        }
      }
  }
#pragma unroll
  for (int t = 0; t < 6; t++) {
    float s = s_[t], qq = q_[t];
    s  += __shfl_xor(s, 16, 64);  s  += __shfl_xor(s, 32, 64);
    qq += __shfl_xor(qq, 16, 64); qq += __shfl_xor(qq, 32, 64);
    if (lane < 16) { sm[wave * 192 + t * 16 + lane] = s; sm[wave * 192 + 96 + t * 16 + lane] = qq; }
  }
  __syncthreads();
  if (threadIdx.x < 192) {
    int which = threadIdx.x / 96, cc = threadIdx.x % 96;
    float v = 0.f;
    for (int w = 0; w < 4; w++) v += sm[w * 192 + which * 96 + cc];
    atomicAdd(statsOut + (blockIdx.x & (NBIN - 1)) * 192 + which * 96 + cc, v);
  }
}

// ======== GEMM B3: h[N,96] -> out[N,32], no activation =====================
__global__ __launch_bounds__(256) void gemmB3_kernel(
    const u16* __restrict__ hin,
    const float* __restrict__ statsB2, float invN,
    const void* __restrict__ g, const void* __restrict__ b,
    const void* __restrict__ W, const void* __restrict__ c,
    void* __restrict__ outv, int N, const int* __restrict__ modep) {
  __shared__ u16 wlds[3072], wpack[3072];
  __shared__ float s_s[96], s_off[96], sbias[32];
  const int mode = *modep;
  fold_block(statsB2, invN, g, b, W, c, 96, 32, mode, wlds, wpack, s_s, s_off, sbias);
  const int lane = threadIdx.x & 63, wave = threadIdx.x >> 6;
  const int q = lane >> 4, r = lane & 15;
  const long wbase = (long)blockIdx.x * 256 + wave * 64;
  bf16x8 bfr[2][3];
#pragma unroll
  for (int t = 0; t < 2; t++)
#pragma unroll
    for (int h = 0; h < 3; h++)
      bfr[t][h] = *reinterpret_cast<const bf16x8*>(wpack + ((t * 3 + h) * 64 + lane) * 8);
  float bv[2];
#pragma unroll
  for (int t = 0; t < 2; t++) bv[t] = sbias[t * 16 + r];
#pragma unroll
  for (int r4 = 0; r4 < 4; r4++) {
    const long row0 = wbase + r4 * 16;
    long m = row0 + r;
    long mm = m < N ? m : (long)N - 1;
    bf16x8 a0 = ldb8(hin + mm * 96 + q * 8);
    bf16x8 a1 = ldb8(hin + mm * 96 + 32 + q * 8);
    bf16x8 a2 = ldb8(hin + mm * 96 + 64 + q * 8);
    floatx4 acc[2];
#pragma unroll
    for (int t = 0; t < 2; t++) {
      acc[t] = (floatx4){bv[t], bv[t], bv[t], bv[t]};
      acc[t] = mfma16(a0, bfr[t][0], acc[t]);
      acc[t] = mfma16(a1, bfr[t][1], acc[t]);
      acc[t] = mfma16(a2, bfr[t][2], acc[t]);
    }
#pragma unroll
    for (int t = 0; t < 2; t++)
#pragma unroll
      for (int gi = 0; gi < 4; gi++) {
        long row = row0 + q * 4 + gi;
        if (row < N) {
          float v = acc[t][gi];
          if (mode) ((u16*)outv)[row * 32 + t * 16 + r] = f2bf(v);
          else      ((float*)outv)[row * 32 + t * 16 + r] = v;
        }
      }
  }
}

// ---------------------------------------------------------------------------
extern "C" void kernel_launch(void* const* d_in, const int* in_sizes, int n_in,
                              void* d_out, int out_size, void* d_ws,
                              size_t ws_size, hipStream_t stream) {
  const int N = in_sizes[0] / 32;
  const int E = in_sizes[2] / 32;

  const void* x    = d_in[0];
  const int*  eidx = (const int*)d_in[1];  // [2][E]: row=eidx, col=eidx+E
  const void* ea   = d_in[2];
  const void *m1_g1 = d_in[5],  *m1_b1 = d_in[6];
  const void *m1_w1 = d_in[7],  *m1_c1 = d_in[8];
  const void *m1_g2 = d_in[9],  *m1_b2 = d_in[10];
  const void *m1_w2 = d_in[11], *m1_c2 = d_in[12];
  const void *m1_g3 = d_in[13], *m1_b3 = d_in[14];
  const void *m1_w3 = d_in[15], *m1_c3 = d_in[16];
  const void *m2_g1 = d_in[17], *m2_b1 = d_in[18];
  const void *m2_w1 = d_in[19], *m2_c1 = d_in[20];
  const void *m2_g2 = d_in[21], *m2_b2 = d_in[22];
  const void *m2_w2 = d_in[23], *m2_c2 = d_in[24];
  const void *m2_g3 = d_in[25], *m2_b3 = d_in[26];
  const void *m2_w3 = d_in[27], *m2_c3 = d_in[28];

  // workspace carve (16B-aligned chunks)
  char* w = (char*)d_ws;
  int*   modep  = (int*)w;   w += 16;
  u16*   h_s    = (u16*)w;   w += (size_t)E * 64 * 2;       // 102.4 MB (sorted)
  u16*   h2b    = (u16*)w;   w += (size_t)N * 96 * 2;       //  19.2 MB
  u16*   agg_b  = (u16*)w;   w += (size_t)N * 64 * 2;       //  12.8 MB
  u16*   xb     = (u16*)w;   w += (size_t)N * 32 * 2;       //   6.4 MB
  int*   offs   = (int*)w;   w += ((size_t)N + 4) * 4;
  int*   cursor = (int*)w;   w += ((size_t)N + 4) * 4;
  int*   ipos   = (int*)w;   w += (size_t)E * 4;            //   3.2 MB
  int*   nodeof = (int*)w;   w += (size_t)E * 4;            //   3.2 MB
  int*   bsum   = (int*)w;   w += 1024 * 4;
  // zero zone: s_e + deg + odeg + all stats buffers (contiguous)
  float* s_e    = (float*)w; w += (size_t)N * 64 * 4;       //  25.6 MB
  int*   deg    = (int*)w;   w += (size_t)N * 4;
  int*   odeg   = (int*)w;   w += (size_t)N * 4;
  float* stats0 = (float*)w; w += NBIN * 128 * 4;
  float* stats1 = (float*)w; w += NBIN * 128 * 4;
  float* stats2 = (float*)w; w += NBIN * 128 * 4;
  float* statsB0= (float*)w; w += NBIN * 192 * 4;
  float* statsB1= (float*)w; w += NBIN * 192 * 4;
  float* statsB2= (float*)w; w += NBIN * 192 * 4;
  const size_t zero_bytes = (size_t)N * 64 * 4 + (size_t)N * 8 +
                            NBIN * (128 * 3 + 192 * 3) * 4;
  // optional bf16 copy of ea (enabled only if workspace allows)
  const size_t eab_bytes = (size_t)E * 32 * 2;              //  51.2 MB
  const size_t used = (size_t)(w - (char*)d_ws);
  const int use_eab = (ws_size >= used + eab_bytes) ? 1 : 0;
  u16* eab = use_eab ? (u16*)w : nullptr;

  const int* erow = eidx;
  const int* ecol = eidx + E;
  const float invE = 1.0f / (float)E, invN = 1.0f / (float)N;
  const int gA = (E + 255) / 256, gB = (N + 255) / 256;
  const int nb = (N + 1023) / 1024;

  detect_kernel<<<1, 256, 0, stream>>>((const u16*)x, modep);
  hipMemsetAsync(s_e, 0, zero_bytes, stream);

  // --- counting sort of edges by destination + degree histograms ---
  count2_kernel<<<1024, 256, 0, stream>>>(erow, ecol, E, odeg, deg);
  scan1_kernel<<<nb, 1024, 0, stream>>>(deg, N, offs, bsum);
  scan2_kernel<<<1, 1024, 0, stream>>>(bsum, nb, offs, N, E);
  scan3_kernel<<<nb, 1024, 0, stream>>>(offs, bsum, N, cursor);
  scatter_kernel<<<1024, 256, 0, stream>>>(ecol, E, cursor, ipos, nodeof);

  // --- merged input stats + xb/eab conversion ---
  stats_in_kernel<<<1024, 256, 0, stream>>>(x, odeg, N, ea, E,
                                            stats0, statsB0, xb, eab, modep);

  // --- phase A: edge MLP (h written destination-sorted; folds inlined) ---
  gemm1_kernel<<<gA, 256, 0, stream>>>(
      xb, use_eab ? (const void*)eab : ea, use_eab ? 1 : -1,
      erow, ipos, stats0, invE, m1_g1, m1_b1, m1_w1, m1_c1,
      h_s, E, stats1, modep);
  gemm2_kernel<<<gA, 256, 0, stream>>>(
      h_s, stats1, invE, m1_g2, m1_b2, m1_w2, m1_c2,
      E, stats2, offs, nodeof, s_e, modep);

  // --- aggregation GEMM ---
  gemmAgg_kernel<<<gB, 256, 0, stream>>>(
      s_e, deg, stats2, invE, m1_g3, m1_b3, m1_w3, m1_c3,
      agg_b, N, statsB0, modep);

  // --- phase B: node MLP ---
  gemmB1_kernel<<<gB, 256, 0, stream>>>(
      xb, agg_b, statsB0, invN, m2_g1, m2_b1, m2_w1, m2_c1,
      h2b, N, statsB1, modep);
  gemmB2_kernel<<<gB, 256, 0, stream>>>(
      h2b, statsB1, invN, m2_g2, m2_b2, m2_w2, m2_c2,
      h2b, N, statsB2, modep);
  gemmB3_kernel<<<gB, 256, 0, stream>>>(
      h2b, statsB2, invN, m2_g3, m2_b3, m2_w3, m2_c3,
      d_out, N, modep);
}